// Round 5
// baseline (629.625 us; speedup 1.0000x reference)
//
#include <hip/hip_runtime.h>
#include <hip/hip_bf16.h>
#include <math.h>

#define NPIX 262144          // 512*512
#define PI_D 3.14159265358979323846264338327950288

// ---------------- ws layout (byte offsets) ----------------
// 0       : double stats[2]            (mean_t, template_var)
// 64      : double spart[64][2]
// 2048    : double den[32][121]
// 33280   : double snn_part[32][8]
// 35328   : double shx[32]
// 35584   : double shy[32]
// 35840   : float  c2[32]
// 36096   : float  partial[32][32][121]   (495,616 B)
// 532480  : float  ary[32][512]
// 598016  : float  arx[32][512]
// 663552  : float  csum[32][8][512]
// 1187840 : float  csum2[32][8][512]
// 2097152 : float  yt[cb][512][512]

// K1a: template partial sums (64 blocks, float4 loads, double accum)
__global__ __launch_bounds__(256) void k_stats_part(const float* __restrict__ t, double* __restrict__ part){
    int base = blockIdx.x * 4096;
    double s = 0.0, s2 = 0.0;
    #pragma unroll
    for (int k = 0; k < 4; ++k){
        float4 v = *(const float4*)&t[base + k*1024 + threadIdx.x*4];
        s  += (double)v.x + (double)v.y + (double)v.z + (double)v.w;
        s2 += (double)v.x*v.x + (double)v.y*v.y + (double)v.z*v.z + (double)v.w*v.w;
    }
    __shared__ double rs[256], rs2[256];
    rs[threadIdx.x] = s; rs2[threadIdx.x] = s2; __syncthreads();
    for (int off = 128; off > 0; off >>= 1){
        if (threadIdx.x < off){ rs[threadIdx.x] += rs[threadIdx.x+off]; rs2[threadIdx.x] += rs2[threadIdx.x+off]; }
        __syncthreads();
    }
    if (threadIdx.x == 0){ part[blockIdx.x*2] = rs[0]; part[blockIdx.x*2+1] = rs2[0]; }
}

// K1b: finalize template stats
__global__ __launch_bounds__(64) void k_stats_final(const double* __restrict__ part, double* __restrict__ stats){
    double s = part[threadIdx.x*2], s2 = part[threadIdx.x*2+1];
    #pragma unroll
    for (int off = 32; off > 0; off >>= 1){
        s  += __shfl_down(s, off);
        s2 += __shfl_down(s2, off);
    }
    if (threadIdx.x == 0){
        stats[0] = s / (double)NPIX;
        stats[1] = s2 - s*s/(double)NPIX + 1e-8;
    }
}

// K2a: per-chunk column sums (+squares) over 64 rows, fused with Nyquist alternating sum
__global__ __launch_bounds__(256) void k_colsums(const float* __restrict__ fr, float* __restrict__ csum,
                                                 float* __restrict__ csum2, double* __restrict__ snn_part){
    int b = blockIdx.x >> 3, chunk = blockIdx.x & 7;
    const float* img = fr + (size_t)b * NPIX + (size_t)chunk * (64*512);
    int t = threadIdx.x;
    float a0=0.f, q0=0.f, a1=0.f, q1=0.f;
    double sn = 0.0;
    for (int r = 0; r < 64; ++r){
        float v0 = img[(r<<9) + t];
        float v1 = img[(r<<9) + t + 256];
        a0 += v0; q0 += v0*v0; a1 += v1; q1 += v1*v1;
        float sv = v0 + v1;                         // cols t and t+256 share parity
        sn += ((r + t) & 1) ? -(double)sv : (double)sv;   // (-1)^(row+col), chunk*64 even
    }
    size_t o = ((size_t)(b*8 + chunk) << 9) + t;
    csum[o] = a0;  csum[o + 256] = a1;
    csum2[o] = q0; csum2[o + 256] = q1;
    __shared__ double rs[256];
    rs[t] = sn; __syncthreads();
    for (int off = 128; off > 0; off >>= 1){
        if (t < off) rs[t] += rs[t+off];
        __syncthreads();
    }
    if (t == 0) snn_part[b*8 + chunk] = rs[0];
}

// K2b: finalize 121 window denominators per image from column sums + edges
__global__ __launch_bounds__(256) void k_winfin(const float* __restrict__ fr, const float* __restrict__ csum,
                                                const float* __restrict__ csum2, const double* __restrict__ stats,
                                                double* __restrict__ den){
    int b = blockIdx.x;
    const float* img = fr + (size_t)b * NPIX;
    __shared__ double fc[512], fc2[512];
    __shared__ double rsum[20], rsum2[20];
    __shared__ float E[20][20], E2[20][20];
    __shared__ double red[256], red2[256];
    int t = threadIdx.x;
    for (int c = t; c < 512; c += 256){
        double s = 0.0, s2 = 0.0;
        for (int k = 0; k < 8; ++k){
            size_t o = ((size_t)(b*8 + k) << 9) + c;
            s += (double)csum[o]; s2 += (double)csum2[o];
        }
        fc[c] = s; fc2[c] = s2;
    }
    if (t < 400){
        int i = t / 20, j = t % 20;
        int row = (i < 10) ? i : (i + 492);    // rows 0..9, 502..511
        int col = (j < 10) ? j : (j + 492);
        float v = img[(row<<9) + col];
        E[i][j] = v; E2[i][j] = v*v;
    }
    __syncthreads();
    red[t] = fc[t] + fc[t+256];
    red2[t] = fc2[t] + fc2[t+256];
    __syncthreads();
    for (int off = 128; off > 0; off >>= 1){
        if (t < off){ red[t] += red[t+off]; red2[t] += red2[t+off]; }
        __syncthreads();
    }
    double F1 = red[0], F2 = red2[0];
    int lane = t & 63, wv = t >> 6;
    for (int e = wv; e < 20; e += 4){
        int row = (e < 10) ? e : (e + 492);
        double s = 0.0, s2 = 0.0;
        for (int c = lane; c < 512; c += 64){
            float v = img[(row<<9) + c];
            s += v; s2 += (double)v*v;
        }
        #pragma unroll
        for (int off = 32; off > 0; off >>= 1){ s += __shfl_down(s, off); s2 += __shfl_down(s2, off); }
        if (lane == 0){ rsum[e] = s; rsum2[e] = s2; }
    }
    __syncthreads();
    if (t < 121){
        int u = t / 11, v = t % 11;
        double S1 = F1, S2 = F2;
        for (int i = 0; i < u; ++i){ S1 -= rsum[i]; S2 -= rsum2[i]; }          // excluded top rows 0..u-1
        for (int k = 10+u; k < 20; ++k){ S1 -= rsum[k]; S2 -= rsum2[k]; }      // excluded bottom rows u+502..511
        for (int j = 0; j < v; ++j){                                           // excluded left cols, minus corners
            double cw = fc[j], cq = fc2[j];
            for (int i = 0; i < u; ++i){ cw -= E[i][j]; cq -= E2[i][j]; }
            for (int k = 10+u; k < 20; ++k){ cw -= E[k][j]; cq -= E2[k][j]; }
            S1 -= cw; S2 -= cq;
        }
        for (int jj = 10+v; jj < 20; ++jj){                                    // excluded right cols v+502..511
            int col = jj + 492;
            double cw = fc[col], cq = fc2[col];
            for (int i = 0; i < u; ++i){ cw -= E[i][jj]; cq -= E2[i][jj]; }
            for (int k = 10+u; k < 20; ++k){ cw -= E[k][jj]; cq -= E2[k][jj]; }
            S1 -= cw; S2 -= cq;
        }
        const double K = 502.0*502.0;
        double ivar = S2/K - (S1*S1)/(K*K*K) + 1e-8;
        if (ivar < 0.0) ivar = 0.0;
        den[b*121 + u*11 + v] = sqrt(stats[1] * ivar);
    }
}

// K3: direct shifted cross-correlation, 121 shifts.
// Block = 128 threads = (4 row-lanes interleaved) x (32 col-groups of 16 cols).
// Grid = 32 images x 32 chunks of 16 rows.
// NOTE: epilogue reduction is FULLY UNROLLED so acc[][] is only ever indexed with
// compile-time constants -> stays in VGPRs (runtime indexing spills the whole array
// to scratch: R4 showed 352 MB of scratch writes from exactly that).
__global__ __launch_bounds__(128, 2) void k_ncc(const float* __restrict__ fr, const float* __restrict__ tpl,
                                                const double* __restrict__ stats, float* __restrict__ partial){
    int b = blockIdx.x >> 5, chunk = blockIdx.x & 31;
    const float* img = fr + (size_t)b * NPIX;
    float mean = (float)stats[0];
    __shared__ float tr[16][548];
    __shared__ float wred[2][121];
    int i0 = chunk << 4;
    int tid = threadIdx.x;
    // prefill ring with unwrapped rows i0-5 .. i0+10
    for (int idx = tid; idx < 16*544; idx += 128){
        int r = idx / 544, k = idx - r*544;
        int rowu = i0 - 5 + r;
        tr[rowu & 15][k] = tpl[(((rowu + 512) & 511) << 9) | ((k - 16) & 511)] - mean;
    }
    __syncthreads();
    int rg = tid & 3;                 // row-lane (interleaved for LDS bank spread)
    int cg = tid >> 2;                // 0..31 col-group
    int j0 = cg << 4;
    float acc[11][11];
    #pragma unroll
    for (int a = 0; a < 11; ++a)
        #pragma unroll
        for (int c = 0; c < 11; ++c) acc[a][c] = 0.f;
    #pragma unroll 1
    for (int k = 0; k < 4; ++k){
        int i = i0 + 4*k + rg;        // 0..511, no wrap needed
        float x[16];
        #pragma unroll
        for (int q = 0; q < 4; ++q)
            *(float4*)&x[4*q] = *(const float4*)&img[(i<<9) + j0 + 4*q];
        #pragma unroll
        for (int s0 = 0; s0 < 11; ++s0){
            int rowt = i + 5 - s0;     // unwrapped; ring & 15 valid (window of 14 <= 16)
            const float* trow = tr[rowt & 15];
            float tv[32];
            #pragma unroll
            for (int q = 0; q < 8; ++q)
                *(float4*)&tv[4*q] = *(const float4*)&trow[j0 + 8 + 4*q];   // t[rowt][j0-8 .. j0+23]
            #pragma unroll
            for (int s1 = 0; s1 < 11; ++s1)
                #pragma unroll
                for (int c = 0; c < 16; ++c)
                    acc[s0][s1] += x[c] * tv[c + 13 - s1];   // t[rowt][j0+c+5-s1]
        }
        __syncthreads();
        if (k < 3){
            // stage next 4 rows: i0+11+4k .. i0+14+4k (replace oldest 4)
            for (int idx = tid; idx < 4*544; idx += 128){
                int r = idx / 544, kk = idx - r*544;
                int rowu = i0 + 11 + 4*k + r;
                tr[rowu & 15][kk] = tpl[(((rowu) & 511) << 9) | ((kk - 16) & 511)] - mean;
            }
        }
        __syncthreads();
    }
    int lane = tid & 63, wv = tid >> 6;
    // fully-unrolled wave reduction (static acc indices -> registers)
    #pragma unroll
    for (int s0 = 0; s0 < 11; ++s0){
        #pragma unroll
        for (int s1 = 0; s1 < 11; ++s1){
            float v = acc[s0][s1];
            v += __shfl_down(v, 32); v += __shfl_down(v, 16); v += __shfl_down(v, 8);
            v += __shfl_down(v, 4);  v += __shfl_down(v, 2);  v += __shfl_down(v, 1);
            if (lane == 0) wred[wv][s0*11 + s1] = v;
        }
    }
    __syncthreads();
    if (tid < 121)
        partial[(size_t)(b*32 + chunk)*121 + tid] = wred[0][tid] + wred[1][tid];
}

// K4: ncc, argmax, log-parabola subpixel -> shifts (double), c2 coefficient
__global__ __launch_bounds__(128) void k_shifts(const float* __restrict__ partial, const double* __restrict__ den,
                                                const double* __restrict__ snn_part, double* __restrict__ shx,
                                                double* __restrict__ shy, float* __restrict__ c2){
    int b = blockIdx.x;
    __shared__ double l[121], nc[121];
    for (int e = threadIdx.x; e < 121; e += 128){
        double s = 0.0;
        for (int c = 0; c < 32; ++c) s += (double)partial[(size_t)(b*32 + c)*121 + e];
        double nom = fabs(s);
        double v = nom / den[b*121 + e];
        if (v != v) v = 0.0;
        nc[e] = v;
        l[e] = log(v);
    }
    __syncthreads();
    if (threadIdx.x == 0){
        int am = 0; double best = nc[0];
        for (int e = 1; e < 121; ++e) if (nc[e] > best){ best = nc[e]; am = e; }
        int u = am / 11, v = am % 11;
        double sx = -(double)(u - 5), sy = -(double)(v - 5);
        int um1 = u - 1; if (um1 < 0) um1 += 11; if (um1 > 10) um1 = 10;
        int up1 = u + 1; if (up1 > 10) up1 = 10;
        int vm1 = v - 1; if (vm1 < 0) vm1 += 11; if (vm1 > 10) vm1 = 10;
        int vp1 = v + 1; if (vp1 > 10) vp1 = 10;
        double l0x4 = 4.0 * l[u*11 + v];
        double lm = l[um1*11 + v], lp = l[up1*11 + v];
        sx -= (lm - lp) / (2.0*lm - l0x4 + 2.0*lp);
        double lm2 = l[u*11 + vm1], lp2 = l[u*11 + vp1];
        sy -= (lm2 - lp2) / (2.0*lm2 - l0x4 + 2.0*lp2);
        shx[b] = sx; shy[b] = sy;
        double snn = 0.0;
        for (int c = 0; c < 8; ++c) snn += snn_part[b*8 + c];
        double kx = sin(PI_D * sx) / 512.0, ky = sin(PI_D * sy) / 512.0;
        c2[b] = (float)(kx * ky * snn);
    }
}

__device__ inline double grekern(int t, double s){
    double u = (double)t - s;
    if (u > 256.0) u -= 512.0;
    double a = PI_D * u / 512.0;
    double sp = sin(a);
    double D;
    if (fabs(sp) < 1e-12) D = cos(PI_D * u) / cos(a);     // u ~ 0
    else D = sin(PI_D * u) / (512.0 * sp);
    return D * cos(a);
}

// K4b: real parts of the Dirichlet shift kernels (imag part handled analytically via c2)
__global__ __launch_bounds__(256) void k_tables(const double* __restrict__ shx, const double* __restrict__ shy,
                                                float* __restrict__ ary, float* __restrict__ arx){
    int b = blockIdx.x;
    double sx = shx[b], sy = shy[b];
    for (int t = threadIdx.x; t < 512; t += 256){
        arx[(b<<9) + t] = (float)grekern(t, sx);
        ary[(b<<9) + t] = (float)grekern(t, sy);
    }
}

// K5/K6: out[r][p] = sum_m in[r][m] * kern[(p-m)&511]   (real circulant matmul), optional parity correction
template<int CORR>
__global__ __launch_bounds__(256) void k_rowcirc(const float* __restrict__ src, int src_local,
                                                 const float* __restrict__ kern_all,
                                                 float* __restrict__ dst,
                                                 const float* __restrict__ c2, int c0){
    int lb = blockIdx.x >> 5, blk = blockIdx.x & 31;
    int b = c0 + lb;
    const float* in = src + (size_t)(src_local ? lb : b) * NPIX;
    const float* kern = kern_all + ((size_t)b << 9);
    float* out = dst + (size_t)b * NPIX;
    __shared__ float kd[1024];
    __shared__ float Xr[16][512];
    int r0 = blk << 4;
    for (int idx = threadIdx.x; idx < 1024; idx += 256) kd[idx] = kern[idx & 511];
    for (int idx = threadIdx.x; idx < 8192; idx += 256){
        int rr = idx >> 9;
        Xr[rr][idx & 511] = in[((size_t)(r0 + rr) << 9) + (idx & 511)];
    }
    __syncthreads();
    int rg = threadIdx.x >> 6;
    int p0 = (threadIdx.x & 63) << 3;
    float acc[4][8];
    #pragma unroll
    for (int a = 0; a < 4; ++a)
        #pragma unroll
        for (int c = 0; c < 8; ++c) acc[a][c] = 0.f;
    for (int m = 0; m < 512; m += 4){
        int base = p0 - m + 508;                  // 4-aligned, in [0,1012]
        float4 kq0 = *(const float4*)&kd[base];
        float4 kq1 = *(const float4*)&kd[base + 4];
        float4 kq2 = *(const float4*)&kd[base + 8];
        float kw[12] = {kq0.x,kq0.y,kq0.z,kq0.w, kq1.x,kq1.y,kq1.z,kq1.w, kq2.x,kq2.y,kq2.z,kq2.w};
        #pragma unroll
        for (int rr = 0; rr < 4; ++rr){
            float4 xv = *(const float4*)&Xr[rg*4 + rr][m];
            float xm[4] = {xv.x, xv.y, xv.z, xv.w};
            #pragma unroll
            for (int mi = 0; mi < 4; ++mi)
                #pragma unroll
                for (int pp = 0; pp < 8; ++pp)
                    acc[rr][pp] += xm[mi] * kw[pp + 4 - mi];
        }
    }
    float cc = CORR ? c2[b] : 0.f;
    #pragma unroll
    for (int rr = 0; rr < 4; ++rr){
        int q = r0 + rg*4 + rr;
        float vals[8];
        #pragma unroll
        for (int pp = 0; pp < 8; ++pp){
            float v = acc[rr][pp];
            if (CORR){
                int p = p0 + pp;
                v -= ((q + p) & 1) ? -cc : cc;    // out -= c2 * (-1)^(p+q)
            }
            vals[pp] = v;
        }
        float4 o0 = {vals[0], vals[1], vals[2], vals[3]};
        float4 o1 = {vals[4], vals[5], vals[6], vals[7]};
        *(float4*)&out[((size_t)q << 9) + p0] = o0;
        *(float4*)&out[((size_t)q << 9) + p0 + 4] = o1;
    }
}

// transpose 512x512 (YRe in d_out -> YT in ws)
__global__ __launch_bounds__(256) void k_transpose(const float* __restrict__ in, float* __restrict__ out, int c0){
    int lb = blockIdx.x >> 8, tb = blockIdx.x & 255;
    int b = c0 + lb;
    int tx = (tb & 15) << 5, ty = ((tb >> 4) & 15) << 5;
    const float* src = in + (size_t)b * NPIX;
    float* dst = out + (size_t)lb * NPIX;
    __shared__ float tile[32][33];
    int col = threadIdx.x & 31, rw = threadIdx.x >> 5;
    #pragma unroll
    for (int k = 0; k < 4; ++k){
        int ry = rw + k*8;
        tile[ry][col] = src[((size_t)(ty + ry) << 9) + tx + col];
    }
    __syncthreads();
    #pragma unroll
    for (int k = 0; k < 4; ++k){
        int ry = rw + k*8;
        dst[((size_t)(tx + ry) << 9) + ty + col] = tile[col][ry];
    }
}

extern "C" void kernel_launch(void* const* d_in, const int* in_sizes, int n_in,
                              void* d_out, int out_size, void* d_ws, size_t ws_size,
                              hipStream_t stream){
    (void)in_sizes; (void)n_in; (void)out_size;
    const float* fr  = (const float*)d_in[0];   // (1,32,512,512,1) f32
    const float* tpl = (const float*)d_in[1];   // (512,512) f32
    float* out = (float*)d_out;                 // (32, 512*512) f32
    char* ws = (char*)d_ws;

    double* stats  = (double*)(ws + 0);
    double* spart  = (double*)(ws + 64);
    double* den    = (double*)(ws + 2048);
    double* snnp   = (double*)(ws + 33280);
    double* shx    = (double*)(ws + 35328);
    double* shy    = (double*)(ws + 35584);
    float*  c2     = (float*) (ws + 35840);
    float*  part   = (float*) (ws + 36096);
    float*  ary    = (float*) (ws + 532480);
    float*  arx    = (float*) (ws + 598016);
    float*  csum   = (float*) (ws + 663552);
    float*  csum2  = (float*) (ws + 1187840);
    float*  yt     = (float*) (ws + 2097152);

    long long ytcap = ((long long)ws_size - 2097152) / ((long long)NPIX * 4);
    int cb = (int)ytcap; if (cb > 32) cb = 32; if (cb < 1) cb = 1;

    k_stats_part<<<64, 256, 0, stream>>>(tpl, spart);
    k_stats_final<<<1, 64, 0, stream>>>(spart, stats);
    k_colsums<<<256, 256, 0, stream>>>(fr, csum, csum2, snnp);
    k_winfin<<<32, 256, 0, stream>>>(fr, csum, csum2, stats, den);
    k_ncc<<<1024, 128, 0, stream>>>(fr, tpl, stats, part);
    k_shifts<<<32, 128, 0, stream>>>(part, den, snnp, shx, shy, c2);
    k_tables<<<32, 256, 0, stream>>>(shx, shy, ary, arx);

    for (int c0 = 0; c0 < 32; c0 += cb){
        int nb = (32 - c0 < cb) ? (32 - c0) : cb;
        // stage 1: YRe[m][q] = sum_n x[m][n] * gyRe[(q-n)&511]   (stored in d_out region of batch)
        k_rowcirc<0><<<nb*32, 256, 0, stream>>>(fr, 0, ary, out, (const float*)nullptr, c0);
        // transpose YRe -> YT
        k_transpose<<<nb*256, 256, 0, stream>>>(out, yt, c0);
        // stage 2: out[q*512+p] = sum_m YT[q][m] * gxRe[(p-m)&511]  - c2*(-1)^(p+q)
        k_rowcirc<1><<<nb*32, 256, 0, stream>>>(yt, 1, arx, out, c2, c0);
    }
}

// Round 6
// 364.837 us; speedup vs baseline: 1.7258x; 1.7258x over previous
//
#include <hip/hip_runtime.h>
#include <hip/hip_bf16.h>
#include <math.h>

#define NPIX 262144          // 512*512
#define PI_D 3.14159265358979323846264338327950288

// ---------------- ws layout (byte offsets) ----------------
// 0       : double stats[2]            (mean_t, template_var)
// 64      : double spart[64][2]
// 2048    : double den[32][121]
// 33280   : double snn_part[32][8]
// 35328   : double shx[32]
// 35584   : double shy[32]
// 35840   : float  c2[32]
// 36096   : float  partial[32][32][121]   (495,616 B)
// 532480  : float  ary[32][512]
// 598016  : float  arx[32][512]
// 663552  : float  csum[32][8][512]
// 1187840 : float  csum2[32][8][512]
// 2097152 : float  yt[cb][512][512]

// K1a: template partial sums (64 blocks, float4 loads, double accum)
__global__ __launch_bounds__(256) void k_stats_part(const float* __restrict__ t, double* __restrict__ part){
    int base = blockIdx.x * 4096;
    double s = 0.0, s2 = 0.0;
    #pragma unroll
    for (int k = 0; k < 4; ++k){
        float4 v = *(const float4*)&t[base + k*1024 + threadIdx.x*4];
        s  += (double)v.x + (double)v.y + (double)v.z + (double)v.w;
        s2 += (double)v.x*v.x + (double)v.y*v.y + (double)v.z*v.z + (double)v.w*v.w;
    }
    __shared__ double rs[256], rs2[256];
    rs[threadIdx.x] = s; rs2[threadIdx.x] = s2; __syncthreads();
    for (int off = 128; off > 0; off >>= 1){
        if (threadIdx.x < off){ rs[threadIdx.x] += rs[threadIdx.x+off]; rs2[threadIdx.x] += rs2[threadIdx.x+off]; }
        __syncthreads();
    }
    if (threadIdx.x == 0){ part[blockIdx.x*2] = rs[0]; part[blockIdx.x*2+1] = rs2[0]; }
}

// K1b: finalize template stats
__global__ __launch_bounds__(64) void k_stats_final(const double* __restrict__ part, double* __restrict__ stats){
    double s = part[threadIdx.x*2], s2 = part[threadIdx.x*2+1];
    #pragma unroll
    for (int off = 32; off > 0; off >>= 1){
        s  += __shfl_down(s, off);
        s2 += __shfl_down(s2, off);
    }
    if (threadIdx.x == 0){
        stats[0] = s / (double)NPIX;
        stats[1] = s2 - s*s/(double)NPIX + 1e-8;
    }
}

// K2a: per-chunk column sums (+squares) over 64 rows, fused with Nyquist alternating sum
__global__ __launch_bounds__(256) void k_colsums(const float* __restrict__ fr, float* __restrict__ csum,
                                                 float* __restrict__ csum2, double* __restrict__ snn_part){
    int b = blockIdx.x >> 3, chunk = blockIdx.x & 7;
    const float* img = fr + (size_t)b * NPIX + (size_t)chunk * (64*512);
    int t = threadIdx.x;
    float a0=0.f, q0=0.f, a1=0.f, q1=0.f;
    double sn = 0.0;
    for (int r = 0; r < 64; ++r){
        float v0 = img[(r<<9) + t];
        float v1 = img[(r<<9) + t + 256];
        a0 += v0; q0 += v0*v0; a1 += v1; q1 += v1*v1;
        float sv = v0 + v1;                         // cols t and t+256 share parity
        sn += ((r + t) & 1) ? -(double)sv : (double)sv;   // (-1)^(row+col), chunk*64 even
    }
    size_t o = ((size_t)(b*8 + chunk) << 9) + t;
    csum[o] = a0;  csum[o + 256] = a1;
    csum2[o] = q0; csum2[o + 256] = q1;
    __shared__ double rs[256];
    rs[t] = sn; __syncthreads();
    for (int off = 128; off > 0; off >>= 1){
        if (t < off) rs[t] += rs[t+off];
        __syncthreads();
    }
    if (t == 0) snn_part[b*8 + chunk] = rs[0];
}

// K2b: finalize 121 window denominators per image from column sums + edges
__global__ __launch_bounds__(256) void k_winfin(const float* __restrict__ fr, const float* __restrict__ csum,
                                                const float* __restrict__ csum2, const double* __restrict__ stats,
                                                double* __restrict__ den){
    int b = blockIdx.x;
    const float* img = fr + (size_t)b * NPIX;
    __shared__ double fc[512], fc2[512];
    __shared__ double rsum[20], rsum2[20];
    __shared__ float E[20][20], E2[20][20];
    __shared__ double red[256], red2[256];
    int t = threadIdx.x;
    for (int c = t; c < 512; c += 256){
        double s = 0.0, s2 = 0.0;
        for (int k = 0; k < 8; ++k){
            size_t o = ((size_t)(b*8 + k) << 9) + c;
            s += (double)csum[o]; s2 += (double)csum2[o];
        }
        fc[c] = s; fc2[c] = s2;
    }
    if (t < 400){
        int i = t / 20, j = t % 20;
        int row = (i < 10) ? i : (i + 492);    // rows 0..9, 502..511
        int col = (j < 10) ? j : (j + 492);
        float v = img[(row<<9) + col];
        E[i][j] = v; E2[i][j] = v*v;
    }
    __syncthreads();
    red[t] = fc[t] + fc[t+256];
    red2[t] = fc2[t] + fc2[t+256];
    __syncthreads();
    for (int off = 128; off > 0; off >>= 1){
        if (t < off){ red[t] += red[t+off]; red2[t] += red2[t+off]; }
        __syncthreads();
    }
    double F1 = red[0], F2 = red2[0];
    int lane = t & 63, wv = t >> 6;
    for (int e = wv; e < 20; e += 4){
        int row = (e < 10) ? e : (e + 492);
        double s = 0.0, s2 = 0.0;
        for (int c = lane; c < 512; c += 64){
            float v = img[(row<<9) + c];
            s += v; s2 += (double)v*v;
        }
        #pragma unroll
        for (int off = 32; off > 0; off >>= 1){ s += __shfl_down(s, off); s2 += __shfl_down(s2, off); }
        if (lane == 0){ rsum[e] = s; rsum2[e] = s2; }
    }
    __syncthreads();
    if (t < 121){
        int u = t / 11, v = t % 11;
        double S1 = F1, S2 = F2;
        for (int i = 0; i < u; ++i){ S1 -= rsum[i]; S2 -= rsum2[i]; }          // excluded top rows 0..u-1
        for (int k = 10+u; k < 20; ++k){ S1 -= rsum[k]; S2 -= rsum2[k]; }      // excluded bottom rows u+502..511
        for (int j = 0; j < v; ++j){                                           // excluded left cols, minus corners
            double cw = fc[j], cq = fc2[j];
            for (int i = 0; i < u; ++i){ cw -= E[i][j]; cq -= E2[i][j]; }
            for (int k = 10+u; k < 20; ++k){ cw -= E[k][j]; cq -= E2[k][j]; }
            S1 -= cw; S2 -= cq;
        }
        for (int jj = 10+v; jj < 20; ++jj){                                    // excluded right cols v+502..511
            int col = jj + 492;
            double cw = fc[col], cq = fc2[col];
            for (int i = 0; i < u; ++i){ cw -= E[i][jj]; cq -= E2[i][jj]; }
            for (int k = 10+u; k < 20; ++k){ cw -= E[k][jj]; cq -= E2[k][jj]; }
            S1 -= cw; S2 -= cq;
        }
        const double K = 502.0*502.0;
        double ivar = S2/K - (S1*S1)/(K*K*K) + 1e-8;
        if (ivar < 0.0) ivar = 0.0;
        den[b*121 + u*11 + v] = sqrt(stats[1] * ivar);
    }
}

// K3: direct shifted cross-correlation, 121 shifts, shift-split across waves.
// Block = 512 threads = (4 row-lanes rg) x (32 col-groups cg of 16 cols) x (4 shift-groups sg).
// Each thread accumulates only acc[3][11] (s0 = sg+4j) -> ~85 live VGPRs, NO spill
// (R4/R5 lesson: 121 accumulators/thread forced scratch spill = 350-850 MB HBM writes).
// Intra-wave = 16 cg x 4 rg, row stride 548 == 4 (mod 32) banks -> conflict-free ds_read_b128.
__global__ __launch_bounds__(512, 2) void k_ncc(const float* __restrict__ fr, const float* __restrict__ tpl,
                                                const double* __restrict__ stats, float* __restrict__ partial){
    int b = blockIdx.x >> 5, chunk = blockIdx.x & 31;
    const float* img = fr + (size_t)b * NPIX;
    float mean = (float)stats[0];
    __shared__ float tr[26][548];      // template rows i0-5 .. i0+20, halo'd cols -16..527
    __shared__ float wred[8][33];
    int i0 = chunk << 4;
    int tid = threadIdx.x;
    for (int idx = tid; idx < 26*544; idx += 512){
        int r = idx / 544, k = idx - r*544;
        tr[r][k] = tpl[(((i0 - 5 + r + 512) & 511) << 9) | ((k - 16) & 511)] - mean;
    }
    __syncthreads();
    int rg = tid & 3;                  // row-lane
    int cg = (tid >> 2) & 31;          // col-group (16 cols)
    int sg = tid >> 7;                 // shift-group: s0 in {sg, sg+4, sg+8}
    int j0 = cg << 4;
    float acc[3][11];
    #pragma unroll
    for (int j = 0; j < 3; ++j)
        #pragma unroll
        for (int s1 = 0; s1 < 11; ++s1) acc[j][s1] = 0.f;
    #pragma unroll 1
    for (int k = 0; k < 4; ++k){
        int i = i0 + 4*k + rg;         // 0..511, no wrap
        float x[16];
        #pragma unroll
        for (int q = 0; q < 4; ++q)
            *(float4*)&x[4*q] = *(const float4*)&img[(i<<9) + j0 + 4*q];
        #pragma unroll
        for (int j = 0; j < 3; ++j){
            int s0 = sg + 4*j;
            if (s0 < 11){              // wave-uniform guard (sg=3,j=2 idles)
                const float* trow = tr[4*k + rg + 10 - s0];   // row i+5-s0, tile-relative
                float tv[32];
                #pragma unroll
                for (int q = 0; q < 8; ++q)
                    *(float4*)&tv[4*q] = *(const float4*)&trow[j0 + 8 + 4*q];   // t cols j0-8..j0+23
                #pragma unroll
                for (int s1 = 0; s1 < 11; ++s1)
                    #pragma unroll
                    for (int c = 0; c < 16; ++c)
                        acc[j][s1] += x[c] * tv[c + 13 - s1];   // t[.][j0+c+5-s1]
            }
        }
    }
    int lane = tid & 63, wv = tid >> 6;
    #pragma unroll
    for (int j = 0; j < 3; ++j){
        #pragma unroll
        for (int s1 = 0; s1 < 11; ++s1){
            float v = acc[j][s1];
            v += __shfl_down(v, 32); v += __shfl_down(v, 16); v += __shfl_down(v, 8);
            v += __shfl_down(v, 4);  v += __shfl_down(v, 2);  v += __shfl_down(v, 1);
            if (lane == 0) wred[wv][j*11 + s1] = v;
        }
    }
    __syncthreads();
    if (tid < 121){
        int s0 = tid / 11, s1 = tid - s0*11;
        int sgo = s0 & 3, jj = s0 >> 2;
        partial[(size_t)(b*32 + chunk)*121 + tid] = wred[2*sgo][jj*11 + s1] + wred[2*sgo + 1][jj*11 + s1];
    }
}

// K4: ncc, argmax, log-parabola subpixel -> shifts (double), c2 coefficient
__global__ __launch_bounds__(128) void k_shifts(const float* __restrict__ partial, const double* __restrict__ den,
                                                const double* __restrict__ snn_part, double* __restrict__ shx,
                                                double* __restrict__ shy, float* __restrict__ c2){
    int b = blockIdx.x;
    __shared__ double l[121], nc[121];
    for (int e = threadIdx.x; e < 121; e += 128){
        double s = 0.0;
        for (int c = 0; c < 32; ++c) s += (double)partial[(size_t)(b*32 + c)*121 + e];
        double nom = fabs(s);
        double v = nom / den[b*121 + e];
        if (v != v) v = 0.0;
        nc[e] = v;
        l[e] = log(v);
    }
    __syncthreads();
    if (threadIdx.x == 0){
        int am = 0; double best = nc[0];
        for (int e = 1; e < 121; ++e) if (nc[e] > best){ best = nc[e]; am = e; }
        int u = am / 11, v = am % 11;
        double sx = -(double)(u - 5), sy = -(double)(v - 5);
        int um1 = u - 1; if (um1 < 0) um1 += 11; if (um1 > 10) um1 = 10;
        int up1 = u + 1; if (up1 > 10) up1 = 10;
        int vm1 = v - 1; if (vm1 < 0) vm1 += 11; if (vm1 > 10) vm1 = 10;
        int vp1 = v + 1; if (vp1 > 10) vp1 = 10;
        double l0x4 = 4.0 * l[u*11 + v];
        double lm = l[um1*11 + v], lp = l[up1*11 + v];
        sx -= (lm - lp) / (2.0*lm - l0x4 + 2.0*lp);
        double lm2 = l[u*11 + vm1], lp2 = l[u*11 + vp1];
        sy -= (lm2 - lp2) / (2.0*lm2 - l0x4 + 2.0*lp2);
        shx[b] = sx; shy[b] = sy;
        double snn = 0.0;
        for (int c = 0; c < 8; ++c) snn += snn_part[b*8 + c];
        double kx = sin(PI_D * sx) / 512.0, ky = sin(PI_D * sy) / 512.0;
        c2[b] = (float)(kx * ky * snn);
    }
}

__device__ inline double grekern(int t, double s){
    double u = (double)t - s;
    if (u > 256.0) u -= 512.0;
    double a = PI_D * u / 512.0;
    double sp = sin(a);
    double D;
    if (fabs(sp) < 1e-12) D = cos(PI_D * u) / cos(a);     // u ~ 0
    else D = sin(PI_D * u) / (512.0 * sp);
    return D * cos(a);
}

// K4b: real parts of the Dirichlet shift kernels (imag part handled analytically via c2)
__global__ __launch_bounds__(256) void k_tables(const double* __restrict__ shx, const double* __restrict__ shy,
                                                float* __restrict__ ary, float* __restrict__ arx){
    int b = blockIdx.x;
    double sx = shx[b], sy = shy[b];
    for (int t = threadIdx.x; t < 512; t += 256){
        arx[(b<<9) + t] = (float)grekern(t, sx);
        ary[(b<<9) + t] = (float)grekern(t, sy);
    }
}

// K5/K6: out[r][p] = sum_m in[r][m] * kern[(p-m)&511]   (real circulant matmul), optional parity correction
template<int CORR>
__global__ __launch_bounds__(256) void k_rowcirc(const float* __restrict__ src, int src_local,
                                                 const float* __restrict__ kern_all,
                                                 float* __restrict__ dst,
                                                 const float* __restrict__ c2, int c0){
    int lb = blockIdx.x >> 5, blk = blockIdx.x & 31;
    int b = c0 + lb;
    const float* in = src + (size_t)(src_local ? lb : b) * NPIX;
    const float* kern = kern_all + ((size_t)b << 9);
    float* out = dst + (size_t)b * NPIX;
    __shared__ float kd[1024];
    __shared__ float Xr[16][512];
    int r0 = blk << 4;
    for (int idx = threadIdx.x; idx < 1024; idx += 256) kd[idx] = kern[idx & 511];
    for (int idx = threadIdx.x; idx < 8192; idx += 256){
        int rr = idx >> 9;
        Xr[rr][idx & 511] = in[((size_t)(r0 + rr) << 9) + (idx & 511)];
    }
    __syncthreads();
    int rg = threadIdx.x >> 6;
    int p0 = (threadIdx.x & 63) << 3;
    float acc[4][8];
    #pragma unroll
    for (int a = 0; a < 4; ++a)
        #pragma unroll
        for (int c = 0; c < 8; ++c) acc[a][c] = 0.f;
    for (int m = 0; m < 512; m += 4){
        int base = p0 - m + 508;                  // 4-aligned, in [0,1012]
        float4 kq0 = *(const float4*)&kd[base];
        float4 kq1 = *(const float4*)&kd[base + 4];
        float4 kq2 = *(const float4*)&kd[base + 8];
        float kw[12] = {kq0.x,kq0.y,kq0.z,kq0.w, kq1.x,kq1.y,kq1.z,kq1.w, kq2.x,kq2.y,kq2.z,kq2.w};
        #pragma unroll
        for (int rr = 0; rr < 4; ++rr){
            float4 xv = *(const float4*)&Xr[rg*4 + rr][m];
            float xm[4] = {xv.x, xv.y, xv.z, xv.w};
            #pragma unroll
            for (int mi = 0; mi < 4; ++mi)
                #pragma unroll
                for (int pp = 0; pp < 8; ++pp)
                    acc[rr][pp] += xm[mi] * kw[pp + 4 - mi];
        }
    }
    float cc = CORR ? c2[b] : 0.f;
    #pragma unroll
    for (int rr = 0; rr < 4; ++rr){
        int q = r0 + rg*4 + rr;
        float vals[8];
        #pragma unroll
        for (int pp = 0; pp < 8; ++pp){
            float v = acc[rr][pp];
            if (CORR){
                int p = p0 + pp;
                v -= ((q + p) & 1) ? -cc : cc;    // out -= c2 * (-1)^(p+q)
            }
            vals[pp] = v;
        }
        float4 o0 = {vals[0], vals[1], vals[2], vals[3]};
        float4 o1 = {vals[4], vals[5], vals[6], vals[7]};
        *(float4*)&out[((size_t)q << 9) + p0] = o0;
        *(float4*)&out[((size_t)q << 9) + p0 + 4] = o1;
    }
}

// transpose 512x512 (YRe in d_out -> YT in ws)
__global__ __launch_bounds__(256) void k_transpose(const float* __restrict__ in, float* __restrict__ out, int c0){
    int lb = blockIdx.x >> 8, tb = blockIdx.x & 255;
    int b = c0 + lb;
    int tx = (tb & 15) << 5, ty = ((tb >> 4) & 15) << 5;
    const float* src = in + (size_t)b * NPIX;
    float* dst = out + (size_t)lb * NPIX;
    __shared__ float tile[32][33];
    int col = threadIdx.x & 31, rw = threadIdx.x >> 5;
    #pragma unroll
    for (int k = 0; k < 4; ++k){
        int ry = rw + k*8;
        tile[ry][col] = src[((size_t)(ty + ry) << 9) + tx + col];
    }
    __syncthreads();
    #pragma unroll
    for (int k = 0; k < 4; ++k){
        int ry = rw + k*8;
        dst[((size_t)(tx + ry) << 9) + ty + col] = tile[col][ry];
    }
}

extern "C" void kernel_launch(void* const* d_in, const int* in_sizes, int n_in,
                              void* d_out, int out_size, void* d_ws, size_t ws_size,
                              hipStream_t stream){
    (void)in_sizes; (void)n_in; (void)out_size;
    const float* fr  = (const float*)d_in[0];   // (1,32,512,512,1) f32
    const float* tpl = (const float*)d_in[1];   // (512,512) f32
    float* out = (float*)d_out;                 // (32, 512*512) f32
    char* ws = (char*)d_ws;

    double* stats  = (double*)(ws + 0);
    double* spart  = (double*)(ws + 64);
    double* den    = (double*)(ws + 2048);
    double* snnp   = (double*)(ws + 33280);
    double* shx    = (double*)(ws + 35328);
    double* shy    = (double*)(ws + 35584);
    float*  c2     = (float*) (ws + 35840);
    float*  part   = (float*) (ws + 36096);
    float*  ary    = (float*) (ws + 532480);
    float*  arx    = (float*) (ws + 598016);
    float*  csum   = (float*) (ws + 663552);
    float*  csum2  = (float*) (ws + 1187840);
    float*  yt     = (float*) (ws + 2097152);

    long long ytcap = ((long long)ws_size - 2097152) / ((long long)NPIX * 4);
    int cb = (int)ytcap; if (cb > 32) cb = 32; if (cb < 1) cb = 1;

    k_stats_part<<<64, 256, 0, stream>>>(tpl, spart);
    k_stats_final<<<1, 64, 0, stream>>>(spart, stats);
    k_colsums<<<256, 256, 0, stream>>>(fr, csum, csum2, snnp);
    k_winfin<<<32, 256, 0, stream>>>(fr, csum, csum2, stats, den);
    k_ncc<<<1024, 512, 0, stream>>>(fr, tpl, stats, part);
    k_shifts<<<32, 128, 0, stream>>>(part, den, snnp, shx, shy, c2);
    k_tables<<<32, 256, 0, stream>>>(shx, shy, ary, arx);

    for (int c0 = 0; c0 < 32; c0 += cb){
        int nb = (32 - c0 < cb) ? (32 - c0) : cb;
        // stage 1: YRe[m][q] = sum_n x[m][n] * gyRe[(q-n)&511]   (stored in d_out region of batch)
        k_rowcirc<0><<<nb*32, 256, 0, stream>>>(fr, 0, ary, out, (const float*)nullptr, c0);
        // transpose YRe -> YT
        k_transpose<<<nb*256, 256, 0, stream>>>(out, yt, c0);
        // stage 2: out[q*512+p] = sum_m YT[q][m] * gxRe[(p-m)&511]  - c2*(-1)^(p+q)
        k_rowcirc<1><<<nb*32, 256, 0, stream>>>(yt, 1, arx, out, c2, c0);
    }
}

// Round 7
// 359.250 us; speedup vs baseline: 1.7526x; 1.0156x over previous
//
#include <hip/hip_runtime.h>
#include <hip/hip_bf16.h>
#include <math.h>

#define NPIX 262144          // 512*512
#define PI_D 3.14159265358979323846264338327950288

// ---------------- ws layout (byte offsets) ----------------
// 0       : double stats[2]            (mean_t, template_var)
// 64      : double spart[64][2]
// 2048    : double den[32][121]
// 33280   : double snn_part[32][8]
// 35328   : double shx[32]
// 35584   : double shy[32]
// 35840   : float  c2[32]
// 36096   : float  partial[32][32][121]   (495,616 B)
// 532480  : float  ary[32][512]
// 598016  : float  arx[32][512]
// 663552  : float  csum[32][8][512]
// 1187840 : float  csum2[32][8][512]
// 2097152 : float  yt[cb][512][512]

// K1a: template partial sums (64 blocks, float4 loads, double accum)
__global__ __launch_bounds__(256) void k_stats_part(const float* __restrict__ t, double* __restrict__ part){
    int base = blockIdx.x * 4096;
    double s = 0.0, s2 = 0.0;
    #pragma unroll
    for (int k = 0; k < 4; ++k){
        float4 v = *(const float4*)&t[base + k*1024 + threadIdx.x*4];
        s  += (double)v.x + (double)v.y + (double)v.z + (double)v.w;
        s2 += (double)v.x*v.x + (double)v.y*v.y + (double)v.z*v.z + (double)v.w*v.w;
    }
    __shared__ double rs[256], rs2[256];
    rs[threadIdx.x] = s; rs2[threadIdx.x] = s2; __syncthreads();
    for (int off = 128; off > 0; off >>= 1){
        if (threadIdx.x < off){ rs[threadIdx.x] += rs[threadIdx.x+off]; rs2[threadIdx.x] += rs2[threadIdx.x+off]; }
        __syncthreads();
    }
    if (threadIdx.x == 0){ part[blockIdx.x*2] = rs[0]; part[blockIdx.x*2+1] = rs2[0]; }
}

// K1b: finalize template stats
__global__ __launch_bounds__(64) void k_stats_final(const double* __restrict__ part, double* __restrict__ stats){
    double s = part[threadIdx.x*2], s2 = part[threadIdx.x*2+1];
    #pragma unroll
    for (int off = 32; off > 0; off >>= 1){
        s  += __shfl_down(s, off);
        s2 += __shfl_down(s2, off);
    }
    if (threadIdx.x == 0){
        stats[0] = s / (double)NPIX;
        stats[1] = s2 - s*s/(double)NPIX + 1e-8;
    }
}

// K2a: per-chunk column sums (+squares) over 64 rows, fused with Nyquist alternating sum
__global__ __launch_bounds__(256) void k_colsums(const float* __restrict__ fr, float* __restrict__ csum,
                                                 float* __restrict__ csum2, double* __restrict__ snn_part){
    int b = blockIdx.x >> 3, chunk = blockIdx.x & 7;
    const float* img = fr + (size_t)b * NPIX + (size_t)chunk * (64*512);
    int t = threadIdx.x;
    float a0=0.f, q0=0.f, a1=0.f, q1=0.f;
    double sn = 0.0;
    for (int r = 0; r < 64; ++r){
        float v0 = img[(r<<9) + t];
        float v1 = img[(r<<9) + t + 256];
        a0 += v0; q0 += v0*v0; a1 += v1; q1 += v1*v1;
        float sv = v0 + v1;                         // cols t and t+256 share parity
        sn += ((r + t) & 1) ? -(double)sv : (double)sv;   // (-1)^(row+col), chunk*64 even
    }
    size_t o = ((size_t)(b*8 + chunk) << 9) + t;
    csum[o] = a0;  csum[o + 256] = a1;
    csum2[o] = q0; csum2[o + 256] = q1;
    __shared__ double rs[256];
    rs[t] = sn; __syncthreads();
    for (int off = 128; off > 0; off >>= 1){
        if (t < off) rs[t] += rs[t+off];
        __syncthreads();
    }
    if (t == 0) snn_part[b*8 + chunk] = rs[0];
}

// K2b: finalize 121 window denominators per image from column sums + edges
__global__ __launch_bounds__(256) void k_winfin(const float* __restrict__ fr, const float* __restrict__ csum,
                                                const float* __restrict__ csum2, const double* __restrict__ stats,
                                                double* __restrict__ den){
    int b = blockIdx.x;
    const float* img = fr + (size_t)b * NPIX;
    __shared__ double fc[512], fc2[512];
    __shared__ double rsum[20], rsum2[20];
    __shared__ float E[20][20], E2[20][20];
    __shared__ double red[256], red2[256];
    int t = threadIdx.x;
    for (int c = t; c < 512; c += 256){
        double s = 0.0, s2 = 0.0;
        for (int k = 0; k < 8; ++k){
            size_t o = ((size_t)(b*8 + k) << 9) + c;
            s += (double)csum[o]; s2 += (double)csum2[o];
        }
        fc[c] = s; fc2[c] = s2;
    }
    if (t < 400){
        int i = t / 20, j = t % 20;
        int row = (i < 10) ? i : (i + 492);    // rows 0..9, 502..511
        int col = (j < 10) ? j : (j + 492);
        float v = img[(row<<9) + col];
        E[i][j] = v; E2[i][j] = v*v;
    }
    __syncthreads();
    red[t] = fc[t] + fc[t+256];
    red2[t] = fc2[t] + fc2[t+256];
    __syncthreads();
    for (int off = 128; off > 0; off >>= 1){
        if (t < off){ red[t] += red[t+off]; red2[t] += red2[t+off]; }
        __syncthreads();
    }
    double F1 = red[0], F2 = red2[0];
    int lane = t & 63, wv = t >> 6;
    for (int e = wv; e < 20; e += 4){
        int row = (e < 10) ? e : (e + 492);
        double s = 0.0, s2 = 0.0;
        for (int c = lane; c < 512; c += 64){
            float v = img[(row<<9) + c];
            s += v; s2 += (double)v*v;
        }
        #pragma unroll
        for (int off = 32; off > 0; off >>= 1){ s += __shfl_down(s, off); s2 += __shfl_down(s2, off); }
        if (lane == 0){ rsum[e] = s; rsum2[e] = s2; }
    }
    __syncthreads();
    if (t < 121){
        int u = t / 11, v = t % 11;
        double S1 = F1, S2 = F2;
        for (int i = 0; i < u; ++i){ S1 -= rsum[i]; S2 -= rsum2[i]; }          // excluded top rows 0..u-1
        for (int k = 10+u; k < 20; ++k){ S1 -= rsum[k]; S2 -= rsum2[k]; }      // excluded bottom rows u+502..511
        for (int j = 0; j < v; ++j){                                           // excluded left cols, minus corners
            double cw = fc[j], cq = fc2[j];
            for (int i = 0; i < u; ++i){ cw -= E[i][j]; cq -= E2[i][j]; }
            for (int k = 10+u; k < 20; ++k){ cw -= E[k][j]; cq -= E2[k][j]; }
            S1 -= cw; S2 -= cq;
        }
        for (int jj = 10+v; jj < 20; ++jj){                                    // excluded right cols v+502..511
            int col = jj + 492;
            double cw = fc[col], cq = fc2[col];
            for (int i = 0; i < u; ++i){ cw -= E[i][jj]; cq -= E2[i][jj]; }
            for (int k = 10+u; k < 20; ++k){ cw -= E[k][jj]; cq -= E2[k][jj]; }
            S1 -= cw; S2 -= cq;
        }
        const double K = 502.0*502.0;
        double ivar = S2/K - (S1*S1)/(K*K*K) + 1e-8;
        if (ivar < 0.0) ivar = 0.0;
        den[b*121 + u*11 + v] = sqrt(stats[1] * ivar);
    }
}

// K3: direct shifted cross-correlation, 121 shifts, shift-split across waves.
// Block = 512 threads = (4 row-lanes rg) x (32 col-groups cg of 16 cols) x (4 shift-groups sg).
// Each thread accumulates only acc[3][11] (s0 = sg+4j) -> ~85 live VGPRs, NO spill
// (R4/R5 lesson: 121 accumulators/thread forced scratch spill = 350-850 MB HBM writes).
__global__ __launch_bounds__(512, 2) void k_ncc(const float* __restrict__ fr, const float* __restrict__ tpl,
                                                const double* __restrict__ stats, float* __restrict__ partial){
    int b = blockIdx.x >> 5, chunk = blockIdx.x & 31;
    const float* img = fr + (size_t)b * NPIX;
    float mean = (float)stats[0];
    __shared__ float tr[26][548];      // template rows i0-5 .. i0+20, halo'd cols -16..527
    __shared__ float wred[8][33];
    int i0 = chunk << 4;
    int tid = threadIdx.x;
    for (int idx = tid; idx < 26*544; idx += 512){
        int r = idx / 544, k = idx - r*544;
        tr[r][k] = tpl[(((i0 - 5 + r + 512) & 511) << 9) | ((k - 16) & 511)] - mean;
    }
    __syncthreads();
    int rg = tid & 3;                  // row-lane
    int cg = (tid >> 2) & 31;          // col-group (16 cols)
    int sg = tid >> 7;                 // shift-group: s0 in {sg, sg+4, sg+8}
    int j0 = cg << 4;
    float acc[3][11];
    #pragma unroll
    for (int j = 0; j < 3; ++j)
        #pragma unroll
        for (int s1 = 0; s1 < 11; ++s1) acc[j][s1] = 0.f;
    #pragma unroll 1
    for (int k = 0; k < 4; ++k){
        int i = i0 + 4*k + rg;         // 0..511, no wrap
        float x[16];
        #pragma unroll
        for (int q = 0; q < 4; ++q)
            *(float4*)&x[4*q] = *(const float4*)&img[(i<<9) + j0 + 4*q];
        #pragma unroll
        for (int j = 0; j < 3; ++j){
            int s0 = sg + 4*j;
            if (s0 < 11){              // wave-uniform guard (sg=3,j=2 idles)
                const float* trow = tr[4*k + rg + 10 - s0];   // row i+5-s0, tile-relative
                float tv[32];
                #pragma unroll
                for (int q = 0; q < 8; ++q)
                    *(float4*)&tv[4*q] = *(const float4*)&trow[j0 + 8 + 4*q];   // t cols j0-8..j0+23
                #pragma unroll
                for (int s1 = 0; s1 < 11; ++s1)
                    #pragma unroll
                    for (int c = 0; c < 16; ++c)
                        acc[j][s1] += x[c] * tv[c + 13 - s1];   // t[.][j0+c+5-s1]
            }
        }
    }
    int lane = tid & 63, wv = tid >> 6;
    #pragma unroll
    for (int j = 0; j < 3; ++j){
        #pragma unroll
        for (int s1 = 0; s1 < 11; ++s1){
            float v = acc[j][s1];
            v += __shfl_down(v, 32); v += __shfl_down(v, 16); v += __shfl_down(v, 8);
            v += __shfl_down(v, 4);  v += __shfl_down(v, 2);  v += __shfl_down(v, 1);
            if (lane == 0) wred[wv][j*11 + s1] = v;
        }
    }
    __syncthreads();
    if (tid < 121){
        int s0 = tid / 11, s1 = tid - s0*11;
        int sgo = s0 & 3, jj = s0 >> 2;
        partial[(size_t)(b*32 + chunk)*121 + tid] = wred[2*sgo][jj*11 + s1] + wred[2*sgo + 1][jj*11 + s1];
    }
}

// K4: ncc, argmax, log-parabola subpixel -> shifts (double), c2 coefficient
__global__ __launch_bounds__(128) void k_shifts(const float* __restrict__ partial, const double* __restrict__ den,
                                                const double* __restrict__ snn_part, double* __restrict__ shx,
                                                double* __restrict__ shy, float* __restrict__ c2){
    int b = blockIdx.x;
    __shared__ double l[121], nc[121];
    for (int e = threadIdx.x; e < 121; e += 128){
        double s = 0.0;
        for (int c = 0; c < 32; ++c) s += (double)partial[(size_t)(b*32 + c)*121 + e];
        double nom = fabs(s);
        double v = nom / den[b*121 + e];
        if (v != v) v = 0.0;
        nc[e] = v;
        l[e] = log(v);
    }
    __syncthreads();
    if (threadIdx.x == 0){
        int am = 0; double best = nc[0];
        for (int e = 1; e < 121; ++e) if (nc[e] > best){ best = nc[e]; am = e; }
        int u = am / 11, v = am % 11;
        double sx = -(double)(u - 5), sy = -(double)(v - 5);
        int um1 = u - 1; if (um1 < 0) um1 += 11; if (um1 > 10) um1 = 10;
        int up1 = u + 1; if (up1 > 10) up1 = 10;
        int vm1 = v - 1; if (vm1 < 0) vm1 += 11; if (vm1 > 10) vm1 = 10;
        int vp1 = v + 1; if (vp1 > 10) vp1 = 10;
        double l0x4 = 4.0 * l[u*11 + v];
        double lm = l[um1*11 + v], lp = l[up1*11 + v];
        sx -= (lm - lp) / (2.0*lm - l0x4 + 2.0*lp);
        double lm2 = l[u*11 + vm1], lp2 = l[u*11 + vp1];
        sy -= (lm2 - lp2) / (2.0*lm2 - l0x4 + 2.0*lp2);
        shx[b] = sx; shy[b] = sy;
        double snn = 0.0;
        for (int c = 0; c < 8; ++c) snn += snn_part[b*8 + c];
        double kx = sin(PI_D * sx) / 512.0, ky = sin(PI_D * sy) / 512.0;
        c2[b] = (float)(kx * ky * snn);
    }
}

__device__ inline double grekern(int t, double s){
    double u = (double)t - s;
    if (u > 256.0) u -= 512.0;
    double a = PI_D * u / 512.0;
    double sp = sin(a);
    double D;
    if (fabs(sp) < 1e-12) D = cos(PI_D * u) / cos(a);     // u ~ 0
    else D = sin(PI_D * u) / (512.0 * sp);
    return D * cos(a);
}

// K4b: real parts of the Dirichlet shift kernels (imag part handled analytically via c2)
__global__ __launch_bounds__(256) void k_tables(const double* __restrict__ shx, const double* __restrict__ shy,
                                                float* __restrict__ ary, float* __restrict__ arx){
    int b = blockIdx.x;
    double sx = shx[b], sy = shy[b];
    for (int t = threadIdx.x; t < 512; t += 256){
        arx[(b<<9) + t] = (float)grekern(t, sx);
        ary[(b<<9) + t] = (float)grekern(t, sy);
    }
}

// XOR swizzle for kd[]: spreads quad-slot s across bank-groups (s mod 8) by XORing
// with (s/8) mod 8. Kills the 16-way conflict of lane-stride-8 float4 reads
// (residual: lanes 32 apart share a bank 2-way, which is free). Keeps 4-float alignment.
__device__ inline int kswz(int i){ return i ^ (((i >> 5) & 7) << 2); }

// K5/K6: out[r][p] = sum_m in[r][m] * kern[(p-m)&511]   (real circulant matmul), optional parity correction
template<int CORR>
__global__ __launch_bounds__(256) void k_rowcirc(const float* __restrict__ src, int src_local,
                                                 const float* __restrict__ kern_all,
                                                 float* __restrict__ dst,
                                                 const float* __restrict__ c2, int c0){
    int lb = blockIdx.x >> 5, blk = blockIdx.x & 31;
    int b = c0 + lb;
    const float* in = src + (size_t)(src_local ? lb : b) * NPIX;
    const float* kern = kern_all + ((size_t)b << 9);
    float* out = dst + (size_t)b * NPIX;
    __shared__ float kd[1024];
    __shared__ float Xr[16][512];
    int r0 = blk << 4;
    for (int idx = threadIdx.x; idx < 1024; idx += 256) kd[kswz(idx)] = kern[idx & 511];
    for (int idx = threadIdx.x; idx < 8192; idx += 256){
        int rr = idx >> 9;
        Xr[rr][idx & 511] = in[((size_t)(r0 + rr) << 9) + (idx & 511)];
    }
    __syncthreads();
    int rg = threadIdx.x >> 6;
    int p0 = (threadIdx.x & 63) << 3;
    float acc[4][8];
    #pragma unroll
    for (int a = 0; a < 4; ++a)
        #pragma unroll
        for (int c = 0; c < 8; ++c) acc[a][c] = 0.f;
    for (int m = 0; m < 512; m += 4){
        int base = p0 - m + 508;                  // 4-aligned, in [0,1012]
        float4 kq0 = *(const float4*)&kd[kswz(base)];
        float4 kq1 = *(const float4*)&kd[kswz(base + 4)];
        float4 kq2 = *(const float4*)&kd[kswz(base + 8)];
        float kw[12] = {kq0.x,kq0.y,kq0.z,kq0.w, kq1.x,kq1.y,kq1.z,kq1.w, kq2.x,kq2.y,kq2.z,kq2.w};
        #pragma unroll
        for (int rr = 0; rr < 4; ++rr){
            float4 xv = *(const float4*)&Xr[rg*4 + rr][m];
            float xm[4] = {xv.x, xv.y, xv.z, xv.w};
            #pragma unroll
            for (int mi = 0; mi < 4; ++mi)
                #pragma unroll
                for (int pp = 0; pp < 8; ++pp)
                    acc[rr][pp] += xm[mi] * kw[pp + 4 - mi];
        }
    }
    float cc = CORR ? c2[b] : 0.f;
    #pragma unroll
    for (int rr = 0; rr < 4; ++rr){
        int q = r0 + rg*4 + rr;
        float vals[8];
        #pragma unroll
        for (int pp = 0; pp < 8; ++pp){
            float v = acc[rr][pp];
            if (CORR){
                int p = p0 + pp;
                v -= ((q + p) & 1) ? -cc : cc;    // out -= c2 * (-1)^(p+q)
            }
            vals[pp] = v;
        }
        float4 o0 = {vals[0], vals[1], vals[2], vals[3]};
        float4 o1 = {vals[4], vals[5], vals[6], vals[7]};
        *(float4*)&out[((size_t)q << 9) + p0] = o0;
        *(float4*)&out[((size_t)q << 9) + p0 + 4] = o1;
    }
}

// transpose 512x512 (YRe in d_out -> YT in ws)
__global__ __launch_bounds__(256) void k_transpose(const float* __restrict__ in, float* __restrict__ out, int c0){
    int lb = blockIdx.x >> 8, tb = blockIdx.x & 255;
    int b = c0 + lb;
    int tx = (tb & 15) << 5, ty = ((tb >> 4) & 15) << 5;
    const float* src = in + (size_t)b * NPIX;
    float* dst = out + (size_t)lb * NPIX;
    __shared__ float tile[32][33];
    int col = threadIdx.x & 31, rw = threadIdx.x >> 5;
    #pragma unroll
    for (int k = 0; k < 4; ++k){
        int ry = rw + k*8;
        tile[ry][col] = src[((size_t)(ty + ry) << 9) + tx + col];
    }
    __syncthreads();
    #pragma unroll
    for (int k = 0; k < 4; ++k){
        int ry = rw + k*8;
        dst[((size_t)(tx + ry) << 9) + ty + col] = tile[col][ry];
    }
}

extern "C" void kernel_launch(void* const* d_in, const int* in_sizes, int n_in,
                              void* d_out, int out_size, void* d_ws, size_t ws_size,
                              hipStream_t stream){
    (void)in_sizes; (void)n_in; (void)out_size;
    const float* fr  = (const float*)d_in[0];   // (1,32,512,512,1) f32
    const float* tpl = (const float*)d_in[1];   // (512,512) f32
    float* out = (float*)d_out;                 // (32, 512*512) f32
    char* ws = (char*)d_ws;

    double* stats  = (double*)(ws + 0);
    double* spart  = (double*)(ws + 64);
    double* den    = (double*)(ws + 2048);
    double* snnp   = (double*)(ws + 33280);
    double* shx    = (double*)(ws + 35328);
    double* shy    = (double*)(ws + 35584);
    float*  c2     = (float*) (ws + 35840);
    float*  part   = (float*) (ws + 36096);
    float*  ary    = (float*) (ws + 532480);
    float*  arx    = (float*) (ws + 598016);
    float*  csum   = (float*) (ws + 663552);
    float*  csum2  = (float*) (ws + 1187840);
    float*  yt     = (float*) (ws + 2097152);

    long long ytcap = ((long long)ws_size - 2097152) / ((long long)NPIX * 4);
    int cb = (int)ytcap; if (cb > 32) cb = 32; if (cb < 1) cb = 1;

    k_stats_part<<<64, 256, 0, stream>>>(tpl, spart);
    k_stats_final<<<1, 64, 0, stream>>>(spart, stats);
    k_colsums<<<256, 256, 0, stream>>>(fr, csum, csum2, snnp);
    k_winfin<<<32, 256, 0, stream>>>(fr, csum, csum2, stats, den);
    k_ncc<<<1024, 512, 0, stream>>>(fr, tpl, stats, part);
    k_shifts<<<32, 128, 0, stream>>>(part, den, snnp, shx, shy, c2);
    k_tables<<<32, 256, 0, stream>>>(shx, shy, ary, arx);

    for (int c0 = 0; c0 < 32; c0 += cb){
        int nb = (32 - c0 < cb) ? (32 - c0) : cb;
        // stage 1: YRe[m][q] = sum_n x[m][n] * gyRe[(q-n)&511]   (stored in d_out region of batch)
        k_rowcirc<0><<<nb*32, 256, 0, stream>>>(fr, 0, ary, out, (const float*)nullptr, c0);
        // transpose YRe -> YT
        k_transpose<<<nb*256, 256, 0, stream>>>(out, yt, c0);
        // stage 2: out[q*512+p] = sum_m YT[q][m] * gxRe[(p-m)&511]  - c2*(-1)^(p+q)
        k_rowcirc<1><<<nb*32, 256, 0, stream>>>(yt, 1, arx, out, c2, c0);
    }
}

// Round 8
// 345.679 us; speedup vs baseline: 1.8214x; 1.0393x over previous
//
#include <hip/hip_runtime.h>
#include <hip/hip_bf16.h>
#include <math.h>

#define NPIX 262144          // 512*512
#define PI_D 3.14159265358979323846264338327950288

// ---------------- ws layout (byte offsets) ----------------
// 0       : double stats[2]            (mean_t, template_var)
// 64      : double spart[64][2]
// 2048    : double den[32][121]
// 33280   : double snn_part[32][8]
// 35328   : double shx[32]
// 35584   : double shy[32]
// 35840   : float  c2[32]
// 36096   : float  partial[32][32][121]   (495,616 B)
// 532480  : float  ary[32][512]
// 598016  : float  arx[32][512]
// 663552  : float  csum[32][8][512]
// 1187840 : float  csum2[32][8][512]
// 2097152 : float  yt[cb][512][512]

// K1a: template partial sums (64 blocks, float4 loads, double accum)
__global__ __launch_bounds__(256) void k_stats_part(const float* __restrict__ t, double* __restrict__ part){
    int base = blockIdx.x * 4096;
    double s = 0.0, s2 = 0.0;
    #pragma unroll
    for (int k = 0; k < 4; ++k){
        float4 v = *(const float4*)&t[base + k*1024 + threadIdx.x*4];
        s  += (double)v.x + (double)v.y + (double)v.z + (double)v.w;
        s2 += (double)v.x*v.x + (double)v.y*v.y + (double)v.z*v.z + (double)v.w*v.w;
    }
    __shared__ double rs[256], rs2[256];
    rs[threadIdx.x] = s; rs2[threadIdx.x] = s2; __syncthreads();
    for (int off = 128; off > 0; off >>= 1){
        if (threadIdx.x < off){ rs[threadIdx.x] += rs[threadIdx.x+off]; rs2[threadIdx.x] += rs2[threadIdx.x+off]; }
        __syncthreads();
    }
    if (threadIdx.x == 0){ part[blockIdx.x*2] = rs[0]; part[blockIdx.x*2+1] = rs2[0]; }
}

// K1b: finalize template stats
__global__ __launch_bounds__(64) void k_stats_final(const double* __restrict__ part, double* __restrict__ stats){
    double s = part[threadIdx.x*2], s2 = part[threadIdx.x*2+1];
    #pragma unroll
    for (int off = 32; off > 0; off >>= 1){
        s  += __shfl_down(s, off);
        s2 += __shfl_down(s2, off);
    }
    if (threadIdx.x == 0){
        stats[0] = s / (double)NPIX;
        stats[1] = s2 - s*s/(double)NPIX + 1e-8;
    }
}

// K2a: per-chunk column sums (+squares) over 64 rows, fused with Nyquist alternating sum
__global__ __launch_bounds__(256) void k_colsums(const float* __restrict__ fr, float* __restrict__ csum,
                                                 float* __restrict__ csum2, double* __restrict__ snn_part){
    int b = blockIdx.x >> 3, chunk = blockIdx.x & 7;
    const float* img = fr + (size_t)b * NPIX + (size_t)chunk * (64*512);
    int t = threadIdx.x;
    float a0=0.f, q0=0.f, a1=0.f, q1=0.f;
    double sn = 0.0;
    for (int r = 0; r < 64; ++r){
        float v0 = img[(r<<9) + t];
        float v1 = img[(r<<9) + t + 256];
        a0 += v0; q0 += v0*v0; a1 += v1; q1 += v1*v1;
        float sv = v0 + v1;                         // cols t and t+256 share parity
        sn += ((r + t) & 1) ? -(double)sv : (double)sv;   // (-1)^(row+col), chunk*64 even
    }
    size_t o = ((size_t)(b*8 + chunk) << 9) + t;
    csum[o] = a0;  csum[o + 256] = a1;
    csum2[o] = q0; csum2[o + 256] = q1;
    __shared__ double rs[256];
    rs[t] = sn; __syncthreads();
    for (int off = 128; off > 0; off >>= 1){
        if (t < off) rs[t] += rs[t+off];
        __syncthreads();
    }
    if (t == 0) snn_part[b*8 + chunk] = rs[0];
}

// K2b: finalize 121 window denominators per image from column sums + edges
__global__ __launch_bounds__(256) void k_winfin(const float* __restrict__ fr, const float* __restrict__ csum,
                                                const float* __restrict__ csum2, const double* __restrict__ stats,
                                                double* __restrict__ den){
    int b = blockIdx.x;
    const float* img = fr + (size_t)b * NPIX;
    __shared__ double fc[512], fc2[512];
    __shared__ double rsum[20], rsum2[20];
    __shared__ float E[20][20], E2[20][20];
    __shared__ double red[256], red2[256];
    int t = threadIdx.x;
    for (int c = t; c < 512; c += 256){
        double s = 0.0, s2 = 0.0;
        for (int k = 0; k < 8; ++k){
            size_t o = ((size_t)(b*8 + k) << 9) + c;
            s += (double)csum[o]; s2 += (double)csum2[o];
        }
        fc[c] = s; fc2[c] = s2;
    }
    if (t < 400){
        int i = t / 20, j = t % 20;
        int row = (i < 10) ? i : (i + 492);    // rows 0..9, 502..511
        int col = (j < 10) ? j : (j + 492);
        float v = img[(row<<9) + col];
        E[i][j] = v; E2[i][j] = v*v;
    }
    __syncthreads();
    red[t] = fc[t] + fc[t+256];
    red2[t] = fc2[t] + fc2[t+256];
    __syncthreads();
    for (int off = 128; off > 0; off >>= 1){
        if (t < off){ red[t] += red[t+off]; red2[t] += red2[t+off]; }
        __syncthreads();
    }
    double F1 = red[0], F2 = red2[0];
    int lane = t & 63, wv = t >> 6;
    for (int e = wv; e < 20; e += 4){
        int row = (e < 10) ? e : (e + 492);
        double s = 0.0, s2 = 0.0;
        for (int c = lane; c < 512; c += 64){
            float v = img[(row<<9) + c];
            s += v; s2 += (double)v*v;
        }
        #pragma unroll
        for (int off = 32; off > 0; off >>= 1){ s += __shfl_down(s, off); s2 += __shfl_down(s2, off); }
        if (lane == 0){ rsum[e] = s; rsum2[e] = s2; }
    }
    __syncthreads();
    if (t < 121){
        int u = t / 11, v = t % 11;
        double S1 = F1, S2 = F2;
        for (int i = 0; i < u; ++i){ S1 -= rsum[i]; S2 -= rsum2[i]; }          // excluded top rows 0..u-1
        for (int k = 10+u; k < 20; ++k){ S1 -= rsum[k]; S2 -= rsum2[k]; }      // excluded bottom rows u+502..511
        for (int j = 0; j < v; ++j){                                           // excluded left cols, minus corners
            double cw = fc[j], cq = fc2[j];
            for (int i = 0; i < u; ++i){ cw -= E[i][j]; cq -= E2[i][j]; }
            for (int k = 10+u; k < 20; ++k){ cw -= E[k][j]; cq -= E2[k][j]; }
            S1 -= cw; S2 -= cq;
        }
        for (int jj = 10+v; jj < 20; ++jj){                                    // excluded right cols v+502..511
            int col = jj + 492;
            double cw = fc[col], cq = fc2[col];
            for (int i = 0; i < u; ++i){ cw -= E[i][jj]; cq -= E2[i][jj]; }
            for (int k = 10+u; k < 20; ++k){ cw -= E[k][jj]; cq -= E2[k][jj]; }
            S1 -= cw; S2 -= cq;
        }
        const double K = 502.0*502.0;
        double ivar = S2/K - (S1*S1)/(K*K*K) + 1e-8;
        if (ivar < 0.0) ivar = 0.0;
        den[b*121 + u*11 + v] = sqrt(stats[1] * ivar);
    }
}

// K3: direct shifted cross-correlation, 121 shifts, shift-split across waves.
// Block = 512 threads = (4 row-lanes rg) x (32 col-groups cg of 16 cols) x (4 shift-groups sg).
// Each thread accumulates only acc[3][11] (s0 = sg+4j) -> ~85 live VGPRs, NO spill
// (R4/R5 lesson: 121 accumulators/thread forced scratch spill = 350-850 MB HBM writes).
__global__ __launch_bounds__(512, 2) void k_ncc(const float* __restrict__ fr, const float* __restrict__ tpl,
                                                const double* __restrict__ stats, float* __restrict__ partial){
    int b = blockIdx.x >> 5, chunk = blockIdx.x & 31;
    const float* img = fr + (size_t)b * NPIX;
    float mean = (float)stats[0];
    __shared__ float tr[26][548];      // template rows i0-5 .. i0+20, halo'd cols -16..527
    __shared__ float wred[8][33];
    int i0 = chunk << 4;
    int tid = threadIdx.x;
    for (int idx = tid; idx < 26*544; idx += 512){
        int r = idx / 544, k = idx - r*544;
        tr[r][k] = tpl[(((i0 - 5 + r + 512) & 511) << 9) | ((k - 16) & 511)] - mean;
    }
    __syncthreads();
    int rg = tid & 3;                  // row-lane
    int cg = (tid >> 2) & 31;          // col-group (16 cols)
    int sg = tid >> 7;                 // shift-group: s0 in {sg, sg+4, sg+8}
    int j0 = cg << 4;
    float acc[3][11];
    #pragma unroll
    for (int j = 0; j < 3; ++j)
        #pragma unroll
        for (int s1 = 0; s1 < 11; ++s1) acc[j][s1] = 0.f;
    #pragma unroll 1
    for (int k = 0; k < 4; ++k){
        int i = i0 + 4*k + rg;         // 0..511, no wrap
        float x[16];
        #pragma unroll
        for (int q = 0; q < 4; ++q)
            *(float4*)&x[4*q] = *(const float4*)&img[(i<<9) + j0 + 4*q];
        #pragma unroll
        for (int j = 0; j < 3; ++j){
            int s0 = sg + 4*j;
            if (s0 < 11){              // wave-uniform guard (sg=3,j=2 idles)
                const float* trow = tr[4*k + rg + 10 - s0];   // row i+5-s0, tile-relative
                float tv[32];
                #pragma unroll
                for (int q = 0; q < 8; ++q)
                    *(float4*)&tv[4*q] = *(const float4*)&trow[j0 + 8 + 4*q];   // t cols j0-8..j0+23
                #pragma unroll
                for (int s1 = 0; s1 < 11; ++s1)
                    #pragma unroll
                    for (int c = 0; c < 16; ++c)
                        acc[j][s1] += x[c] * tv[c + 13 - s1];   // t[.][j0+c+5-s1]
            }
        }
    }
    int lane = tid & 63, wv = tid >> 6;
    #pragma unroll
    for (int j = 0; j < 3; ++j){
        #pragma unroll
        for (int s1 = 0; s1 < 11; ++s1){
            float v = acc[j][s1];
            v += __shfl_down(v, 32); v += __shfl_down(v, 16); v += __shfl_down(v, 8);
            v += __shfl_down(v, 4);  v += __shfl_down(v, 2);  v += __shfl_down(v, 1);
            if (lane == 0) wred[wv][j*11 + s1] = v;
        }
    }
    __syncthreads();
    if (tid < 121){
        int s0 = tid / 11, s1 = tid - s0*11;
        int sgo = s0 & 3, jj = s0 >> 2;
        partial[(size_t)(b*32 + chunk)*121 + tid] = wred[2*sgo][jj*11 + s1] + wred[2*sgo + 1][jj*11 + s1];
    }
}

// K4: ncc, argmax, log-parabola subpixel -> shifts (double), c2 coefficient
__global__ __launch_bounds__(128) void k_shifts(const float* __restrict__ partial, const double* __restrict__ den,
                                                const double* __restrict__ snn_part, double* __restrict__ shx,
                                                double* __restrict__ shy, float* __restrict__ c2){
    int b = blockIdx.x;
    __shared__ double l[121], nc[121];
    for (int e = threadIdx.x; e < 121; e += 128){
        double s = 0.0;
        for (int c = 0; c < 32; ++c) s += (double)partial[(size_t)(b*32 + c)*121 + e];
        double nom = fabs(s);
        double v = nom / den[b*121 + e];
        if (v != v) v = 0.0;
        nc[e] = v;
        l[e] = log(v);
    }
    __syncthreads();
    if (threadIdx.x == 0){
        int am = 0; double best = nc[0];
        for (int e = 1; e < 121; ++e) if (nc[e] > best){ best = nc[e]; am = e; }
        int u = am / 11, v = am % 11;
        double sx = -(double)(u - 5), sy = -(double)(v - 5);
        int um1 = u - 1; if (um1 < 0) um1 += 11; if (um1 > 10) um1 = 10;
        int up1 = u + 1; if (up1 > 10) up1 = 10;
        int vm1 = v - 1; if (vm1 < 0) vm1 += 11; if (vm1 > 10) vm1 = 10;
        int vp1 = v + 1; if (vp1 > 10) vp1 = 10;
        double l0x4 = 4.0 * l[u*11 + v];
        double lm = l[um1*11 + v], lp = l[up1*11 + v];
        sx -= (lm - lp) / (2.0*lm - l0x4 + 2.0*lp);
        double lm2 = l[u*11 + vm1], lp2 = l[u*11 + vp1];
        sy -= (lm2 - lp2) / (2.0*lm2 - l0x4 + 2.0*lp2);
        shx[b] = sx; shy[b] = sy;
        double snn = 0.0;
        for (int c = 0; c < 8; ++c) snn += snn_part[b*8 + c];
        double kx = sin(PI_D * sx) / 512.0, ky = sin(PI_D * sy) / 512.0;
        c2[b] = (float)(kx * ky * snn);
    }
}

__device__ inline double grekern(int t, double s){
    double u = (double)t - s;
    if (u > 256.0) u -= 512.0;
    double a = PI_D * u / 512.0;
    double sp = sin(a);
    double D;
    if (fabs(sp) < 1e-12) D = cos(PI_D * u) / cos(a);     // u ~ 0
    else D = sin(PI_D * u) / (512.0 * sp);
    return D * cos(a);
}

// K4b: real parts of the Dirichlet shift kernels (imag part handled analytically via c2)
__global__ __launch_bounds__(256) void k_tables(const double* __restrict__ shx, const double* __restrict__ shy,
                                                float* __restrict__ ary, float* __restrict__ arx){
    int b = blockIdx.x;
    double sx = shx[b], sy = shy[b];
    for (int t = threadIdx.x; t < 512; t += 256){
        arx[(b<<9) + t] = (float)grekern(t, sx);
        ary[(b<<9) + t] = (float)grekern(t, sy);
    }
}

// XOR swizzle on quad index (float4-granular): spreads quad s across bank groups.
__device__ inline int kswzq(int s){ return s ^ ((s >> 3) & 7); }          // quad -> quad
__device__ inline int kswz(int i){ return i ^ (((i >> 5) & 7) << 2); }    // float -> float (same map)

// K5/K6: out[r][p] = sum_m in[r][m] * kern[(p-m)&511]   (real circulant matmul), optional parity correction
// Sliding register window win[16] over kd: 2 kd reads per 8 m-steps (was 6) -> 3x fewer
// LDS reads + address ops. All win[] indices static after unroll (rule #20).
template<int CORR>
__global__ __launch_bounds__(256) void k_rowcirc(const float* __restrict__ src, int src_local,
                                                 const float* __restrict__ kern_all,
                                                 float* __restrict__ dst,
                                                 const float* __restrict__ c2, int c0){
    int lb = blockIdx.x >> 5, blk = blockIdx.x & 31;
    int b = c0 + lb;
    const float* in = src + (size_t)(src_local ? lb : b) * NPIX;
    const float* kern = kern_all + ((size_t)b << 9);
    float* out = dst + (size_t)b * NPIX;
    __shared__ float kd[1024];
    __shared__ float Xr[16][512];
    int r0 = blk << 4;
    // kd staging: one ds_write_b128 per thread, swizzled quad dest
    {
        int s = threadIdx.x;                       // quad 0..255
        *(float4*)&kd[4*kswzq(s)] = *(const float4*)&kern[(4*s) & 511];
    }
    // Xr staging: float4 loads (8 per thread)
    for (int idx = threadIdx.x; idx < 2048; idx += 256){
        int f = idx << 2;
        *(float4*)&Xr[f >> 9][f & 511] = *(const float4*)&in[((size_t)(r0 + (f >> 9)) << 9) + (f & 511)];
    }
    __syncthreads();
    int rg = threadIdx.x >> 6;
    int p0 = (threadIdx.x & 63) << 3;
    float acc[4][8];
    #pragma unroll
    for (int a = 0; a < 4; ++a)
        #pragma unroll
        for (int c = 0; c < 8; ++c) acc[a][c] = 0.f;
    // init window: win[k] = kd[bw + k], bw = p0 + 504  (covers kd[p0+504 .. p0+519])
    float win[16];
    {
        int bw = p0 + 504;
        #pragma unroll
        for (int q = 0; q < 4; ++q)
            *(float4*)&win[4*q] = *(const float4*)&kd[kswz(bw + 4*q)];
    }
    #pragma unroll 1
    for (int m = 0; m < 512; m += 8){
        // sub-step A (this m): kw[j] = kd[base + j] = win[4 + j],  base = p0 - m + 508 = bw + 4
        // sub-step B (m + 4):  kw[j] = kd[base-4+j] = win[j]
        #pragma unroll
        for (int h = 0; h < 2; ++h){
            int mm = m + 4*h;
            #pragma unroll
            for (int rr = 0; rr < 4; ++rr){
                float4 xv = *(const float4*)&Xr[rg*4 + rr][mm];
                float xm[4] = {xv.x, xv.y, xv.z, xv.w};
                #pragma unroll
                for (int mi = 0; mi < 4; ++mi)
                    #pragma unroll
                    for (int pp = 0; pp < 8; ++pp)
                        acc[rr][pp] += xm[mi] * win[(4 - 4*h) + pp + 4 - mi];
            }
        }
        // rotate window down 8 and refill low half: new win[k] = kd[bw-8 + k]
        if (m < 504){
            #pragma unroll
            for (int k = 15; k >= 8; --k) win[k] = win[k - 8];
            int bwn = p0 - m + 496;               // old bw - 8
            *(float4*)&win[0] = *(const float4*)&kd[kswz(bwn)];
            *(float4*)&win[4] = *(const float4*)&kd[kswz(bwn + 4)];
        }
    }
    float cc = CORR ? c2[b] : 0.f;
    #pragma unroll
    for (int rr = 0; rr < 4; ++rr){
        int q = r0 + rg*4 + rr;
        float vals[8];
        #pragma unroll
        for (int pp = 0; pp < 8; ++pp){
            float v = acc[rr][pp];
            if (CORR){
                int p = p0 + pp;
                v -= ((q + p) & 1) ? -cc : cc;    // out -= c2 * (-1)^(p+q)
            }
            vals[pp] = v;
        }
        float4 o0 = {vals[0], vals[1], vals[2], vals[3]};
        float4 o1 = {vals[4], vals[5], vals[6], vals[7]};
        *(float4*)&out[((size_t)q << 9) + p0] = o0;
        *(float4*)&out[((size_t)q << 9) + p0 + 4] = o1;
    }
}

// transpose 512x512 (YRe in d_out -> YT in ws)
__global__ __launch_bounds__(256) void k_transpose(const float* __restrict__ in, float* __restrict__ out, int c0){
    int lb = blockIdx.x >> 8, tb = blockIdx.x & 255;
    int b = c0 + lb;
    int tx = (tb & 15) << 5, ty = ((tb >> 4) & 15) << 5;
    const float* src = in + (size_t)b * NPIX;
    float* dst = out + (size_t)lb * NPIX;
    __shared__ float tile[32][33];
    int col = threadIdx.x & 31, rw = threadIdx.x >> 5;
    #pragma unroll
    for (int k = 0; k < 4; ++k){
        int ry = rw + k*8;
        tile[ry][col] = src[((size_t)(ty + ry) << 9) + tx + col];
    }
    __syncthreads();
    #pragma unroll
    for (int k = 0; k < 4; ++k){
        int ry = rw + k*8;
        dst[((size_t)(tx + ry) << 9) + ty + col] = tile[col][ry];
    }
}

extern "C" void kernel_launch(void* const* d_in, const int* in_sizes, int n_in,
                              void* d_out, int out_size, void* d_ws, size_t ws_size,
                              hipStream_t stream){
    (void)in_sizes; (void)n_in; (void)out_size;
    const float* fr  = (const float*)d_in[0];   // (1,32,512,512,1) f32
    const float* tpl = (const float*)d_in[1];   // (512,512) f32
    float* out = (float*)d_out;                 // (32, 512*512) f32
    char* ws = (char*)d_ws;

    double* stats  = (double*)(ws + 0);
    double* spart  = (double*)(ws + 64);
    double* den    = (double*)(ws + 2048);
    double* snnp   = (double*)(ws + 33280);
    double* shx    = (double*)(ws + 35328);
    double* shy    = (double*)(ws + 35584);
    float*  c2     = (float*) (ws + 35840);
    float*  part   = (float*) (ws + 36096);
    float*  ary    = (float*) (ws + 532480);
    float*  arx    = (float*) (ws + 598016);
    float*  csum   = (float*) (ws + 663552);
    float*  csum2  = (float*) (ws + 1187840);
    float*  yt     = (float*) (ws + 2097152);

    long long ytcap = ((long long)ws_size - 2097152) / ((long long)NPIX * 4);
    int cb = (int)ytcap; if (cb > 32) cb = 32; if (cb < 1) cb = 1;

    k_stats_part<<<64, 256, 0, stream>>>(tpl, spart);
    k_stats_final<<<1, 64, 0, stream>>>(spart, stats);
    k_colsums<<<256, 256, 0, stream>>>(fr, csum, csum2, snnp);
    k_winfin<<<32, 256, 0, stream>>>(fr, csum, csum2, stats, den);
    k_ncc<<<1024, 512, 0, stream>>>(fr, tpl, stats, part);
    k_shifts<<<32, 128, 0, stream>>>(part, den, snnp, shx, shy, c2);
    k_tables<<<32, 256, 0, stream>>>(shx, shy, ary, arx);

    for (int c0 = 0; c0 < 32; c0 += cb){
        int nb = (32 - c0 < cb) ? (32 - c0) : cb;
        // stage 1: YRe[m][q] = sum_n x[m][n] * gyRe[(q-n)&511]   (stored in d_out region of batch)
        k_rowcirc<0><<<nb*32, 256, 0, stream>>>(fr, 0, ary, out, (const float*)nullptr, c0);
        // transpose YRe -> YT
        k_transpose<<<nb*256, 256, 0, stream>>>(out, yt, c0);
        // stage 2: out[q*512+p] = sum_m YT[q][m] * gxRe[(p-m)&511]  - c2*(-1)^(p+q)
        k_rowcirc<1><<<nb*32, 256, 0, stream>>>(yt, 1, arx, out, c2, c0);
    }
}

// Round 9
// 261.818 us; speedup vs baseline: 2.4048x; 1.3203x over previous
//
#include <hip/hip_runtime.h>
#include <hip/hip_bf16.h>
#include <math.h>

#define NPIX 262144          // 512*512
#define PI_D 3.14159265358979323846264338327950288

typedef __attribute__((ext_vector_type(8))) short v8s;           // bf16x8 MFMA fragment
typedef __attribute__((ext_vector_type(4))) float v4f;           // f32x4 accumulator
typedef __attribute__((ext_vector_type(4))) unsigned short v4u;

// ---------------- ws layout (byte offsets) ----------------
// 0        double stats[2]
// 64       double spart[64][2]
// 2048     double den[32][121]
// 33280    double snn_part[32][8]
// 35328    double shx[32]
// 35584    double shy[32]
// 35840    float  c2[32]
// 36096    float  partial[32][32][121]      (495,616 B)
// 532480   ushort gtab[32][2 axis][2 pol][512]   (131,072 B)
// 663552   float  csum[32][8][512]
// 1187840  float  csum2[32][8][512]         (ends 1,712,128)
// 1720320  chunk area: per image 4 MB:
//          Xhi/Xlo/YThi/YTlo: NC*512KB each; Bym/Bxm: NC*1MB each

__device__ inline unsigned short f2bf(float x){
    unsigned u = __float_as_uint(x);
    return (unsigned short)((u + 0x7FFFu + ((u >> 16) & 1u)) >> 16);   // RNE
}
__device__ inline float bf2f(unsigned short h){ return __uint_as_float(((unsigned)h) << 16); }

// K1a: template partial sums
__global__ __launch_bounds__(256) void k_stats_part(const float* __restrict__ t, double* __restrict__ part){
    int base = blockIdx.x * 4096;
    double s = 0.0, s2 = 0.0;
    #pragma unroll
    for (int k = 0; k < 4; ++k){
        float4 v = *(const float4*)&t[base + k*1024 + threadIdx.x*4];
        s  += (double)v.x + (double)v.y + (double)v.z + (double)v.w;
        s2 += (double)v.x*v.x + (double)v.y*v.y + (double)v.z*v.z + (double)v.w*v.w;
    }
    __shared__ double rs[256], rs2[256];
    rs[threadIdx.x] = s; rs2[threadIdx.x] = s2; __syncthreads();
    for (int off = 128; off > 0; off >>= 1){
        if (threadIdx.x < off){ rs[threadIdx.x] += rs[threadIdx.x+off]; rs2[threadIdx.x] += rs2[threadIdx.x+off]; }
        __syncthreads();
    }
    if (threadIdx.x == 0){ part[blockIdx.x*2] = rs[0]; part[blockIdx.x*2+1] = rs2[0]; }
}

__global__ __launch_bounds__(64) void k_stats_final(const double* __restrict__ part, double* __restrict__ stats){
    double s = part[threadIdx.x*2], s2 = part[threadIdx.x*2+1];
    #pragma unroll
    for (int off = 32; off > 0; off >>= 1){
        s  += __shfl_down(s, off);
        s2 += __shfl_down(s2, off);
    }
    if (threadIdx.x == 0){
        stats[0] = s / (double)NPIX;
        stats[1] = s2 - s*s/(double)NPIX + 1e-8;
    }
}

// K2a: per-chunk column sums + Nyquist alternating sum
__global__ __launch_bounds__(256) void k_colsums(const float* __restrict__ fr, float* __restrict__ csum,
                                                 float* __restrict__ csum2, double* __restrict__ snn_part){
    int b = blockIdx.x >> 3, chunk = blockIdx.x & 7;
    const float* img = fr + (size_t)b * NPIX + (size_t)chunk * (64*512);
    int t = threadIdx.x;
    float a0=0.f, q0=0.f, a1=0.f, q1=0.f;
    double sn = 0.0;
    for (int r = 0; r < 64; ++r){
        float v0 = img[(r<<9) + t];
        float v1 = img[(r<<9) + t + 256];
        a0 += v0; q0 += v0*v0; a1 += v1; q1 += v1*v1;
        float sv = v0 + v1;
        sn += ((r + t) & 1) ? -(double)sv : (double)sv;
    }
    size_t o = ((size_t)(b*8 + chunk) << 9) + t;
    csum[o] = a0;  csum[o + 256] = a1;
    csum2[o] = q0; csum2[o + 256] = q1;
    __shared__ double rs[256];
    rs[t] = sn; __syncthreads();
    for (int off = 128; off > 0; off >>= 1){
        if (t < off) rs[t] += rs[t+off];
        __syncthreads();
    }
    if (t == 0) snn_part[b*8 + chunk] = rs[0];
}

// K2b: finalize 121 window denominators
__global__ __launch_bounds__(256) void k_winfin(const float* __restrict__ fr, const float* __restrict__ csum,
                                                const float* __restrict__ csum2, const double* __restrict__ stats,
                                                double* __restrict__ den){
    int b = blockIdx.x;
    const float* img = fr + (size_t)b * NPIX;
    __shared__ double fc[512], fc2[512];
    __shared__ double rsum[20], rsum2[20];
    __shared__ float E[20][20], E2[20][20];
    __shared__ double red[256], red2[256];
    int t = threadIdx.x;
    for (int c = t; c < 512; c += 256){
        double s = 0.0, s2 = 0.0;
        for (int k = 0; k < 8; ++k){
            size_t o = ((size_t)(b*8 + k) << 9) + c;
            s += (double)csum[o]; s2 += (double)csum2[o];
        }
        fc[c] = s; fc2[c] = s2;
    }
    if (t < 400){
        int i = t / 20, j = t % 20;
        int row = (i < 10) ? i : (i + 492);
        int col = (j < 10) ? j : (j + 492);
        float v = img[(row<<9) + col];
        E[i][j] = v; E2[i][j] = v*v;
    }
    __syncthreads();
    red[t] = fc[t] + fc[t+256];
    red2[t] = fc2[t] + fc2[t+256];
    __syncthreads();
    for (int off = 128; off > 0; off >>= 1){
        if (t < off){ red[t] += red[t+off]; red2[t] += red2[t+off]; }
        __syncthreads();
    }
    double F1 = red[0], F2 = red2[0];
    int lane = t & 63, wv = t >> 6;
    for (int e = wv; e < 20; e += 4){
        int row = (e < 10) ? e : (e + 492);
        double s = 0.0, s2 = 0.0;
        for (int c = lane; c < 512; c += 64){
            float v = img[(row<<9) + c];
            s += v; s2 += (double)v*v;
        }
        #pragma unroll
        for (int off = 32; off > 0; off >>= 1){ s += __shfl_down(s, off); s2 += __shfl_down(s2, off); }
        if (lane == 0){ rsum[e] = s; rsum2[e] = s2; }
    }
    __syncthreads();
    if (t < 121){
        int u = t / 11, v = t % 11;
        double S1 = F1, S2 = F2;
        for (int i = 0; i < u; ++i){ S1 -= rsum[i]; S2 -= rsum2[i]; }
        for (int k = 10+u; k < 20; ++k){ S1 -= rsum[k]; S2 -= rsum2[k]; }
        for (int j = 0; j < v; ++j){
            double cw = fc[j], cq = fc2[j];
            for (int i = 0; i < u; ++i){ cw -= E[i][j]; cq -= E2[i][j]; }
            for (int k = 10+u; k < 20; ++k){ cw -= E[k][j]; cq -= E2[k][j]; }
            S1 -= cw; S2 -= cq;
        }
        for (int jj = 10+v; jj < 20; ++jj){
            int col = jj + 492;
            double cw = fc[col], cq = fc2[col];
            for (int i = 0; i < u; ++i){ cw -= E[i][jj]; cq -= E2[i][jj]; }
            for (int k = 10+u; k < 20; ++k){ cw -= E[k][jj]; cq -= E2[k][jj]; }
            S1 -= cw; S2 -= cq;
        }
        const double K = 502.0*502.0;
        double ivar = S2/K - (S1*S1)/(K*K*K) + 1e-8;
        if (ivar < 0.0) ivar = 0.0;
        den[b*121 + u*11 + v] = sqrt(stats[1] * ivar);
    }
}

// K3: direct shifted cross-correlation (shift-split across waves; R6 structure, unchanged)
__global__ __launch_bounds__(512, 2) void k_ncc(const float* __restrict__ fr, const float* __restrict__ tpl,
                                                const double* __restrict__ stats, float* __restrict__ partial){
    int b = blockIdx.x >> 5, chunk = blockIdx.x & 31;
    const float* img = fr + (size_t)b * NPIX;
    float mean = (float)stats[0];
    __shared__ float tr[26][548];
    __shared__ float wred[8][33];
    int i0 = chunk << 4;
    int tid = threadIdx.x;
    for (int idx = tid; idx < 26*544; idx += 512){
        int r = idx / 544, k = idx - r*544;
        tr[r][k] = tpl[(((i0 - 5 + r + 512) & 511) << 9) | ((k - 16) & 511)] - mean;
    }
    __syncthreads();
    int rg = tid & 3;
    int cg = (tid >> 2) & 31;
    int sg = tid >> 7;
    int j0 = cg << 4;
    float acc[3][11];
    #pragma unroll
    for (int j = 0; j < 3; ++j)
        #pragma unroll
        for (int s1 = 0; s1 < 11; ++s1) acc[j][s1] = 0.f;
    #pragma unroll 1
    for (int k = 0; k < 4; ++k){
        int i = i0 + 4*k + rg;
        float x[16];
        #pragma unroll
        for (int q = 0; q < 4; ++q)
            *(float4*)&x[4*q] = *(const float4*)&img[(i<<9) + j0 + 4*q];
        #pragma unroll
        for (int j = 0; j < 3; ++j){
            int s0 = sg + 4*j;
            if (s0 < 11){
                const float* trow = tr[4*k + rg + 10 - s0];
                float tv[32];
                #pragma unroll
                for (int q = 0; q < 8; ++q)
                    *(float4*)&tv[4*q] = *(const float4*)&trow[j0 + 8 + 4*q];
                #pragma unroll
                for (int s1 = 0; s1 < 11; ++s1)
                    #pragma unroll
                    for (int c = 0; c < 16; ++c)
                        acc[j][s1] += x[c] * tv[c + 13 - s1];
            }
        }
    }
    int lane = tid & 63, wv = tid >> 6;
    #pragma unroll
    for (int j = 0; j < 3; ++j){
        #pragma unroll
        for (int s1 = 0; s1 < 11; ++s1){
            float v = acc[j][s1];
            v += __shfl_down(v, 32); v += __shfl_down(v, 16); v += __shfl_down(v, 8);
            v += __shfl_down(v, 4);  v += __shfl_down(v, 2);  v += __shfl_down(v, 1);
            if (lane == 0) wred[wv][j*11 + s1] = v;
        }
    }
    __syncthreads();
    if (tid < 121){
        int s0 = tid / 11, s1 = tid - s0*11;
        int sgo = s0 & 3, jj = s0 >> 2;
        partial[(size_t)(b*32 + chunk)*121 + tid] = wred[2*sgo][jj*11 + s1] + wred[2*sgo + 1][jj*11 + s1];
    }
}

// K4: ncc finalize -> shifts, c2
__global__ __launch_bounds__(128) void k_shifts(const float* __restrict__ partial, const double* __restrict__ den,
                                                const double* __restrict__ snn_part, double* __restrict__ shx,
                                                double* __restrict__ shy, float* __restrict__ c2){
    int b = blockIdx.x;
    __shared__ double l[121], nc[121];
    for (int e = threadIdx.x; e < 121; e += 128){
        double s = 0.0;
        for (int c = 0; c < 32; ++c) s += (double)partial[(size_t)(b*32 + c)*121 + e];
        double nom = fabs(s);
        double v = nom / den[b*121 + e];
        if (v != v) v = 0.0;
        nc[e] = v;
        l[e] = log(v);
    }
    __syncthreads();
    if (threadIdx.x == 0){
        int am = 0; double best = nc[0];
        for (int e = 1; e < 121; ++e) if (nc[e] > best){ best = nc[e]; am = e; }
        int u = am / 11, v = am % 11;
        double sx = -(double)(u - 5), sy = -(double)(v - 5);
        int um1 = u - 1; if (um1 < 0) um1 += 11; if (um1 > 10) um1 = 10;
        int up1 = u + 1; if (up1 > 10) up1 = 10;
        int vm1 = v - 1; if (vm1 < 0) vm1 += 11; if (vm1 > 10) vm1 = 10;
        int vp1 = v + 1; if (vp1 > 10) vp1 = 10;
        double l0x4 = 4.0 * l[u*11 + v];
        double lm = l[um1*11 + v], lp = l[up1*11 + v];
        sx -= (lm - lp) / (2.0*lm - l0x4 + 2.0*lp);
        double lm2 = l[u*11 + vm1], lp2 = l[u*11 + vp1];
        sy -= (lm2 - lp2) / (2.0*lm2 - l0x4 + 2.0*lp2);
        shx[b] = sx; shy[b] = sy;
        double snn = 0.0;
        for (int c = 0; c < 8; ++c) snn += snn_part[b*8 + c];
        double kx = sin(PI_D * sx) / 512.0, ky = sin(PI_D * sy) / 512.0;
        c2[b] = (float)(kx * ky * snn);
    }
}

__device__ inline double grekern(int t, double s){
    double u = (double)t - s;
    if (u > 256.0) u -= 512.0;
    double a = PI_D * u / 512.0;
    double sp = sin(a);
    double D;
    if (fabs(sp) < 1e-12) D = cos(PI_D * u) / cos(a);
    else D = sin(PI_D * u) / (512.0 * sp);
    return D * cos(a);
}

// K4b: Dirichlet kernels -> bf16 hi/lo tables: gtab[b][axis(0=y,1=x)][pol(0=hi,1=lo)][512]
__global__ __launch_bounds__(256) void k_tables(const double* __restrict__ shx, const double* __restrict__ shy,
                                                unsigned short* __restrict__ gtab){
    int b = blockIdx.x;
    double sx = shx[b], sy = shy[b];
    unsigned short* g = gtab + ((size_t)b << 11);   // 2048 ushorts per image
    for (int t = threadIdx.x; t < 512; t += 256){
        float gy = (float)grekern(t, sy);
        float gx = (float)grekern(t, sx);
        unsigned short yh = f2bf(gy); unsigned short yl = f2bf(gy - bf2f(yh));
        unsigned short xh = f2bf(gx); unsigned short xl = f2bf(gx - bf2f(xh));
        g[t] = yh; g[512 + t] = yl; g[1024 + t] = xh; g[1536 + t] = xl;
    }
}

// K5: split X (frames f32) -> Xhi/Xlo bf16, chunk-local
__global__ __launch_bounds__(256) void k_splitx(const float* __restrict__ fr, unsigned short* __restrict__ Xhi,
                                                unsigned short* __restrict__ Xlo, int b0){
    int lb = blockIdx.x >> 4, blk = blockIdx.x & 15;
    const float* src = fr + (((size_t)(b0 + lb)) << 18) + blk*16384;
    unsigned short* dh = Xhi + (((size_t)lb) << 18) + blk*16384;
    unsigned short* dl = Xlo + (((size_t)lb) << 18) + blk*16384;
    for (int i = threadIdx.x; i < 4096; i += 256){
        float4 v = ((const float4*)src)[i];
        v4u hv, lv;
        unsigned short h;
        h = f2bf(v.x); hv.x = h; lv.x = f2bf(v.x - bf2f(h));
        h = f2bf(v.y); hv.y = h; lv.y = f2bf(v.y - bf2f(h));
        h = f2bf(v.z); hv.z = h; lv.z = f2bf(v.z - bf2f(h));
        h = f2bf(v.w); hv.w = h; lv.w = f2bf(v.w - bf2f(h));
        *(v4u*)&dh[4*i] = hv;
        *(v4u*)&dl[4*i] = lv;
    }
}

// K6: build fragment-ordered circulant B matrices from 512-entry tables.
// Bm layout per image: [pol(2)][ks(16)][q(512)][lk(4)*8+j] ushort  (= 524288 ushorts = 1MB)
// value = g_pol[(q - (ks*32 + lk*8 + j)) & 511]
__global__ __launch_bounds__(256) void k_bmat(const unsigned short* __restrict__ gtab,
                                              unsigned short* __restrict__ Bym, unsigned short* __restrict__ Bxm,
                                              int b0){
    int ks = blockIdx.x & 15;
    int axis = (blockIdx.x >> 4) & 1;
    int lb = blockIdx.x >> 5;
    int bg = b0 + lb;
    __shared__ unsigned short gl[1024];   // [pol][512]
    const unsigned short* gsrc = gtab + ((size_t)bg << 11) + axis*1024;
    for (int i = threadIdx.x; i < 128; i += 256)
        ((float4*)gl)[i] = ((const float4*)gsrc)[i];
    __syncthreads();
    unsigned short* out = (axis ? Bxm : Bym) + ((size_t)lb << 19);
    for (int f = threadIdx.x; f < 4096; f += 256){
        int pol = f >> 11, rem = f & 2047;
        int q = rem >> 2, lk = rem & 3;
        int kb = ks*32 + lk*8;
        unsigned short tmp[8];
        #pragma unroll
        for (int j = 0; j < 8; ++j) tmp[j] = gl[pol*512 + ((q - kb - j) & 511)];
        *(float4*)&out[(size_t)pol*262144 + ((size_t)ks*512 + q)*32 + lk*8] = *(float4*)tmp;
    }
}

// K7: MFMA circulant GEMM.  C[b][512][512] (f32) = A(hi/lo bf16) x B(circulant, fragment-ordered).
// 3 passes: Ahi*Bhi + Alo*Bhi + Ahi*Blo.  BM=64, BN=128, 4 waves (2x2), wave tile 32x64.
// A-frag: lane l holds A[row=l&15][k=8*(l>>4)+j]; B-frag: B[k=8*(l>>4)+j][col=l&15];
// C/D: col=lane&15, row=(lane>>4)*4+reg  [m89-verified].
template<int CORR>
__global__ __launch_bounds__(256) void k_gemm(const unsigned short* __restrict__ Ahi,
                                              const unsigned short* __restrict__ Alo,
                                              const unsigned short* __restrict__ Bm,
                                              float* __restrict__ Cout,
                                              const float* __restrict__ c2, int b0, int swz){
    int bid = blockIdx.x;
    int lb, tile;
    if (swz){ int x = bid & 7; int r = bid >> 3; lb = (r >> 5)*8 + x; tile = r & 31; }
    else    { lb = bid >> 5; tile = bid & 31; }
    int mt = tile >> 2, nt = tile & 3;
    int tid = threadIdx.x;
    __shared__ unsigned short At[64][40];     // padded: 80B rows -> 2-way banks (free)
    __shared__ unsigned short Bt[128][40];
    v4f acc[2][4];
    #pragma unroll
    for (int mi = 0; mi < 2; ++mi)
        #pragma unroll
        for (int ni = 0; ni < 4; ++ni) acc[mi][ni] = (v4f){0.f, 0.f, 0.f, 0.f};
    const size_t imgoff = (size_t)lb << 18;
    const unsigned short* Bbase = Bm + ((size_t)lb << 19);
    int l = tid & 63, wv = tid >> 6;
    int wm = wv >> 1, wn = wv & 1;
    int lr = l & 15, lk = l >> 4;
    #pragma unroll 1
    for (int pass = 0; pass < 3; ++pass){
        const unsigned short* Ap = ((pass == 1) ? Alo : Ahi) + imgoff + (size_t)mt*64*512;
        const unsigned short* Bp = Bbase + ((pass == 2) ? (size_t)262144 : (size_t)0);
        #pragma unroll 1
        for (int ks = 0; ks < 16; ++ks){
            __syncthreads();
            { int row = tid >> 2, c8 = (tid & 3) << 3;
              *(float4*)&At[row][c8] = *(const float4*)&Ap[(size_t)row*512 + ks*32 + c8]; }
            { int row = tid >> 1, h = tid & 1;
              const float4* s = (const float4*)&Bp[((size_t)ks*512 + nt*128 + row)*32 + h*16];
              *(float4*)&Bt[row][h*16]     = s[0];
              *(float4*)&Bt[row][h*16 + 8] = s[1]; }
            __syncthreads();
            v8s a0 = *(v8s*)&At[wm*32 + lr][lk*8];
            v8s a1 = *(v8s*)&At[wm*32 + 16 + lr][lk*8];
            #pragma unroll
            for (int ni = 0; ni < 4; ++ni){
                v8s bf = *(v8s*)&Bt[wn*64 + ni*16 + lr][lk*8];
                acc[0][ni] = __builtin_amdgcn_mfma_f32_16x16x32_bf16(a0, bf, acc[0][ni], 0, 0, 0);
                acc[1][ni] = __builtin_amdgcn_mfma_f32_16x16x32_bf16(a1, bf, acc[1][ni], 0, 0, 0);
            }
        }
    }
    int bg = b0 + lb;
    float cc = CORR ? c2[bg] : 0.f;
    float* outp = Cout + ((size_t)bg << 18);
    int crow4 = (l >> 4) * 4;
    #pragma unroll
    for (int mi = 0; mi < 2; ++mi)
        #pragma unroll
        for (int ni = 0; ni < 4; ++ni)
            #pragma unroll
            for (int rg = 0; rg < 4; ++rg){
                int row = mt*64 + wm*32 + mi*16 + crow4 + rg;
                int col = nt*128 + wn*64 + ni*16 + lr;
                float v = acc[mi][ni][rg];
                if (CORR) v -= ((row + col) & 1) ? -cc : cc;
                outp[((size_t)row << 9) + col] = v;
            }
}

// K8: transpose Y (f32 in d_out) -> YT hi/lo bf16 chunk-local
__global__ __launch_bounds__(256) void k_transpose2(const float* __restrict__ Y,
                                                    unsigned short* __restrict__ Thi,
                                                    unsigned short* __restrict__ Tlo, int b0){
    int lb = blockIdx.x >> 8, tb = blockIdx.x & 255;
    int tx = (tb & 15) << 5, ty = ((tb >> 4) & 15) << 5;
    const float* src = Y + (((size_t)(b0 + lb)) << 18);
    unsigned short* dh = Thi + (((size_t)lb) << 18);
    unsigned short* dl = Tlo + (((size_t)lb) << 18);
    __shared__ float tile[32][33];
    int col = threadIdx.x & 31, rw = threadIdx.x >> 5;
    #pragma unroll
    for (int k = 0; k < 4; ++k){
        int ry = rw + k*8;
        tile[ry][col] = src[((size_t)(ty + ry) << 9) + tx + col];
    }
    __syncthreads();
    #pragma unroll
    for (int k = 0; k < 4; ++k){
        int ry = rw + k*8;
        float v = tile[col][ry];
        unsigned short h = f2bf(v);
        size_t o = ((size_t)(tx + ry) << 9) + ty + col;
        dh[o] = h;
        dl[o] = f2bf(v - bf2f(h));
    }
}

extern "C" void kernel_launch(void* const* d_in, const int* in_sizes, int n_in,
                              void* d_out, int out_size, void* d_ws, size_t ws_size,
                              hipStream_t stream){
    (void)in_sizes; (void)n_in; (void)out_size;
    const float* fr  = (const float*)d_in[0];
    const float* tpl = (const float*)d_in[1];
    float* out = (float*)d_out;
    char* ws = (char*)d_ws;

    double* stats  = (double*)(ws + 0);
    double* spart  = (double*)(ws + 64);
    double* den    = (double*)(ws + 2048);
    double* snnp   = (double*)(ws + 33280);
    double* shx    = (double*)(ws + 35328);
    double* shy    = (double*)(ws + 35584);
    float*  c2     = (float*) (ws + 35840);
    float*  part   = (float*) (ws + 36096);
    unsigned short* gtab = (unsigned short*)(ws + 532480);
    float*  csum   = (float*) (ws + 663552);
    float*  csum2  = (float*) (ws + 1187840);

    const size_t CB = 1720320;
    long long avail = ((long long)ws_size - (long long)CB) / (4ll << 20);
    int NC = (int)avail; if (NC > 32) NC = 32; if (NC < 1) NC = 1;
    if (NC >= 8) NC &= ~7;                       // multiple of 8 -> XCD swizzle valid
    int swz = (NC % 8 == 0) ? 1 : 0;

    unsigned short* Xhi  = (unsigned short*)(ws + CB);
    unsigned short* Xlo  = Xhi  + (size_t)NC*262144;
    unsigned short* YThi = Xlo  + (size_t)NC*262144;
    unsigned short* YTlo = YThi + (size_t)NC*262144;
    unsigned short* Bym  = YTlo + (size_t)NC*262144;
    unsigned short* Bxm  = Bym  + (size_t)NC*524288;

    k_stats_part<<<64, 256, 0, stream>>>(tpl, spart);
    k_stats_final<<<1, 64, 0, stream>>>(spart, stats);
    k_colsums<<<256, 256, 0, stream>>>(fr, csum, csum2, snnp);
    k_winfin<<<32, 256, 0, stream>>>(fr, csum, csum2, stats, den);
    k_ncc<<<1024, 512, 0, stream>>>(fr, tpl, stats, part);
    k_shifts<<<32, 128, 0, stream>>>(part, den, snnp, shx, shy, c2);
    k_tables<<<32, 256, 0, stream>>>(shx, shy, gtab);

    for (int b0 = 0; b0 < 32; b0 += NC){
        int nb = (32 - b0 < NC) ? (32 - b0) : NC;
        int sw = (swz && (nb % 8 == 0)) ? 1 : 0;
        k_splitx<<<nb*16, 256, 0, stream>>>(fr, Xhi, Xlo, b0);
        k_bmat<<<nb*32, 256, 0, stream>>>(gtab, Bym, Bxm, b0);
        // stage 1: Y = X * Gy  -> d_out (f32 scratch)
        k_gemm<0><<<nb*32, 256, 0, stream>>>(Xhi, Xlo, Bym, out, (const float*)nullptr, b0, sw);
        // transpose + split: YT hi/lo
        k_transpose2<<<nb*256, 256, 0, stream>>>(out, YThi, YTlo, b0);
        // stage 2: Out = YT * Gx - c2*(-1)^(p+q) -> d_out (final)
        k_gemm<1><<<nb*32, 256, 0, stream>>>(YThi, YTlo, Bxm, out, c2, b0, sw);
    }
}

// Round 10
// 226.425 us; speedup vs baseline: 2.7807x; 1.1563x over previous
//
#include <hip/hip_runtime.h>
#include <hip/hip_bf16.h>
#include <math.h>

#define NPIX 262144          // 512*512
#define PI_D 3.14159265358979323846264338327950288

typedef __attribute__((ext_vector_type(8))) short v8s;           // bf16x8 MFMA fragment
typedef __attribute__((ext_vector_type(4))) float v4f;           // f32x4 accumulator
typedef __attribute__((ext_vector_type(4))) unsigned short v4u;

// ---------------- ws layout (byte offsets) ----------------
// 0        double stats[2]
// 64       double spart[64][2]
// 2048     double den[32][121]
// 33280    double snn_part[32][8]
// 35328    double shx[32]
// 35584    double shy[32]
// 35840    float  c2[32]
// 36096    float  partial[32][64][121]          (991,232 B) ends 1,027,328
// 1027328  ushort gtab[32][2][2][512]           (131,072 B) ends 1,158,400
// 1158400  ushort tsp[2][512][512]              (1,048,576 B) ends 2,206,976
// 2206976  float  csum[32][8][512]              ends 2,731,264
// 2731264  float  csum2[32][8][512]             ends 3,255,552
// 3255552  chunk area: per image 4 MB (Xhi/Xlo/YThi/YTlo 512KB; Bym/Bxm 1MB)

__device__ inline unsigned short f2bf(float x){
    unsigned u = __float_as_uint(x);
    return (unsigned short)((u + 0x7FFFu + ((u >> 16) & 1u)) >> 16);   // RNE
}
__device__ inline float bf2f(unsigned short h){ return __uint_as_float(((unsigned)h) << 16); }

// K1a: template partial sums
__global__ __launch_bounds__(256) void k_stats_part(const float* __restrict__ t, double* __restrict__ part){
    int base = blockIdx.x * 4096;
    double s = 0.0, s2 = 0.0;
    #pragma unroll
    for (int k = 0; k < 4; ++k){
        float4 v = *(const float4*)&t[base + k*1024 + threadIdx.x*4];
        s  += (double)v.x + (double)v.y + (double)v.z + (double)v.w;
        s2 += (double)v.x*v.x + (double)v.y*v.y + (double)v.z*v.z + (double)v.w*v.w;
    }
    __shared__ double rs[256], rs2[256];
    rs[threadIdx.x] = s; rs2[threadIdx.x] = s2; __syncthreads();
    for (int off = 128; off > 0; off >>= 1){
        if (threadIdx.x < off){ rs[threadIdx.x] += rs[threadIdx.x+off]; rs2[threadIdx.x] += rs2[threadIdx.x+off]; }
        __syncthreads();
    }
    if (threadIdx.x == 0){ part[blockIdx.x*2] = rs[0]; part[blockIdx.x*2+1] = rs2[0]; }
}

__global__ __launch_bounds__(64) void k_stats_final(const double* __restrict__ part, double* __restrict__ stats){
    double s = part[threadIdx.x*2], s2 = part[threadIdx.x*2+1];
    #pragma unroll
    for (int off = 32; off > 0; off >>= 1){
        s  += __shfl_down(s, off);
        s2 += __shfl_down(s2, off);
    }
    if (threadIdx.x == 0){
        stats[0] = s / (double)NPIX;
        stats[1] = s2 - s*s/(double)NPIX + 1e-8;
    }
}

// K1c: template -> zero-mean bf16 hi/lo (tsp[0]=hi, tsp[1]=lo)
__global__ __launch_bounds__(256) void k_tsplit(const float* __restrict__ tpl, const double* __restrict__ stats,
                                                unsigned short* __restrict__ tsp){
    float mean = (float)stats[0];
    int base = blockIdx.x * 1024 + threadIdx.x * 4;
    float4 v = *(const float4*)&tpl[base];
    v.x -= mean; v.y -= mean; v.z -= mean; v.w -= mean;
    unsigned short h0 = f2bf(v.x), h1 = f2bf(v.y), h2 = f2bf(v.z), h3 = f2bf(v.w);
    v4u hv = {h0, h1, h2, h3};
    v4u lv = {f2bf(v.x - bf2f(h0)), f2bf(v.y - bf2f(h1)), f2bf(v.z - bf2f(h2)), f2bf(v.w - bf2f(h3))};
    *(v4u*)&tsp[base] = hv;
    *(v4u*)&tsp[262144 + base] = lv;
}

// K2a: per-chunk column sums + Nyquist alternating sum
__global__ __launch_bounds__(256) void k_colsums(const float* __restrict__ fr, float* __restrict__ csum,
                                                 float* __restrict__ csum2, double* __restrict__ snn_part){
    int b = blockIdx.x >> 3, chunk = blockIdx.x & 7;
    const float* img = fr + (size_t)b * NPIX + (size_t)chunk * (64*512);
    int t = threadIdx.x;
    float a0=0.f, q0=0.f, a1=0.f, q1=0.f;
    double sn = 0.0;
    for (int r = 0; r < 64; ++r){
        float v0 = img[(r<<9) + t];
        float v1 = img[(r<<9) + t + 256];
        a0 += v0; q0 += v0*v0; a1 += v1; q1 += v1*v1;
        float sv = v0 + v1;
        sn += ((r + t) & 1) ? -(double)sv : (double)sv;
    }
    size_t o = ((size_t)(b*8 + chunk) << 9) + t;
    csum[o] = a0;  csum[o + 256] = a1;
    csum2[o] = q0; csum2[o + 256] = q1;
    __shared__ double rs[256];
    rs[t] = sn; __syncthreads();
    for (int off = 128; off > 0; off >>= 1){
        if (t < off) rs[t] += rs[t+off];
        __syncthreads();
    }
    if (t == 0) snn_part[b*8 + chunk] = rs[0];
}

// K2b: finalize 121 window denominators
__global__ __launch_bounds__(256) void k_winfin(const float* __restrict__ fr, const float* __restrict__ csum,
                                                const float* __restrict__ csum2, const double* __restrict__ stats,
                                                double* __restrict__ den){
    int b = blockIdx.x;
    const float* img = fr + (size_t)b * NPIX;
    __shared__ double fc[512], fc2[512];
    __shared__ double rsum[20], rsum2[20];
    __shared__ float E[20][20], E2[20][20];
    __shared__ double red[256], red2[256];
    int t = threadIdx.x;
    for (int c = t; c < 512; c += 256){
        double s = 0.0, s2 = 0.0;
        for (int k = 0; k < 8; ++k){
            size_t o = ((size_t)(b*8 + k) << 9) + c;
            s += (double)csum[o]; s2 += (double)csum2[o];
        }
        fc[c] = s; fc2[c] = s2;
    }
    if (t < 400){
        int i = t / 20, j = t % 20;
        int row = (i < 10) ? i : (i + 492);
        int col = (j < 10) ? j : (j + 492);
        float v = img[(row<<9) + col];
        E[i][j] = v; E2[i][j] = v*v;
    }
    __syncthreads();
    red[t] = fc[t] + fc[t+256];
    red2[t] = fc2[t] + fc2[t+256];
    __syncthreads();
    for (int off = 128; off > 0; off >>= 1){
        if (t < off){ red[t] += red[t+off]; red2[t] += red2[t+off]; }
        __syncthreads();
    }
    double F1 = red[0], F2 = red2[0];
    int lane = t & 63, wv = t >> 6;
    for (int e = wv; e < 20; e += 4){
        int row = (e < 10) ? e : (e + 492);
        double s = 0.0, s2 = 0.0;
        for (int c = lane; c < 512; c += 64){
            float v = img[(row<<9) + c];
            s += v; s2 += (double)v*v;
        }
        #pragma unroll
        for (int off = 32; off > 0; off >>= 1){ s += __shfl_down(s, off); s2 += __shfl_down(s2, off); }
        if (lane == 0){ rsum[e] = s; rsum2[e] = s2; }
    }
    __syncthreads();
    if (t < 121){
        int u = t / 11, v = t % 11;
        double S1 = F1, S2 = F2;
        for (int i = 0; i < u; ++i){ S1 -= rsum[i]; S2 -= rsum2[i]; }
        for (int k = 10+u; k < 20; ++k){ S1 -= rsum[k]; S2 -= rsum2[k]; }
        for (int j = 0; j < v; ++j){
            double cw = fc[j], cq = fc2[j];
            for (int i = 0; i < u; ++i){ cw -= E[i][j]; cq -= E2[i][j]; }
            for (int k = 10+u; k < 20; ++k){ cw -= E[k][j]; cq -= E2[k][j]; }
            S1 -= cw; S2 -= cq;
        }
        for (int jj = 10+v; jj < 20; ++jj){
            int col = jj + 492;
            double cw = fc[col], cq = fc2[col];
            for (int i = 0; i < u; ++i){ cw -= E[i][jj]; cq -= E2[i][jj]; }
            for (int k = 10+u; k < 20; ++k){ cw -= E[k][jj]; cq -= E2[k][jj]; }
            S1 -= cw; S2 -= cq;
        }
        const double K = 502.0*502.0;
        double ivar = S2/K - (S1*S1)/(K*K*K) + 1e-8;
        if (ivar < 0.0) ivar = 0.0;
        den[b*121 + u*11 + v] = sqrt(stats[1] * ivar);
    }
}

// K3: MFMA NCC.  Per image row i: D[dy][dx] += sum_k t_zm[(i+dy-5)&511][k] * x[i][(k-dx+5)&511]
// (dy=10-s0, dx=10-s1 maps to the old acc[s0][s1]).  A-frag: lane row = dy (aligned b128 from
// padded template tile).  B-frag: per-lane 1-ushort shift -> built via 5x ds_read_b32 + 4x
// alignbit funnel extract (always 4B-aligned; rule #20 safe, all indices static).
// Block = 256 thr = 4 waves; 8 image rows/block (2 per wave); grid = 32 images x 64 chunks.
__global__ __launch_bounds__(256, 2) void k_ncc(const float* __restrict__ fr,
                                                const unsigned short* __restrict__ tsp,
                                                float* __restrict__ partial){
    int b = blockIdx.x >> 6, chunk = blockIdx.x & 63;
    int i0 = chunk << 3;
    int tid = threadIdx.x;
    __shared__ unsigned short Th[24][520], Tl[24][520];   // template rows i0-5 .. i0+18 (pad 520)
    __shared__ unsigned short Xh[8][544], Xl[8][544];     // x rows, halo'd: [p] = x[(p-16)&511]
    __shared__ float Dred[4][16][16];
    // stage template (bf16 pre-split)
    for (int q = tid; q < 1536; q += 256){
        int r = q >> 6, c8 = (q & 63) << 3;
        int grow = (i0 - 5 + r + 512) & 511;
        *(float4*)&Th[r][c8] = *(const float4*)&tsp[((size_t)grow << 9) + c8];
        *(float4*)&Tl[r][c8] = *(const float4*)&tsp[262144 + ((size_t)grow << 9) + c8];
    }
    // stage x rows: load f32 (aligned quads incl. wrap halo), split hi/lo once
    const float* img = fr + ((size_t)b << 18);
    for (int q = tid; q < 1088; q += 256){
        int r = q / 136, qq = q - r*136;
        int col = ((qq << 2) - 16) & 511;
        float4 v = *(const float4*)&img[((size_t)(i0 + r) << 9) + col];
        unsigned short h0 = f2bf(v.x), h1 = f2bf(v.y), h2 = f2bf(v.z), h3 = f2bf(v.w);
        v4u hv = {h0, h1, h2, h3};
        v4u lv = {f2bf(v.x - bf2f(h0)), f2bf(v.y - bf2f(h1)), f2bf(v.z - bf2f(h2)), f2bf(v.w - bf2f(h3))};
        *(v4u*)&Xh[r][qq << 2] = hv;
        *(v4u*)&Xl[r][qq << 2] = lv;
    }
    __syncthreads();
    int l = tid & 63, wv = tid >> 6;
    int lr = l & 15, lk = l >> 4;
    v4f acc = (v4f){0.f, 0.f, 0.f, 0.f};
    union UB { unsigned u[4]; v8s s; };
    int sbase = (lk << 3) - lr + 21;          // ushort index base (+32*ks); parity fixed per thread
    unsigned sh = (unsigned)((sbase & 1) << 4);
    #pragma unroll
    for (int ii = 0; ii < 2; ++ii){
        int ro = 2*wv + ii;
        const unsigned* xh32 = (const unsigned*)&Xh[ro][0];
        const unsigned* xl32 = (const unsigned*)&Xl[ro][0];
        #pragma unroll 1
        for (int ks = 0; ks < 16; ++ks){
            int ka = (ks << 5) + (lk << 3);
            v8s ah = *(v8s*)&Th[ro + lr][ka];
            v8s al = *(v8s*)&Tl[ro + lr][ka];
            int W = ((ks << 5) + sbase) >> 1;
            unsigned wh[5], wl[5];
            #pragma unroll
            for (int j = 0; j < 5; ++j){ wh[j] = xh32[W + j]; wl[j] = xl32[W + j]; }
            UB bh, bl;
            #pragma unroll
            for (int j = 0; j < 4; ++j){
                bh.u[j] = __builtin_amdgcn_alignbit(wh[j+1], wh[j], sh);
                bl.u[j] = __builtin_amdgcn_alignbit(wl[j+1], wl[j], sh);
            }
            acc = __builtin_amdgcn_mfma_f32_16x16x32_bf16(ah, bh.s, acc, 0, 0, 0);
            acc = __builtin_amdgcn_mfma_f32_16x16x32_bf16(al, bh.s, acc, 0, 0, 0);
            acc = __builtin_amdgcn_mfma_f32_16x16x32_bf16(ah, bl.s, acc, 0, 0, 0);
        }
    }
    // C/D: col = lane&15 (dx), row = 4*(lane>>4)+reg (dy)   [m89-verified]
    #pragma unroll
    for (int r = 0; r < 4; ++r) Dred[wv][4*lk + r][lr] = acc[r];
    __syncthreads();
    if (tid < 121){
        int s0 = tid / 11, s1 = tid - s0*11;
        int dy = 10 - s0, dx = 10 - s1;
        partial[(size_t)(b*64 + chunk)*121 + tid] =
            Dred[0][dy][dx] + Dred[1][dy][dx] + Dred[2][dy][dx] + Dred[3][dy][dx];
    }
}

// K4: ncc finalize -> shifts, c2   (64 chunks now)
__global__ __launch_bounds__(128) void k_shifts(const float* __restrict__ partial, const double* __restrict__ den,
                                                const double* __restrict__ snn_part, double* __restrict__ shx,
                                                double* __restrict__ shy, float* __restrict__ c2){
    int b = blockIdx.x;
    __shared__ double l[121], nc[121];
    for (int e = threadIdx.x; e < 121; e += 128){
        double s = 0.0;
        for (int c = 0; c < 64; ++c) s += (double)partial[(size_t)(b*64 + c)*121 + e];
        double nom = fabs(s);
        double v = nom / den[b*121 + e];
        if (v != v) v = 0.0;
        nc[e] = v;
        l[e] = log(v);
    }
    __syncthreads();
    if (threadIdx.x == 0){
        int am = 0; double best = nc[0];
        for (int e = 1; e < 121; ++e) if (nc[e] > best){ best = nc[e]; am = e; }
        int u = am / 11, v = am % 11;
        double sx = -(double)(u - 5), sy = -(double)(v - 5);
        int um1 = u - 1; if (um1 < 0) um1 += 11; if (um1 > 10) um1 = 10;
        int up1 = u + 1; if (up1 > 10) up1 = 10;
        int vm1 = v - 1; if (vm1 < 0) vm1 += 11; if (vm1 > 10) vm1 = 10;
        int vp1 = v + 1; if (vp1 > 10) vp1 = 10;
        double l0x4 = 4.0 * l[u*11 + v];
        double lm = l[um1*11 + v], lp = l[up1*11 + v];
        sx -= (lm - lp) / (2.0*lm - l0x4 + 2.0*lp);
        double lm2 = l[u*11 + vm1], lp2 = l[u*11 + vp1];
        sy -= (lm2 - lp2) / (2.0*lm2 - l0x4 + 2.0*lp2);
        shx[b] = sx; shy[b] = sy;
        double snn = 0.0;
        for (int c = 0; c < 8; ++c) snn += snn_part[b*8 + c];
        double kx = sin(PI_D * sx) / 512.0, ky = sin(PI_D * sy) / 512.0;
        c2[b] = (float)(kx * ky * snn);
    }
}

__device__ inline double grekern(int t, double s){
    double u = (double)t - s;
    if (u > 256.0) u -= 512.0;
    double a = PI_D * u / 512.0;
    double sp = sin(a);
    double D;
    if (fabs(sp) < 1e-12) D = cos(PI_D * u) / cos(a);
    else D = sin(PI_D * u) / (512.0 * sp);
    return D * cos(a);
}

// K4b: Dirichlet kernels -> bf16 hi/lo tables
__global__ __launch_bounds__(256) void k_tables(const double* __restrict__ shx, const double* __restrict__ shy,
                                                unsigned short* __restrict__ gtab){
    int b = blockIdx.x;
    double sx = shx[b], sy = shy[b];
    unsigned short* g = gtab + ((size_t)b << 11);
    for (int t = threadIdx.x; t < 512; t += 256){
        float gy = (float)grekern(t, sy);
        float gx = (float)grekern(t, sx);
        unsigned short yh = f2bf(gy); unsigned short yl = f2bf(gy - bf2f(yh));
        unsigned short xh = f2bf(gx); unsigned short xl = f2bf(gx - bf2f(xh));
        g[t] = yh; g[512 + t] = yl; g[1024 + t] = xh; g[1536 + t] = xl;
    }
}

// K5: split X -> Xhi/Xlo bf16, chunk-local
__global__ __launch_bounds__(256) void k_splitx(const float* __restrict__ fr, unsigned short* __restrict__ Xhi,
                                                unsigned short* __restrict__ Xlo, int b0){
    int lb = blockIdx.x >> 4, blk = blockIdx.x & 15;
    const float* src = fr + (((size_t)(b0 + lb)) << 18) + blk*16384;
    unsigned short* dh = Xhi + (((size_t)lb) << 18) + blk*16384;
    unsigned short* dl = Xlo + (((size_t)lb) << 18) + blk*16384;
    for (int i = threadIdx.x; i < 4096; i += 256){
        float4 v = ((const float4*)src)[i];
        v4u hv, lv;
        unsigned short h;
        h = f2bf(v.x); hv.x = h; lv.x = f2bf(v.x - bf2f(h));
        h = f2bf(v.y); hv.y = h; lv.y = f2bf(v.y - bf2f(h));
        h = f2bf(v.z); hv.z = h; lv.z = f2bf(v.z - bf2f(h));
        h = f2bf(v.w); hv.w = h; lv.w = f2bf(v.w - bf2f(h));
        *(v4u*)&dh[4*i] = hv;
        *(v4u*)&dl[4*i] = lv;
    }
}

// K6: build fragment-ordered circulant B matrices
__global__ __launch_bounds__(256) void k_bmat(const unsigned short* __restrict__ gtab,
                                              unsigned short* __restrict__ Bym, unsigned short* __restrict__ Bxm,
                                              int b0){
    int ks = blockIdx.x & 15;
    int axis = (blockIdx.x >> 4) & 1;
    int lb = blockIdx.x >> 5;
    int bg = b0 + lb;
    __shared__ unsigned short gl[1024];
    const unsigned short* gsrc = gtab + ((size_t)bg << 11) + axis*1024;
    for (int i = threadIdx.x; i < 128; i += 256)
        ((float4*)gl)[i] = ((const float4*)gsrc)[i];
    __syncthreads();
    unsigned short* out = (axis ? Bxm : Bym) + ((size_t)lb << 19);
    for (int f = threadIdx.x; f < 4096; f += 256){
        int pol = f >> 11, rem = f & 2047;
        int q = rem >> 2, lk = rem & 3;
        int kb = ks*32 + lk*8;
        unsigned short tmp[8];
        #pragma unroll
        for (int j = 0; j < 8; ++j) tmp[j] = gl[pol*512 + ((q - kb - j) & 511)];
        *(float4*)&out[(size_t)pol*262144 + ((size_t)ks*512 + q)*32 + lk*8] = *(float4*)tmp;
    }
}

// K7: MFMA circulant GEMM (unchanged from R9)
template<int CORR>
__global__ __launch_bounds__(256) void k_gemm(const unsigned short* __restrict__ Ahi,
                                              const unsigned short* __restrict__ Alo,
                                              const unsigned short* __restrict__ Bm,
                                              float* __restrict__ Cout,
                                              const float* __restrict__ c2, int b0, int swz){
    int bid = blockIdx.x;
    int lb, tile;
    if (swz){ int x = bid & 7; int r = bid >> 3; lb = (r >> 5)*8 + x; tile = r & 31; }
    else    { lb = bid >> 5; tile = bid & 31; }
    int mt = tile >> 2, nt = tile & 3;
    int tid = threadIdx.x;
    __shared__ unsigned short At[64][40];
    __shared__ unsigned short Bt[128][40];
    v4f acc[2][4];
    #pragma unroll
    for (int mi = 0; mi < 2; ++mi)
        #pragma unroll
        for (int ni = 0; ni < 4; ++ni) acc[mi][ni] = (v4f){0.f, 0.f, 0.f, 0.f};
    const size_t imgoff = (size_t)lb << 18;
    const unsigned short* Bbase = Bm + ((size_t)lb << 19);
    int l = tid & 63, wv = tid >> 6;
    int wm = wv >> 1, wn = wv & 1;
    int lr = l & 15, lk = l >> 4;
    #pragma unroll 1
    for (int pass = 0; pass < 3; ++pass){
        const unsigned short* Ap = ((pass == 1) ? Alo : Ahi) + imgoff + (size_t)mt*64*512;
        const unsigned short* Bp = Bbase + ((pass == 2) ? (size_t)262144 : (size_t)0);
        #pragma unroll 1
        for (int ks = 0; ks < 16; ++ks){
            __syncthreads();
            { int row = tid >> 2, c8 = (tid & 3) << 3;
              *(float4*)&At[row][c8] = *(const float4*)&Ap[(size_t)row*512 + ks*32 + c8]; }
            { int row = tid >> 1, h = tid & 1;
              const float4* s = (const float4*)&Bp[((size_t)ks*512 + nt*128 + row)*32 + h*16];
              *(float4*)&Bt[row][h*16]     = s[0];
              *(float4*)&Bt[row][h*16 + 8] = s[1]; }
            __syncthreads();
            v8s a0 = *(v8s*)&At[wm*32 + lr][lk*8];
            v8s a1 = *(v8s*)&At[wm*32 + 16 + lr][lk*8];
            #pragma unroll
            for (int ni = 0; ni < 4; ++ni){
                v8s bf = *(v8s*)&Bt[wn*64 + ni*16 + lr][lk*8];
                acc[0][ni] = __builtin_amdgcn_mfma_f32_16x16x32_bf16(a0, bf, acc[0][ni], 0, 0, 0);
                acc[1][ni] = __builtin_amdgcn_mfma_f32_16x16x32_bf16(a1, bf, acc[1][ni], 0, 0, 0);
            }
        }
    }
    int bg = b0 + lb;
    float cc = CORR ? c2[bg] : 0.f;
    float* outp = Cout + ((size_t)bg << 18);
    int crow4 = (l >> 4) * 4;
    #pragma unroll
    for (int mi = 0; mi < 2; ++mi)
        #pragma unroll
        for (int ni = 0; ni < 4; ++ni)
            #pragma unroll
            for (int rg = 0; rg < 4; ++rg){
                int row = mt*64 + wm*32 + mi*16 + crow4 + rg;
                int col = nt*128 + wn*64 + ni*16 + lr;
                float v = acc[mi][ni][rg];
                if (CORR) v -= ((row + col) & 1) ? -cc : cc;
                outp[((size_t)row << 9) + col] = v;
            }
}

// K8: transpose Y -> YT hi/lo bf16
__global__ __launch_bounds__(256) void k_transpose2(const float* __restrict__ Y,
                                                    unsigned short* __restrict__ Thi,
                                                    unsigned short* __restrict__ Tlo, int b0){
    int lb = blockIdx.x >> 8, tb = blockIdx.x & 255;
    int tx = (tb & 15) << 5, ty = ((tb >> 4) & 15) << 5;
    const float* src = Y + (((size_t)(b0 + lb)) << 18);
    unsigned short* dh = Thi + (((size_t)lb) << 18);
    unsigned short* dl = Tlo + (((size_t)lb) << 18);
    __shared__ float tile[32][33];
    int col = threadIdx.x & 31, rw = threadIdx.x >> 5;
    #pragma unroll
    for (int k = 0; k < 4; ++k){
        int ry = rw + k*8;
        tile[ry][col] = src[((size_t)(ty + ry) << 9) + tx + col];
    }
    __syncthreads();
    #pragma unroll
    for (int k = 0; k < 4; ++k){
        int ry = rw + k*8;
        float v = tile[col][ry];
        unsigned short h = f2bf(v);
        size_t o = ((size_t)(tx + ry) << 9) + ty + col;
        dh[o] = h;
        dl[o] = f2bf(v - bf2f(h));
    }
}

extern "C" void kernel_launch(void* const* d_in, const int* in_sizes, int n_in,
                              void* d_out, int out_size, void* d_ws, size_t ws_size,
                              hipStream_t stream){
    (void)in_sizes; (void)n_in; (void)out_size;
    const float* fr  = (const float*)d_in[0];
    const float* tpl = (const float*)d_in[1];
    float* out = (float*)d_out;
    char* ws = (char*)d_ws;

    double* stats  = (double*)(ws + 0);
    double* spart  = (double*)(ws + 64);
    double* den    = (double*)(ws + 2048);
    double* snnp   = (double*)(ws + 33280);
    double* shx    = (double*)(ws + 35328);
    double* shy    = (double*)(ws + 35584);
    float*  c2     = (float*) (ws + 35840);
    float*  part   = (float*) (ws + 36096);
    unsigned short* gtab = (unsigned short*)(ws + 1027328);
    unsigned short* tsp  = (unsigned short*)(ws + 1158400);
    float*  csum   = (float*) (ws + 2206976);
    float*  csum2  = (float*) (ws + 2731264);

    const size_t CB = 3255552;
    long long avail = ((long long)ws_size - (long long)CB) / (4ll << 20);
    int NC = (int)avail; if (NC > 32) NC = 32; if (NC < 1) NC = 1;
    if (NC >= 8) NC &= ~7;
    int swz = (NC % 8 == 0) ? 1 : 0;

    unsigned short* Xhi  = (unsigned short*)(ws + CB);
    unsigned short* Xlo  = Xhi  + (size_t)NC*262144;
    unsigned short* YThi = Xlo  + (size_t)NC*262144;
    unsigned short* YTlo = YThi + (size_t)NC*262144;
    unsigned short* Bym  = YTlo + (size_t)NC*262144;
    unsigned short* Bxm  = Bym  + (size_t)NC*524288;

    k_stats_part<<<64, 256, 0, stream>>>(tpl, spart);
    k_stats_final<<<1, 64, 0, stream>>>(spart, stats);
    k_tsplit<<<256, 256, 0, stream>>>(tpl, stats, tsp);
    k_colsums<<<256, 256, 0, stream>>>(fr, csum, csum2, snnp);
    k_winfin<<<32, 256, 0, stream>>>(fr, csum, csum2, stats, den);
    k_ncc<<<2048, 256, 0, stream>>>(fr, tsp, part);
    k_shifts<<<32, 128, 0, stream>>>(part, den, snnp, shx, shy, c2);
    k_tables<<<32, 256, 0, stream>>>(shx, shy, gtab);

    for (int b0 = 0; b0 < 32; b0 += NC){
        int nb = (32 - b0 < NC) ? (32 - b0) : NC;
        int sw = (swz && (nb % 8 == 0)) ? 1 : 0;
        k_splitx<<<nb*16, 256, 0, stream>>>(fr, Xhi, Xlo, b0);
        k_bmat<<<nb*32, 256, 0, stream>>>(gtab, Bym, Bxm, b0);
        k_gemm<0><<<nb*32, 256, 0, stream>>>(Xhi, Xlo, Bym, out, (const float*)nullptr, b0, sw);
        k_transpose2<<<nb*256, 256, 0, stream>>>(out, YThi, YTlo, b0);
        k_gemm<1><<<nb*32, 256, 0, stream>>>(YThi, YTlo, Bxm, out, c2, b0, sw);
    }
}

// Round 12
// 182.293 us; speedup vs baseline: 3.4539x; 1.2421x over previous
//
#include <hip/hip_runtime.h>
#include <hip/hip_bf16.h>
#include <math.h>

#define NPIX 262144          // 512*512
#define PI_D 3.14159265358979323846264338327950288

typedef __attribute__((ext_vector_type(8))) short v8s;           // bf16x8 MFMA fragment
typedef __attribute__((ext_vector_type(4))) float v4f;           // f32x4 accumulator
typedef __attribute__((ext_vector_type(4))) unsigned short v4u;

// ---------------- ws layout (byte offsets) ----------------
// 0        double stats[2]
// 64       double spart[64][2]
// 2048     double den[32][121]
// 33280    double snn_part[32][8]
// 35328    double shx[32]
// 35584    double shy[32]
// 35840    float  c2[32]
// 36096    float  partial[32][64][121]          ends 1,027,328
// 1027328  ushort gtab[32][2][2][512]           ends 1,158,400
// 1158400  ushort tsp[2][512][512]              ends 2,206,976
// 2206976  float  csum[32][8][512]              ends 2,731,264
// 2731264  float  csum2[32][8][512]             ends 3,255,552
// 3255552  chunk area: per image 2 MB (Xhi/Xlo/YThi/YTlo 512KB each)

__device__ inline unsigned short f2bf(float x){
    unsigned u = __float_as_uint(x);
    return (unsigned short)((u + 0x7FFFu + ((u >> 16) & 1u)) >> 16);   // RNE
}
__device__ inline float bf2f(unsigned short h){ return __uint_as_float(((unsigned)h) << 16); }

// K1a: template partial sums
__global__ __launch_bounds__(256) void k_stats_part(const float* __restrict__ t, double* __restrict__ part){
    int base = blockIdx.x * 4096;
    double s = 0.0, s2 = 0.0;
    #pragma unroll
    for (int k = 0; k < 4; ++k){
        float4 v = *(const float4*)&t[base + k*1024 + threadIdx.x*4];
        s  += (double)v.x + (double)v.y + (double)v.z + (double)v.w;
        s2 += (double)v.x*v.x + (double)v.y*v.y + (double)v.z*v.z + (double)v.w*v.w;
    }
    __shared__ double rs[256], rs2[256];
    rs[threadIdx.x] = s; rs2[threadIdx.x] = s2; __syncthreads();
    for (int off = 128; off > 0; off >>= 1){
        if (threadIdx.x < off){ rs[threadIdx.x] += rs[threadIdx.x+off]; rs2[threadIdx.x] += rs2[threadIdx.x+off]; }
        __syncthreads();
    }
    if (threadIdx.x == 0){ part[blockIdx.x*2] = rs[0]; part[blockIdx.x*2+1] = rs2[0]; }
}

__global__ __launch_bounds__(64) void k_stats_final(const double* __restrict__ part, double* __restrict__ stats){
    double s = part[threadIdx.x*2], s2 = part[threadIdx.x*2+1];
    #pragma unroll
    for (int off = 32; off > 0; off >>= 1){
        s  += __shfl_down(s, off);
        s2 += __shfl_down(s2, off);
    }
    if (threadIdx.x == 0){
        stats[0] = s / (double)NPIX;
        stats[1] = s2 - s*s/(double)NPIX + 1e-8;
    }
}

// K1c: template -> zero-mean bf16 hi/lo
__global__ __launch_bounds__(256) void k_tsplit(const float* __restrict__ tpl, const double* __restrict__ stats,
                                                unsigned short* __restrict__ tsp){
    float mean = (float)stats[0];
    int base = blockIdx.x * 1024 + threadIdx.x * 4;
    float4 v = *(const float4*)&tpl[base];
    v.x -= mean; v.y -= mean; v.z -= mean; v.w -= mean;
    unsigned short h0 = f2bf(v.x), h1 = f2bf(v.y), h2 = f2bf(v.z), h3 = f2bf(v.w);
    v4u hv = {h0, h1, h2, h3};
    v4u lv = {f2bf(v.x - bf2f(h0)), f2bf(v.y - bf2f(h1)), f2bf(v.z - bf2f(h2)), f2bf(v.w - bf2f(h3))};
    *(v4u*)&tsp[base] = hv;
    *(v4u*)&tsp[262144 + base] = lv;
}

// K2a: per-chunk column sums + Nyquist alternating sum
__global__ __launch_bounds__(256) void k_colsums(const float* __restrict__ fr, float* __restrict__ csum,
                                                 float* __restrict__ csum2, double* __restrict__ snn_part){
    int b = blockIdx.x >> 3, chunk = blockIdx.x & 7;
    const float* img = fr + (size_t)b * NPIX + (size_t)chunk * (64*512);
    int t = threadIdx.x;
    float a0=0.f, q0=0.f, a1=0.f, q1=0.f;
    double sn = 0.0;
    for (int r = 0; r < 64; ++r){
        float v0 = img[(r<<9) + t];
        float v1 = img[(r<<9) + t + 256];
        a0 += v0; q0 += v0*v0; a1 += v1; q1 += v1*v1;
        float sv = v0 + v1;
        sn += ((r + t) & 1) ? -(double)sv : (double)sv;
    }
    size_t o = ((size_t)(b*8 + chunk) << 9) + t;
    csum[o] = a0;  csum[o + 256] = a1;
    csum2[o] = q0; csum2[o + 256] = q1;
    __shared__ double rs[256];
    rs[t] = sn; __syncthreads();
    for (int off = 128; off > 0; off >>= 1){
        if (t < off) rs[t] += rs[t+off];
        __syncthreads();
    }
    if (t == 0) snn_part[b*8 + chunk] = rs[0];
}

// K2b: finalize 121 window denominators
__global__ __launch_bounds__(256) void k_winfin(const float* __restrict__ fr, const float* __restrict__ csum,
                                                const float* __restrict__ csum2, const double* __restrict__ stats,
                                                double* __restrict__ den){
    int b = blockIdx.x;
    const float* img = fr + (size_t)b * NPIX;
    __shared__ double fc[512], fc2[512];
    __shared__ double rsum[20], rsum2[20];
    __shared__ float E[20][20], E2[20][20];
    __shared__ double red[256], red2[256];
    int t = threadIdx.x;
    for (int c = t; c < 512; c += 256){
        double s = 0.0, s2 = 0.0;
        for (int k = 0; k < 8; ++k){
            size_t o = ((size_t)(b*8 + k) << 9) + c;
            s += (double)csum[o]; s2 += (double)csum2[o];
        }
        fc[c] = s; fc2[c] = s2;
    }
    if (t < 400){
        int i = t / 20, j = t % 20;
        int row = (i < 10) ? i : (i + 492);
        int col = (j < 10) ? j : (j + 492);
        float v = img[(row<<9) + col];
        E[i][j] = v; E2[i][j] = v*v;
    }
    __syncthreads();
    red[t] = fc[t] + fc[t+256];
    red2[t] = fc2[t] + fc2[t+256];
    __syncthreads();
    for (int off = 128; off > 0; off >>= 1){
        if (t < off){ red[t] += red[t+off]; red2[t] += red2[t+off]; }
        __syncthreads();
    }
    double F1 = red[0], F2 = red2[0];
    int lane = t & 63, wv = t >> 6;
    for (int e = wv; e < 20; e += 4){
        int row = (e < 10) ? e : (e + 492);
        double s = 0.0, s2 = 0.0;
        for (int c = lane; c < 512; c += 64){
            float v = img[(row<<9) + c];
            s += v; s2 += (double)v*v;
        }
        #pragma unroll
        for (int off = 32; off > 0; off >>= 1){ s += __shfl_down(s, off); s2 += __shfl_down(s2, off); }
        if (lane == 0){ rsum[e] = s; rsum2[e] = s2; }
    }
    __syncthreads();
    if (t < 121){
        int u = t / 11, v = t % 11;
        double S1 = F1, S2 = F2;
        for (int i = 0; i < u; ++i){ S1 -= rsum[i]; S2 -= rsum2[i]; }
        for (int k = 10+u; k < 20; ++k){ S1 -= rsum[k]; S2 -= rsum2[k]; }
        for (int j = 0; j < v; ++j){
            double cw = fc[j], cq = fc2[j];
            for (int i = 0; i < u; ++i){ cw -= E[i][j]; cq -= E2[i][j]; }
            for (int k = 10+u; k < 20; ++k){ cw -= E[k][j]; cq -= E2[k][j]; }
            S1 -= cw; S2 -= cq;
        }
        for (int jj = 10+v; jj < 20; ++jj){
            int col = jj + 492;
            double cw = fc[col], cq = fc2[col];
            for (int i = 0; i < u; ++i){ cw -= E[i][jj]; cq -= E2[i][jj]; }
            for (int k = 10+u; k < 20; ++k){ cw -= E[k][jj]; cq -= E2[k][jj]; }
            S1 -= cw; S2 -= cq;
        }
        const double K = 502.0*502.0;
        double ivar = S2/K - (S1*S1)/(K*K*K) + 1e-8;
        if (ivar < 0.0) ivar = 0.0;
        den[b*121 + u*11 + v] = sqrt(stats[1] * ivar);
    }
}

// K3: MFMA NCC (R10 structure, verified)
__global__ __launch_bounds__(256, 2) void k_ncc(const float* __restrict__ fr,
                                                const unsigned short* __restrict__ tsp,
                                                float* __restrict__ partial){
    int b = blockIdx.x >> 6, chunk = blockIdx.x & 63;
    int i0 = chunk << 3;
    int tid = threadIdx.x;
    __shared__ unsigned short Th[24][520], Tl[24][520];
    __shared__ unsigned short Xh[8][544], Xl[8][544];
    __shared__ float Dred[4][16][16];
    for (int q = tid; q < 1536; q += 256){
        int r = q >> 6, c8 = (q & 63) << 3;
        int grow = (i0 - 5 + r + 512) & 511;
        *(float4*)&Th[r][c8] = *(const float4*)&tsp[((size_t)grow << 9) + c8];
        *(float4*)&Tl[r][c8] = *(const float4*)&tsp[262144 + ((size_t)grow << 9) + c8];
    }
    const float* img = fr + ((size_t)b << 18);
    for (int q = tid; q < 1088; q += 256){
        int r = q / 136, qq = q - r*136;
        int col = ((qq << 2) - 16) & 511;
        float4 v = *(const float4*)&img[((size_t)(i0 + r) << 9) + col];
        unsigned short h0 = f2bf(v.x), h1 = f2bf(v.y), h2 = f2bf(v.z), h3 = f2bf(v.w);
        v4u hv = {h0, h1, h2, h3};
        v4u lv = {f2bf(v.x - bf2f(h0)), f2bf(v.y - bf2f(h1)), f2bf(v.z - bf2f(h2)), f2bf(v.w - bf2f(h3))};
        *(v4u*)&Xh[r][qq << 2] = hv;
        *(v4u*)&Xl[r][qq << 2] = lv;
    }
    __syncthreads();
    int l = tid & 63, wv = tid >> 6;
    int lr = l & 15, lk = l >> 4;
    v4f acc = (v4f){0.f, 0.f, 0.f, 0.f};
    union UB { unsigned u[4]; v8s s; };
    int sbase = (lk << 3) - lr + 21;
    unsigned sh = (unsigned)((sbase & 1) << 4);
    #pragma unroll
    for (int ii = 0; ii < 2; ++ii){
        int ro = 2*wv + ii;
        const unsigned* xh32 = (const unsigned*)&Xh[ro][0];
        const unsigned* xl32 = (const unsigned*)&Xl[ro][0];
        #pragma unroll 1
        for (int ks = 0; ks < 16; ++ks){
            int ka = (ks << 5) + (lk << 3);
            v8s ah = *(v8s*)&Th[ro + lr][ka];
            v8s al = *(v8s*)&Tl[ro + lr][ka];
            int W = ((ks << 5) + sbase) >> 1;
            unsigned wh[5], wl[5];
            #pragma unroll
            for (int j = 0; j < 5; ++j){ wh[j] = xh32[W + j]; wl[j] = xl32[W + j]; }
            UB bh, bl;
            #pragma unroll
            for (int j = 0; j < 4; ++j){
                bh.u[j] = __builtin_amdgcn_alignbit(wh[j+1], wh[j], sh);
                bl.u[j] = __builtin_amdgcn_alignbit(wl[j+1], wl[j], sh);
            }
            acc = __builtin_amdgcn_mfma_f32_16x16x32_bf16(ah, bh.s, acc, 0, 0, 0);
            acc = __builtin_amdgcn_mfma_f32_16x16x32_bf16(al, bh.s, acc, 0, 0, 0);
            acc = __builtin_amdgcn_mfma_f32_16x16x32_bf16(ah, bl.s, acc, 0, 0, 0);
        }
    }
    #pragma unroll
    for (int r = 0; r < 4; ++r) Dred[wv][4*lk + r][lr] = acc[r];
    __syncthreads();
    if (tid < 121){
        int s0 = tid / 11, s1 = tid - s0*11;
        int dy = 10 - s0, dx = 10 - s1;
        partial[(size_t)(b*64 + chunk)*121 + tid] =
            Dred[0][dy][dx] + Dred[1][dy][dx] + Dred[2][dy][dx] + Dred[3][dy][dx];
    }
}

// K4: ncc finalize -> shifts, c2
__global__ __launch_bounds__(128) void k_shifts(const float* __restrict__ partial, const double* __restrict__ den,
                                                const double* __restrict__ snn_part, double* __restrict__ shx,
                                                double* __restrict__ shy, float* __restrict__ c2){
    int b = blockIdx.x;
    __shared__ double l[121], nc[121];
    for (int e = threadIdx.x; e < 121; e += 128){
        double s = 0.0;
        for (int c = 0; c < 64; ++c) s += (double)partial[(size_t)(b*64 + c)*121 + e];
        double nom = fabs(s);
        double v = nom / den[b*121 + e];
        if (v != v) v = 0.0;
        nc[e] = v;
        l[e] = log(v);
    }
    __syncthreads();
    if (threadIdx.x == 0){
        int am = 0; double best = nc[0];
        for (int e = 1; e < 121; ++e) if (nc[e] > best){ best = nc[e]; am = e; }
        int u = am / 11, v = am % 11;
        double sx = -(double)(u - 5), sy = -(double)(v - 5);
        int um1 = u - 1; if (um1 < 0) um1 += 11; if (um1 > 10) um1 = 10;
        int up1 = u + 1; if (up1 > 10) up1 = 10;
        int vm1 = v - 1; if (vm1 < 0) vm1 += 11; if (vm1 > 10) vm1 = 10;
        int vp1 = v + 1; if (vp1 > 10) vp1 = 10;
        double l0x4 = 4.0 * l[u*11 + v];
        double lm = l[um1*11 + v], lp = l[up1*11 + v];
        sx -= (lm - lp) / (2.0*lm - l0x4 + 2.0*lp);
        double lm2 = l[u*11 + vm1], lp2 = l[u*11 + vp1];
        sy -= (lm2 - lp2) / (2.0*lm2 - l0x4 + 2.0*lp2);
        shx[b] = sx; shy[b] = sy;
        double snn = 0.0;
        for (int c = 0; c < 8; ++c) snn += snn_part[b*8 + c];
        double kx = sin(PI_D * sx) / 512.0, ky = sin(PI_D * sy) / 512.0;
        c2[b] = (float)(kx * ky * snn);
    }
}

__device__ inline double grekern(int t, double s){
    double u = (double)t - s;
    if (u > 256.0) u -= 512.0;
    double a = PI_D * u / 512.0;
    double sp = sin(a);
    double D;
    if (fabs(sp) < 1e-12) D = cos(PI_D * u) / cos(a);
    else D = sin(PI_D * u) / (512.0 * sp);
    return D * cos(a);
}

// K4b: Dirichlet kernels -> bf16 hi/lo tables
__global__ __launch_bounds__(256) void k_tables(const double* __restrict__ shx, const double* __restrict__ shy,
                                                unsigned short* __restrict__ gtab){
    int b = blockIdx.x;
    double sx = shx[b], sy = shy[b];
    unsigned short* g = gtab + ((size_t)b << 11);
    for (int t = threadIdx.x; t < 512; t += 256){
        float gy = (float)grekern(t, sy);
        float gx = (float)grekern(t, sx);
        unsigned short yh = f2bf(gy); unsigned short yl = f2bf(gy - bf2f(yh));
        unsigned short xh = f2bf(gx); unsigned short xl = f2bf(gx - bf2f(xh));
        g[t] = yh; g[512 + t] = yl; g[1024 + t] = xh; g[1536 + t] = xl;
    }
}

// K5: split X -> Xhi/Xlo bf16, chunk-local
__global__ __launch_bounds__(256) void k_splitx(const float* __restrict__ fr, unsigned short* __restrict__ Xhi,
                                                unsigned short* __restrict__ Xlo, int b0){
    int lb = blockIdx.x >> 4, blk = blockIdx.x & 15;
    const float* src = fr + (((size_t)(b0 + lb)) << 18) + blk*16384;
    unsigned short* dh = Xhi + (((size_t)lb) << 18) + blk*16384;
    unsigned short* dl = Xlo + (((size_t)lb) << 18) + blk*16384;
    for (int i = threadIdx.x; i < 4096; i += 256){
        float4 v = ((const float4*)src)[i];
        v4u hv, lv;
        unsigned short h;
        h = f2bf(v.x); hv.x = h; lv.x = f2bf(v.x - bf2f(h));
        h = f2bf(v.y); hv.y = h; lv.y = f2bf(v.y - bf2f(h));
        h = f2bf(v.z); hv.z = h; lv.z = f2bf(v.z - bf2f(h));
        h = f2bf(v.w); hv.w = h; lv.w = f2bf(v.w - bf2f(h));
        *(v4u*)&dh[4*i] = hv;
        *(v4u*)&dl[4*i] = lv;
    }
}

// K7: MFMA circulant GEMM v2 (fixed).  BM=128, BN=128, single K-pass, 3-MFMA hi/lo fusion,
// B generated on-the-fly from reversed+duplicated Dirichlet table via alignbit.
// FIX vs R11: A-tile stride 36 -> 40 ushorts (80 B = 16B multiple; stride-36 rows broke
// ds_read_b128 alignment on odd rows -> wrong A data).  B-frags hoisted before mi-loop
// to cap live registers; no forced occupancy bound.
template<int CORR>
__global__ __launch_bounds__(256) void k_gemm(const unsigned short* __restrict__ Ahi,
                                              const unsigned short* __restrict__ Alo,
                                              const unsigned short* __restrict__ gtab, int axis,
                                              float* __restrict__ Cout,
                                              const float* __restrict__ c2, int b0, int swz){
    int bid = blockIdx.x;
    int lb, tile;
    if (swz){ int x = bid & 7; int r = bid >> 3; lb = (r >> 4)*8 + x; tile = r & 15; }
    else    { lb = bid >> 4; tile = bid & 15; }
    int mt = tile >> 2, nt = tile & 3;
    int tid = threadIdx.x;
    __shared__ unsigned short Ath[128][40], Atl[128][40];   // 80B rows: 16B-aligned b128 reads
    __shared__ unsigned short grh[1024], grl[1024];         // reversed + duplicated table
    int bg = b0 + lb;
    const unsigned short* gax = gtab + ((size_t)bg << 11) + (axis << 10);
    for (int i = tid; i < 1024; i += 256){
        int src = (512 - (i & 511)) & 511;
        grh[i] = gax[src];
        grl[i] = gax[512 + src];
    }
    v4f acc[4][4];
    #pragma unroll
    for (int mi = 0; mi < 4; ++mi)
        #pragma unroll
        for (int ni = 0; ni < 4; ++ni) acc[mi][ni] = (v4f){0.f, 0.f, 0.f, 0.f};
    const unsigned short* Aph = Ahi + ((size_t)lb << 18) + (size_t)mt*128*512;
    const unsigned short* Apl = Alo + ((size_t)lb << 18) + (size_t)mt*128*512;
    int l = tid & 63, wv = tid >> 6;
    int wm = wv >> 1, wn = wv & 1;
    int lr = l & 15, lk = l >> 4;
    int colb = nt*128 + wn*64 + lr;                 // + ni*16
    unsigned sh = (unsigned)((colb & 1) << 4);      // parity fixed per thread
    int srow = tid >> 1, sc = (tid & 1) << 4;       // staging map
    const unsigned* grh32 = (const unsigned*)grh;
    const unsigned* grl32 = (const unsigned*)grl;
    union UB { unsigned u[4]; v8s s; };
    #pragma unroll 1
    for (int ks = 0; ks < 16; ++ks){
        __syncthreads();
        { size_t go = (size_t)srow*512 + (ks << 5) + sc;
          *(float4*)&Ath[srow][sc]     = *(const float4*)&Aph[go];
          *(float4*)&Ath[srow][sc + 8] = *(const float4*)&Aph[go + 8];
          *(float4*)&Atl[srow][sc]     = *(const float4*)&Apl[go];
          *(float4*)&Atl[srow][sc + 8] = *(const float4*)&Apl[go + 8]; }
        __syncthreads();
        // build all 4 B hi/lo fragments first (statically indexed; reduces peak live regs)
        v8s bhs[4], bls[4];
        #pragma unroll
        for (int ni = 0; ni < 4; ++ni){
            int f = ((ks << 5) + (lk << 3) - (colb + ni*16)) & 511;
            int W = f >> 1;
            unsigned wh[5], wl[5];
            #pragma unroll
            for (int j = 0; j < 5; ++j){ wh[j] = grh32[W + j]; wl[j] = grl32[W + j]; }
            UB bh, bl;
            #pragma unroll
            for (int j = 0; j < 4; ++j){
                bh.u[j] = __builtin_amdgcn_alignbit(wh[j+1], wh[j], sh);
                bl.u[j] = __builtin_amdgcn_alignbit(wl[j+1], wl[j], sh);
            }
            bhs[ni] = bh.s; bls[ni] = bl.s;
        }
        #pragma unroll
        for (int mi = 0; mi < 4; ++mi){
            int row = wm*64 + mi*16 + lr;
            v8s ah = *(v8s*)&Ath[row][lk*8];
            v8s al = *(v8s*)&Atl[row][lk*8];
            #pragma unroll
            for (int ni = 0; ni < 4; ++ni){
                acc[mi][ni] = __builtin_amdgcn_mfma_f32_16x16x32_bf16(ah, bhs[ni], acc[mi][ni], 0, 0, 0);
                acc[mi][ni] = __builtin_amdgcn_mfma_f32_16x16x32_bf16(al, bhs[ni], acc[mi][ni], 0, 0, 0);
                acc[mi][ni] = __builtin_amdgcn_mfma_f32_16x16x32_bf16(ah, bls[ni], acc[mi][ni], 0, 0, 0);
            }
        }
    }
    float cc = CORR ? c2[bg] : 0.f;
    float* outp = Cout + ((size_t)bg << 18);
    int crow4 = lk * 4;
    #pragma unroll
    for (int mi = 0; mi < 4; ++mi)
        #pragma unroll
        for (int ni = 0; ni < 4; ++ni)
            #pragma unroll
            for (int rg = 0; rg < 4; ++rg){
                int row = mt*128 + wm*64 + mi*16 + crow4 + rg;
                int col = nt*128 + wn*64 + ni*16 + lr;
                float v = acc[mi][ni][rg];
                if (CORR) v -= ((row + col) & 1) ? -cc : cc;
                outp[((size_t)row << 9) + col] = v;
            }
}

// K8: transpose Y -> YT hi/lo bf16
__global__ __launch_bounds__(256) void k_transpose2(const float* __restrict__ Y,
                                                    unsigned short* __restrict__ Thi,
                                                    unsigned short* __restrict__ Tlo, int b0){
    int lb = blockIdx.x >> 8, tb = blockIdx.x & 255;
    int tx = (tb & 15) << 5, ty = ((tb >> 4) & 15) << 5;
    const float* src = Y + (((size_t)(b0 + lb)) << 18);
    unsigned short* dh = Thi + (((size_t)lb) << 18);
    unsigned short* dl = Tlo + (((size_t)lb) << 18);
    __shared__ float tile[32][33];
    int col = threadIdx.x & 31, rw = threadIdx.x >> 5;
    #pragma unroll
    for (int k = 0; k < 4; ++k){
        int ry = rw + k*8;
        tile[ry][col] = src[((size_t)(ty + ry) << 9) + tx + col];
    }
    __syncthreads();
    #pragma unroll
    for (int k = 0; k < 4; ++k){
        int ry = rw + k*8;
        float v = tile[col][ry];
        unsigned short h = f2bf(v);
        size_t o = ((size_t)(tx + ry) << 9) + ty + col;
        dh[o] = h;
        dl[o] = f2bf(v - bf2f(h));
    }
}

extern "C" void kernel_launch(void* const* d_in, const int* in_sizes, int n_in,
                              void* d_out, int out_size, void* d_ws, size_t ws_size,
                              hipStream_t stream){
    (void)in_sizes; (void)n_in; (void)out_size;
    const float* fr  = (const float*)d_in[0];
    const float* tpl = (const float*)d_in[1];
    float* out = (float*)d_out;
    char* ws = (char*)d_ws;

    double* stats  = (double*)(ws + 0);
    double* spart  = (double*)(ws + 64);
    double* den    = (double*)(ws + 2048);
    double* snnp   = (double*)(ws + 33280);
    double* shx    = (double*)(ws + 35328);
    double* shy    = (double*)(ws + 35584);
    float*  c2     = (float*) (ws + 35840);
    float*  part   = (float*) (ws + 36096);
    unsigned short* gtab = (unsigned short*)(ws + 1027328);
    unsigned short* tsp  = (unsigned short*)(ws + 1158400);
    float*  csum   = (float*) (ws + 2206976);
    float*  csum2  = (float*) (ws + 2731264);

    const size_t CB = 3255552;
    long long avail = ((long long)ws_size - (long long)CB) / (2ll << 20);
    int NC = (int)avail; if (NC > 32) NC = 32; if (NC < 1) NC = 1;
    if (NC >= 8) NC &= ~7;
    int swz = (NC % 8 == 0) ? 1 : 0;

    unsigned short* Xhi  = (unsigned short*)(ws + CB);
    unsigned short* Xlo  = Xhi  + (size_t)NC*262144;
    unsigned short* YThi = Xlo  + (size_t)NC*262144;
    unsigned short* YTlo = YThi + (size_t)NC*262144;

    k_stats_part<<<64, 256, 0, stream>>>(tpl, spart);
    k_stats_final<<<1, 64, 0, stream>>>(spart, stats);
    k_tsplit<<<256, 256, 0, stream>>>(tpl, stats, tsp);
    k_colsums<<<256, 256, 0, stream>>>(fr, csum, csum2, snnp);
    k_winfin<<<32, 256, 0, stream>>>(fr, csum, csum2, stats, den);
    k_ncc<<<2048, 256, 0, stream>>>(fr, tsp, part);
    k_shifts<<<32, 128, 0, stream>>>(part, den, snnp, shx, shy, c2);
    k_tables<<<32, 256, 0, stream>>>(shx, shy, gtab);

    for (int b0 = 0; b0 < 32; b0 += NC){
        int nb = (32 - b0 < NC) ? (32 - b0) : NC;
        int sw = (swz && (nb % 8 == 0)) ? 1 : 0;
        k_splitx<<<nb*16, 256, 0, stream>>>(fr, Xhi, Xlo, b0);
        // stage 1: Y = X * Gy -> d_out (f32 scratch)
        k_gemm<0><<<nb*16, 256, 0, stream>>>(Xhi, Xlo, gtab, 0, out, (const float*)nullptr, b0, sw);
        // transpose + split: YT hi/lo
        k_transpose2<<<nb*256, 256, 0, stream>>>(out, YThi, YTlo, b0);
        // stage 2: Out = YT * Gx - c2*(-1)^(p+q) -> d_out (final)
        k_gemm<1><<<nb*16, 256, 0, stream>>>(YThi, YTlo, gtab, 1, out, c2, b0, sw);
    }
}

// Round 14
// 177.683 us; speedup vs baseline: 3.5435x; 1.0259x over previous
//
#include <hip/hip_runtime.h>
#include <hip/hip_bf16.h>
#include <math.h>

#define NPIX 262144          // 512*512
#define PI_D 3.14159265358979323846264338327950288

typedef __attribute__((ext_vector_type(8))) short v8s;           // bf16x8 MFMA fragment
typedef __attribute__((ext_vector_type(4))) float v4f;           // f32x4 accumulator
typedef __attribute__((ext_vector_type(4))) unsigned short v4u;

// ---------------- ws layout (byte offsets) ----------------
// 0        double stats[2]
// 64       double spart[64][2]
// 2048     double den[32][121]
// 33280    double snn_part[32][8]
// 35328    double shx[32]
// 35584    double shy[32]
// 35840    float  c2[32]
// 36096    float  partial[32][64][121]          ends 1,027,328
// 1027328  ushort gtab[32][2][2][512]           ends 1,158,400
// 1158400  ushort tsp[2][512][512]              ends 2,206,976
// 2206976  float  csum[32][8][512]              ends 2,731,264
// 2731264  float  csum2[32][8][512]             ends 3,255,552
// 3255552  chunk area: per image 1 MB (YThi/YTlo 512KB each)

__device__ inline unsigned short f2bf(float x){
    unsigned u = __float_as_uint(x);
    return (unsigned short)((u + 0x7FFFu + ((u >> 16) & 1u)) >> 16);   // RNE
}
__device__ inline float bf2f(unsigned short h){ return __uint_as_float(((unsigned)h) << 16); }

// K1a: template partial sums
__global__ __launch_bounds__(256) void k_stats_part(const float* __restrict__ t, double* __restrict__ part){
    int base = blockIdx.x * 4096;
    double s = 0.0, s2 = 0.0;
    #pragma unroll
    for (int k = 0; k < 4; ++k){
        float4 v = *(const float4*)&t[base + k*1024 + threadIdx.x*4];
        s  += (double)v.x + (double)v.y + (double)v.z + (double)v.w;
        s2 += (double)v.x*v.x + (double)v.y*v.y + (double)v.z*v.z + (double)v.w*v.w;
    }
    __shared__ double rs[256], rs2[256];
    rs[threadIdx.x] = s; rs2[threadIdx.x] = s2; __syncthreads();
    for (int off = 128; off > 0; off >>= 1){
        if (threadIdx.x < off){ rs[threadIdx.x] += rs[threadIdx.x+off]; rs2[threadIdx.x] += rs2[threadIdx.x+off]; }
        __syncthreads();
    }
    if (threadIdx.x == 0){ part[blockIdx.x*2] = rs[0]; part[blockIdx.x*2+1] = rs2[0]; }
}

__global__ __launch_bounds__(64) void k_stats_final(const double* __restrict__ part, double* __restrict__ stats){
    double s = part[threadIdx.x*2], s2 = part[threadIdx.x*2+1];
    #pragma unroll
    for (int off = 32; off > 0; off >>= 1){
        s  += __shfl_down(s, off);
        s2 += __shfl_down(s2, off);
    }
    if (threadIdx.x == 0){
        stats[0] = s / (double)NPIX;
        stats[1] = s2 - s*s/(double)NPIX + 1e-8;
    }
}

// K1c: template -> zero-mean bf16 hi/lo
__global__ __launch_bounds__(256) void k_tsplit(const float* __restrict__ tpl, const double* __restrict__ stats,
                                                unsigned short* __restrict__ tsp){
    float mean = (float)stats[0];
    int base = blockIdx.x * 1024 + threadIdx.x * 4;
    float4 v = *(const float4*)&tpl[base];
    v.x -= mean; v.y -= mean; v.z -= mean; v.w -= mean;
    unsigned short h0 = f2bf(v.x), h1 = f2bf(v.y), h2 = f2bf(v.z), h3 = f2bf(v.w);
    v4u hv = {h0, h1, h2, h3};
    v4u lv = {f2bf(v.x - bf2f(h0)), f2bf(v.y - bf2f(h1)), f2bf(v.z - bf2f(h2)), f2bf(v.w - bf2f(h3))};
    *(v4u*)&tsp[base] = hv;
    *(v4u*)&tsp[262144 + base] = lv;
}

// K2a: per-chunk column sums + Nyquist alternating sum
__global__ __launch_bounds__(256) void k_colsums(const float* __restrict__ fr, float* __restrict__ csum,
                                                 float* __restrict__ csum2, double* __restrict__ snn_part){
    int b = blockIdx.x >> 3, chunk = blockIdx.x & 7;
    const float* img = fr + (size_t)b * NPIX + (size_t)chunk * (64*512);
    int t = threadIdx.x;
    float a0=0.f, q0=0.f, a1=0.f, q1=0.f;
    double sn = 0.0;
    for (int r = 0; r < 64; ++r){
        float v0 = img[(r<<9) + t];
        float v1 = img[(r<<9) + t + 256];
        a0 += v0; q0 += v0*v0; a1 += v1; q1 += v1*v1;
        float sv = v0 + v1;
        sn += ((r + t) & 1) ? -(double)sv : (double)sv;
    }
    size_t o = ((size_t)(b*8 + chunk) << 9) + t;
    csum[o] = a0;  csum[o + 256] = a1;
    csum2[o] = q0; csum2[o + 256] = q1;
    __shared__ double rs[256];
    rs[t] = sn; __syncthreads();
    for (int off = 128; off > 0; off >>= 1){
        if (t < off) rs[t] += rs[t+off];
        __syncthreads();
    }
    if (t == 0) snn_part[b*8 + chunk] = rs[0];
}

// K2b: finalize 121 window denominators
__global__ __launch_bounds__(256) void k_winfin(const float* __restrict__ fr, const float* __restrict__ csum,
                                                const float* __restrict__ csum2, const double* __restrict__ stats,
                                                double* __restrict__ den){
    int b = blockIdx.x;
    const float* img = fr + (size_t)b * NPIX;
    __shared__ double fc[512], fc2[512];
    __shared__ double rsum[20], rsum2[20];
    __shared__ float E[20][20], E2[20][20];
    __shared__ double red[256], red2[256];
    int t = threadIdx.x;
    for (int c = t; c < 512; c += 256){
        double s = 0.0, s2 = 0.0;
        for (int k = 0; k < 8; ++k){
            size_t o = ((size_t)(b*8 + k) << 9) + c;
            s += (double)csum[o]; s2 += (double)csum2[o];
        }
        fc[c] = s; fc2[c] = s2;
    }
    if (t < 400){
        int i = t / 20, j = t % 20;
        int row = (i < 10) ? i : (i + 492);
        int col = (j < 10) ? j : (j + 492);
        float v = img[(row<<9) + col];
        E[i][j] = v; E2[i][j] = v*v;
    }
    __syncthreads();
    red[t] = fc[t] + fc[t+256];
    red2[t] = fc2[t] + fc2[t+256];
    __syncthreads();
    for (int off = 128; off > 0; off >>= 1){
        if (t < off){ red[t] += red[t+off]; red2[t] += red2[t+off]; }
        __syncthreads();
    }
    double F1 = red[0], F2 = red2[0];
    int lane = t & 63, wv = t >> 6;
    for (int e = wv; e < 20; e += 4){
        int row = (e < 10) ? e : (e + 492);
        double s = 0.0, s2 = 0.0;
        for (int c = lane; c < 512; c += 64){
            float v = img[(row<<9) + c];
            s += v; s2 += (double)v*v;
        }
        #pragma unroll
        for (int off = 32; off > 0; off >>= 1){ s += __shfl_down(s, off); s2 += __shfl_down(s2, off); }
        if (lane == 0){ rsum[e] = s; rsum2[e] = s2; }
    }
    __syncthreads();
    if (t < 121){
        int u = t / 11, v = t % 11;
        double S1 = F1, S2 = F2;
        for (int i = 0; i < u; ++i){ S1 -= rsum[i]; S2 -= rsum2[i]; }
        for (int k = 10+u; k < 20; ++k){ S1 -= rsum[k]; S2 -= rsum2[k]; }
        for (int j = 0; j < v; ++j){
            double cw = fc[j], cq = fc2[j];
            for (int i = 0; i < u; ++i){ cw -= E[i][j]; cq -= E2[i][j]; }
            for (int k = 10+u; k < 20; ++k){ cw -= E[k][j]; cq -= E2[k][j]; }
            S1 -= cw; S2 -= cq;
        }
        for (int jj = 10+v; jj < 20; ++jj){
            int col = jj + 492;
            double cw = fc[col], cq = fc2[col];
            for (int i = 0; i < u; ++i){ cw -= E[i][jj]; cq -= E2[i][jj]; }
            for (int k = 10+u; k < 20; ++k){ cw -= E[k][jj]; cq -= E2[k][jj]; }
            S1 -= cw; S2 -= cq;
        }
        const double K = 502.0*502.0;
        double ivar = S2/K - (S1*S1)/(K*K*K) + 1e-8;
        if (ivar < 0.0) ivar = 0.0;
        den[b*121 + u*11 + v] = sqrt(stats[1] * ivar);
    }
}

// K3: MFMA NCC (R10 structure, verified)
__global__ __launch_bounds__(256, 2) void k_ncc(const float* __restrict__ fr,
                                                const unsigned short* __restrict__ tsp,
                                                float* __restrict__ partial){
    int b = blockIdx.x >> 6, chunk = blockIdx.x & 63;
    int i0 = chunk << 3;
    int tid = threadIdx.x;
    __shared__ unsigned short Th[24][520], Tl[24][520];
    __shared__ unsigned short Xh[8][544], Xl[8][544];
    __shared__ float Dred[4][16][16];
    for (int q = tid; q < 1536; q += 256){
        int r = q >> 6, c8 = (q & 63) << 3;
        int grow = (i0 - 5 + r + 512) & 511;
        *(float4*)&Th[r][c8] = *(const float4*)&tsp[((size_t)grow << 9) + c8];
        *(float4*)&Tl[r][c8] = *(const float4*)&tsp[262144 + ((size_t)grow << 9) + c8];
    }
    const float* img = fr + ((size_t)b << 18);
    for (int q = tid; q < 1088; q += 256){
        int r = q / 136, qq = q - r*136;
        int col = ((qq << 2) - 16) & 511;
        float4 v = *(const float4*)&img[((size_t)(i0 + r) << 9) + col];
        unsigned short h0 = f2bf(v.x), h1 = f2bf(v.y), h2 = f2bf(v.z), h3 = f2bf(v.w);
        v4u hv = {h0, h1, h2, h3};
        v4u lv = {f2bf(v.x - bf2f(h0)), f2bf(v.y - bf2f(h1)), f2bf(v.z - bf2f(h2)), f2bf(v.w - bf2f(h3))};
        *(v4u*)&Xh[r][qq << 2] = hv;
        *(v4u*)&Xl[r][qq << 2] = lv;
    }
    __syncthreads();
    int l = tid & 63, wv = tid >> 6;
    int lr = l & 15, lk = l >> 4;
    v4f acc = (v4f){0.f, 0.f, 0.f, 0.f};
    union UB { unsigned u[4]; v8s s; };
    int sbase = (lk << 3) - lr + 21;
    unsigned sh = (unsigned)((sbase & 1) << 4);
    #pragma unroll
    for (int ii = 0; ii < 2; ++ii){
        int ro = 2*wv + ii;
        const unsigned* xh32 = (const unsigned*)&Xh[ro][0];
        const unsigned* xl32 = (const unsigned*)&Xl[ro][0];
        #pragma unroll 1
        for (int ks = 0; ks < 16; ++ks){
            int ka = (ks << 5) + (lk << 3);
            v8s ah = *(v8s*)&Th[ro + lr][ka];
            v8s al = *(v8s*)&Tl[ro + lr][ka];
            int W = ((ks << 5) + sbase) >> 1;
            unsigned wh[5], wl[5];
            #pragma unroll
            for (int j = 0; j < 5; ++j){ wh[j] = xh32[W + j]; wl[j] = xl32[W + j]; }
            UB bh, bl;
            #pragma unroll
            for (int j = 0; j < 4; ++j){
                bh.u[j] = __builtin_amdgcn_alignbit(wh[j+1], wh[j], sh);
                bl.u[j] = __builtin_amdgcn_alignbit(wl[j+1], wl[j], sh);
            }
            acc = __builtin_amdgcn_mfma_f32_16x16x32_bf16(ah, bh.s, acc, 0, 0, 0);
            acc = __builtin_amdgcn_mfma_f32_16x16x32_bf16(al, bh.s, acc, 0, 0, 0);
            acc = __builtin_amdgcn_mfma_f32_16x16x32_bf16(ah, bl.s, acc, 0, 0, 0);
        }
    }
    #pragma unroll
    for (int r = 0; r < 4; ++r) Dred[wv][4*lk + r][lr] = acc[r];
    __syncthreads();
    if (tid < 121){
        int s0 = tid / 11, s1 = tid - s0*11;
        int dy = 10 - s0, dx = 10 - s1;
        partial[(size_t)(b*64 + chunk)*121 + tid] =
            Dred[0][dy][dx] + Dred[1][dy][dx] + Dred[2][dy][dx] + Dred[3][dy][dx];
    }
}

// K4: ncc finalize -> shifts, c2
__global__ __launch_bounds__(128) void k_shifts(const float* __restrict__ partial, const double* __restrict__ den,
                                                const double* __restrict__ snn_part, double* __restrict__ shx,
                                                double* __restrict__ shy, float* __restrict__ c2){
    int b = blockIdx.x;
    __shared__ double l[121], nc[121];
    for (int e = threadIdx.x; e < 121; e += 128){
        double s = 0.0;
        for (int c = 0; c < 64; ++c) s += (double)partial[(size_t)(b*64 + c)*121 + e];
        double nom = fabs(s);
        double v = nom / den[b*121 + e];
        if (v != v) v = 0.0;
        nc[e] = v;
        l[e] = log(v);
    }
    __syncthreads();
    if (threadIdx.x == 0){
        int am = 0; double best = nc[0];
        for (int e = 1; e < 121; ++e) if (nc[e] > best){ best = nc[e]; am = e; }
        int u = am / 11, v = am % 11;
        double sx = -(double)(u - 5), sy = -(double)(v - 5);
        int um1 = u - 1; if (um1 < 0) um1 += 11; if (um1 > 10) um1 = 10;
        int up1 = u + 1; if (up1 > 10) up1 = 10;
        int vm1 = v - 1; if (vm1 < 0) vm1 += 11; if (vm1 > 10) vm1 = 10;
        int vp1 = v + 1; if (vp1 > 10) vp1 = 10;
        double l0x4 = 4.0 * l[u*11 + v];
        double lm = l[um1*11 + v], lp = l[up1*11 + v];
        sx -= (lm - lp) / (2.0*lm - l0x4 + 2.0*lp);
        double lm2 = l[u*11 + vm1], lp2 = l[u*11 + vp1];
        sy -= (lm2 - lp2) / (2.0*lm2 - l0x4 + 2.0*lp2);
        shx[b] = sx; shy[b] = sy;
        double snn = 0.0;
        for (int c = 0; c < 8; ++c) snn += snn_part[b*8 + c];
        double kx = sin(PI_D * sx) / 512.0, ky = sin(PI_D * sy) / 512.0;
        c2[b] = (float)(kx * ky * snn);
    }
}

__device__ inline double grekern(int t, double s){
    double u = (double)t - s;
    if (u > 256.0) u -= 512.0;
    double a = PI_D * u / 512.0;
    double sp = sin(a);
    double D;
    if (fabs(sp) < 1e-12) D = cos(PI_D * u) / cos(a);
    else D = sin(PI_D * u) / (512.0 * sp);
    return D * cos(a);
}

// K4b: Dirichlet kernels -> bf16 hi/lo tables
__global__ __launch_bounds__(256) void k_tables(const double* __restrict__ shx, const double* __restrict__ shy,
                                                unsigned short* __restrict__ gtab){
    int b = blockIdx.x;
    double sx = shx[b], sy = shy[b];
    unsigned short* g = gtab + ((size_t)b << 11);
    for (int t = threadIdx.x; t < 512; t += 256){
        float gy = (float)grekern(t, sy);
        float gx = (float)grekern(t, sx);
        unsigned short yh = f2bf(gy); unsigned short yl = f2bf(gy - bf2f(yh));
        unsigned short xh = f2bf(gx); unsigned short xl = f2bf(gx - bf2f(xh));
        g[t] = yh; g[512 + t] = yl; g[1024 + t] = xh; g[1536 + t] = xl;
    }
}

// K7a: stage-1 MFMA circulant GEMM, A staged directly from f32 frames (splitx fused).
// Y[m][q] = sum_n X[m][n]*gy[(q-n)&511]; BM=128, BN=128, B on-the-fly from reversed table.
__global__ __launch_bounds__(256) void k_gemmA(const float* __restrict__ fr,
                                               const unsigned short* __restrict__ gtab,
                                               float* __restrict__ Cout, int b0, int swz){
    int bid = blockIdx.x;
    int lb, tile;
    if (swz){ int x = bid & 7; int r = bid >> 3; lb = (r >> 4)*8 + x; tile = r & 15; }
    else    { lb = bid >> 4; tile = bid & 15; }
    int mt = tile >> 2, nt = tile & 3;
    int tid = threadIdx.x;
    __shared__ unsigned short Ath[128][40], Atl[128][40];   // 80B rows: 16B-aligned b128 reads
    __shared__ unsigned short grh[1024], grl[1024];
    int bg = b0 + lb;
    const unsigned short* gax = gtab + ((size_t)bg << 11);  // axis 0 (gy)
    for (int i = tid; i < 1024; i += 256){
        int src = (512 - (i & 511)) & 511;
        grh[i] = gax[src];
        grl[i] = gax[512 + src];
    }
    v4f acc[4][4];
    #pragma unroll
    for (int mi = 0; mi < 4; ++mi)
        #pragma unroll
        for (int ni = 0; ni < 4; ++ni) acc[mi][ni] = (v4f){0.f, 0.f, 0.f, 0.f};
    const float* img = fr + ((size_t)bg << 18) + (size_t)mt*128*512;
    int l = tid & 63, wv = tid >> 6;
    int wm = wv >> 1, wn = wv & 1;
    int lr = l & 15, lk = l >> 4;
    int colb = nt*128 + wn*64 + lr;
    unsigned sh = (unsigned)((colb & 1) << 4);
    const unsigned* grh32 = (const unsigned*)grh;
    const unsigned* grl32 = (const unsigned*)grl;
    union UB { unsigned u[4]; v8s s; };
    #pragma unroll 1
    for (int ks = 0; ks < 16; ++ks){
        __syncthreads();
        #pragma unroll
        for (int p = 0; p < 4; ++p){
            int lin = tid + 256*p;
            int r = lin >> 3, qf = lin & 7;
            float4 v = *(const float4*)&img[(size_t)r*512 + (ks << 5) + qf*4];
            unsigned short h0 = f2bf(v.x), h1 = f2bf(v.y), h2 = f2bf(v.z), h3 = f2bf(v.w);
            v4u hv = {h0, h1, h2, h3};
            v4u lv = {f2bf(v.x - bf2f(h0)), f2bf(v.y - bf2f(h1)), f2bf(v.z - bf2f(h2)), f2bf(v.w - bf2f(h3))};
            *(v4u*)&Ath[r][qf*4] = hv;
            *(v4u*)&Atl[r][qf*4] = lv;
        }
        __syncthreads();
        v8s bhs[4], bls[4];
        #pragma unroll
        for (int ni = 0; ni < 4; ++ni){
            int f = ((ks << 5) + (lk << 3) - (colb + ni*16)) & 511;
            int W = f >> 1;
            unsigned wh[5], wl[5];
            #pragma unroll
            for (int j = 0; j < 5; ++j){ wh[j] = grh32[W + j]; wl[j] = grl32[W + j]; }
            UB bh, bl;
            #pragma unroll
            for (int j = 0; j < 4; ++j){
                bh.u[j] = __builtin_amdgcn_alignbit(wh[j+1], wh[j], sh);
                bl.u[j] = __builtin_amdgcn_alignbit(wl[j+1], wl[j], sh);
            }
            bhs[ni] = bh.s; bls[ni] = bl.s;
        }
        #pragma unroll
        for (int mi = 0; mi < 4; ++mi){
            int row = wm*64 + mi*16 + lr;
            v8s ah = *(v8s*)&Ath[row][lk*8];
            v8s al = *(v8s*)&Atl[row][lk*8];
            #pragma unroll
            for (int ni = 0; ni < 4; ++ni){
                acc[mi][ni] = __builtin_amdgcn_mfma_f32_16x16x32_bf16(ah, bhs[ni], acc[mi][ni], 0, 0, 0);
                acc[mi][ni] = __builtin_amdgcn_mfma_f32_16x16x32_bf16(al, bhs[ni], acc[mi][ni], 0, 0, 0);
                acc[mi][ni] = __builtin_amdgcn_mfma_f32_16x16x32_bf16(ah, bls[ni], acc[mi][ni], 0, 0, 0);
            }
        }
    }
    float* outp = Cout + ((size_t)bg << 18);       // Y -> d_out (f32 scratch, as R12)
    int crow4 = lk * 4;
    #pragma unroll
    for (int mi = 0; mi < 4; ++mi)
        #pragma unroll
        for (int ni = 0; ni < 4; ++ni)
            #pragma unroll
            for (int rg = 0; rg < 4; ++rg){
                int row = mt*128 + wm*64 + mi*16 + crow4 + rg;
                int col = nt*128 + wn*64 + ni*16 + lr;
                outp[((size_t)row << 9) + col] = acc[mi][ni][rg];
            }
}

// K7: MFMA circulant GEMM (R12-verified, verbatim) — used for stage 2 with A=YThi/YTlo.
template<int CORR>
__global__ __launch_bounds__(256) void k_gemm(const unsigned short* __restrict__ Ahi,
                                              const unsigned short* __restrict__ Alo,
                                              const unsigned short* __restrict__ gtab, int axis,
                                              float* __restrict__ Cout,
                                              const float* __restrict__ c2, int b0, int swz){
    int bid = blockIdx.x;
    int lb, tile;
    if (swz){ int x = bid & 7; int r = bid >> 3; lb = (r >> 4)*8 + x; tile = r & 15; }
    else    { lb = bid >> 4; tile = bid & 15; }
    int mt = tile >> 2, nt = tile & 3;
    int tid = threadIdx.x;
    __shared__ unsigned short Ath[128][40], Atl[128][40];   // 80B rows: 16B-aligned b128 reads
    __shared__ unsigned short grh[1024], grl[1024];         // reversed + duplicated table
    int bg = b0 + lb;
    const unsigned short* gax = gtab + ((size_t)bg << 11) + (axis << 10);
    for (int i = tid; i < 1024; i += 256){
        int src = (512 - (i & 511)) & 511;
        grh[i] = gax[src];
        grl[i] = gax[512 + src];
    }
    v4f acc[4][4];
    #pragma unroll
    for (int mi = 0; mi < 4; ++mi)
        #pragma unroll
        for (int ni = 0; ni < 4; ++ni) acc[mi][ni] = (v4f){0.f, 0.f, 0.f, 0.f};
    const unsigned short* Aph = Ahi + ((size_t)lb << 18) + (size_t)mt*128*512;
    const unsigned short* Apl = Alo + ((size_t)lb << 18) + (size_t)mt*128*512;
    int l = tid & 63, wv = tid >> 6;
    int wm = wv >> 1, wn = wv & 1;
    int lr = l & 15, lk = l >> 4;
    int colb = nt*128 + wn*64 + lr;                 // + ni*16
    unsigned sh = (unsigned)((colb & 1) << 4);      // parity fixed per thread
    int srow = tid >> 1, sc = (tid & 1) << 4;       // staging map
    const unsigned* grh32 = (const unsigned*)grh;
    const unsigned* grl32 = (const unsigned*)grl;
    union UB { unsigned u[4]; v8s s; };
    #pragma unroll 1
    for (int ks = 0; ks < 16; ++ks){
        __syncthreads();
        { size_t go = (size_t)srow*512 + (ks << 5) + sc;
          *(float4*)&Ath[srow][sc]     = *(const float4*)&Aph[go];
          *(float4*)&Ath[srow][sc + 8] = *(const float4*)&Aph[go + 8];
          *(float4*)&Atl[srow][sc]     = *(const float4*)&Apl[go];
          *(float4*)&Atl[srow][sc + 8] = *(const float4*)&Apl[go + 8]; }
        __syncthreads();
        v8s bhs[4], bls[4];
        #pragma unroll
        for (int ni = 0; ni < 4; ++ni){
            int f = ((ks << 5) + (lk << 3) - (colb + ni*16)) & 511;
            int W = f >> 1;
            unsigned wh[5], wl[5];
            #pragma unroll
            for (int j = 0; j < 5; ++j){ wh[j] = grh32[W + j]; wl[j] = grl32[W + j]; }
            UB bh, bl;
            #pragma unroll
            for (int j = 0; j < 4; ++j){
                bh.u[j] = __builtin_amdgcn_alignbit(wh[j+1], wh[j], sh);
                bl.u[j] = __builtin_amdgcn_alignbit(wl[j+1], wl[j], sh);
            }
            bhs[ni] = bh.s; bls[ni] = bl.s;
        }
        #pragma unroll
        for (int mi = 0; mi < 4; ++mi){
            int row = wm*64 + mi*16 + lr;
            v8s ah = *(v8s*)&Ath[row][lk*8];
            v8s al = *(v8s*)&Atl[row][lk*8];
            #pragma unroll
            for (int ni = 0; ni < 4; ++ni){
                acc[mi][ni] = __builtin_amdgcn_mfma_f32_16x16x32_bf16(ah, bhs[ni], acc[mi][ni], 0, 0, 0);
                acc[mi][ni] = __builtin_amdgcn_mfma_f32_16x16x32_bf16(al, bhs[ni], acc[mi][ni], 0, 0, 0);
                acc[mi][ni] = __builtin_amdgcn_mfma_f32_16x16x32_bf16(ah, bls[ni], acc[mi][ni], 0, 0, 0);
            }
        }
    }
    float cc = CORR ? c2[bg] : 0.f;
    float* outp = Cout + ((size_t)bg << 18);
    int crow4 = lk * 4;
    #pragma unroll
    for (int mi = 0; mi < 4; ++mi)
        #pragma unroll
        for (int ni = 0; ni < 4; ++ni)
            #pragma unroll
            for (int rg = 0; rg < 4; ++rg){
                int row = mt*128 + wm*64 + mi*16 + crow4 + rg;
                int col = nt*128 + wn*64 + ni*16 + lr;
                float v = acc[mi][ni][rg];
                if (CORR) v -= ((row + col) & 1) ? -cc : cc;
                outp[((size_t)row << 9) + col] = v;
            }
}

// K8: transpose Y -> YT hi/lo bf16 (R12-verified, verbatim)
__global__ __launch_bounds__(256) void k_transpose2(const float* __restrict__ Y,
                                                    unsigned short* __restrict__ Thi,
                                                    unsigned short* __restrict__ Tlo, int b0){
    int lb = blockIdx.x >> 8, tb = blockIdx.x & 255;
    int tx = (tb & 15) << 5, ty = ((tb >> 4) & 15) << 5;
    const float* src = Y + (((size_t)(b0 + lb)) << 18);
    unsigned short* dh = Thi + (((size_t)lb) << 18);
    unsigned short* dl = Tlo + (((size_t)lb) << 18);
    __shared__ float tile[32][33];
    int col = threadIdx.x & 31, rw = threadIdx.x >> 5;
    #pragma unroll
    for (int k = 0; k < 4; ++k){
        int ry = rw + k*8;
        tile[ry][col] = src[((size_t)(ty + ry) << 9) + tx + col];
    }
    __syncthreads();
    #pragma unroll
    for (int k = 0; k < 4; ++k){
        int ry = rw + k*8;
        float v = tile[col][ry];
        unsigned short h = f2bf(v);
        size_t o = ((size_t)(tx + ry) << 9) + ty + col;
        dh[o] = h;
        dl[o] = f2bf(v - bf2f(h));
    }
}

extern "C" void kernel_launch(void* const* d_in, const int* in_sizes, int n_in,
                              void* d_out, int out_size, void* d_ws, size_t ws_size,
                              hipStream_t stream){
    (void)in_sizes; (void)n_in; (void)out_size;
    const float* fr  = (const float*)d_in[0];
    const float* tpl = (const float*)d_in[1];
    float* out = (float*)d_out;
    char* ws = (char*)d_ws;

    double* stats  = (double*)(ws + 0);
    double* spart  = (double*)(ws + 64);
    double* den    = (double*)(ws + 2048);
    double* snnp   = (double*)(ws + 33280);
    double* shx    = (double*)(ws + 35328);
    double* shy    = (double*)(ws + 35584);
    float*  c2     = (float*) (ws + 35840);
    float*  part   = (float*) (ws + 36096);
    unsigned short* gtab = (unsigned short*)(ws + 1027328);
    unsigned short* tsp  = (unsigned short*)(ws + 1158400);
    float*  csum   = (float*) (ws + 2206976);
    float*  csum2  = (float*) (ws + 2731264);

    const size_t CB = 3255552;
    long long avail = ((long long)ws_size - (long long)CB) / (1ll << 20);
    int NC = (int)avail; if (NC > 32) NC = 32; if (NC < 1) NC = 1;
    if (NC >= 8) NC &= ~7;
    int swz = (NC % 8 == 0) ? 1 : 0;

    unsigned short* YThi = (unsigned short*)(ws + CB);
    unsigned short* YTlo = YThi + (size_t)NC*262144;

    k_stats_part<<<64, 256, 0, stream>>>(tpl, spart);
    k_stats_final<<<1, 64, 0, stream>>>(spart, stats);
    k_tsplit<<<256, 256, 0, stream>>>(tpl, stats, tsp);
    k_colsums<<<256, 256, 0, stream>>>(fr, csum, csum2, snnp);
    k_winfin<<<32, 256, 0, stream>>>(fr, csum, csum2, stats, den);
    k_ncc<<<2048, 256, 0, stream>>>(fr, tsp, part);
    k_shifts<<<32, 128, 0, stream>>>(part, den, snnp, shx, shy, c2);
    k_tables<<<32, 256, 0, stream>>>(shx, shy, gtab);

    for (int b0 = 0; b0 < 32; b0 += NC){
        int nb = (32 - b0 < NC) ? (32 - b0) : NC;
        int sw = (swz && (nb % 8 == 0)) ? 1 : 0;
        // stage 1 (fused splitx): Y = X * Gy -> d_out (f32 scratch)
        k_gemmA<<<nb*16, 256, 0, stream>>>(fr, gtab, out, b0, sw);
        // transpose + split: YT hi/lo (R12 path)
        k_transpose2<<<nb*256, 256, 0, stream>>>(out, YThi, YTlo, b0);
        // stage 2: Out = YT * Gx - c2*(-1)^(p+q) -> d_out (final)
        k_gemm<1><<<nb*16, 256, 0, stream>>>(YThi, YTlo, gtab, 1, out, c2, b0, sw);
    }
}

// Round 15
// 170.539 us; speedup vs baseline: 3.6920x; 1.0419x over previous
//
#include <hip/hip_runtime.h>
#include <hip/hip_bf16.h>
#include <math.h>

#define NPIX 262144          // 512*512
#define PI_D 3.14159265358979323846264338327950288

typedef __attribute__((ext_vector_type(8))) short v8s;           // bf16x8 MFMA fragment
typedef __attribute__((ext_vector_type(4))) float v4f;           // f32x4 accumulator
typedef __attribute__((ext_vector_type(4))) unsigned short v4u;

// ---------------- ws layout (byte offsets) ----------------
// 0        double stats[2]
// 64       double spart[64][2]
// 2048     double den[32][121]
// 33280    double snn_part[32][8]
// 35328    double shx[32]
// 35584    double shy[32]
// 35840    float  c2[32]
// 36096    float  partial[32][64][121]          ends 1,027,328
// 1027328  ushort gtab[32][2][2][512]           ends 1,158,400
// 1158400  ushort tsp[2][512][512]              ends 2,206,976
// 2206976  float  csum[32][8][512]              ends 2,731,264
// 2731264  float  csum2[32][8][512]             ends 3,255,552
// 3255552  chunk area: per image 1 MB (YThi/YTlo 512KB each)

__device__ inline unsigned short f2bf(float x){
    unsigned u = __float_as_uint(x);
    return (unsigned short)((u + 0x7FFFu + ((u >> 16) & 1u)) >> 16);   // RNE
}
__device__ inline float bf2f(unsigned short h){ return __uint_as_float(((unsigned)h) << 16); }

// K1a: template partial sums
__global__ __launch_bounds__(256) void k_stats_part(const float* __restrict__ t, double* __restrict__ part){
    int base = blockIdx.x * 4096;
    double s = 0.0, s2 = 0.0;
    #pragma unroll
    for (int k = 0; k < 4; ++k){
        float4 v = *(const float4*)&t[base + k*1024 + threadIdx.x*4];
        s  += (double)v.x + (double)v.y + (double)v.z + (double)v.w;
        s2 += (double)v.x*v.x + (double)v.y*v.y + (double)v.z*v.z + (double)v.w*v.w;
    }
    __shared__ double rs[256], rs2[256];
    rs[threadIdx.x] = s; rs2[threadIdx.x] = s2; __syncthreads();
    for (int off = 128; off > 0; off >>= 1){
        if (threadIdx.x < off){ rs[threadIdx.x] += rs[threadIdx.x+off]; rs2[threadIdx.x] += rs2[threadIdx.x+off]; }
        __syncthreads();
    }
    if (threadIdx.x == 0){ part[blockIdx.x*2] = rs[0]; part[blockIdx.x*2+1] = rs2[0]; }
}

__global__ __launch_bounds__(64) void k_stats_final(const double* __restrict__ part, double* __restrict__ stats){
    double s = part[threadIdx.x*2], s2 = part[threadIdx.x*2+1];
    #pragma unroll
    for (int off = 32; off > 0; off >>= 1){
        s  += __shfl_down(s, off);
        s2 += __shfl_down(s2, off);
    }
    if (threadIdx.x == 0){
        stats[0] = s / (double)NPIX;
        stats[1] = s2 - s*s/(double)NPIX + 1e-8;
    }
}

// K1c: template -> zero-mean bf16 hi/lo
__global__ __launch_bounds__(256) void k_tsplit(const float* __restrict__ tpl, const double* __restrict__ stats,
                                                unsigned short* __restrict__ tsp){
    float mean = (float)stats[0];
    int base = blockIdx.x * 1024 + threadIdx.x * 4;
    float4 v = *(const float4*)&tpl[base];
    v.x -= mean; v.y -= mean; v.z -= mean; v.w -= mean;
    unsigned short h0 = f2bf(v.x), h1 = f2bf(v.y), h2 = f2bf(v.z), h3 = f2bf(v.w);
    v4u hv = {h0, h1, h2, h3};
    v4u lv = {f2bf(v.x - bf2f(h0)), f2bf(v.y - bf2f(h1)), f2bf(v.z - bf2f(h2)), f2bf(v.w - bf2f(h3))};
    *(v4u*)&tsp[base] = hv;
    *(v4u*)&tsp[262144 + base] = lv;
}

// K2a: per-chunk column sums + Nyquist alternating sum
__global__ __launch_bounds__(256) void k_colsums(const float* __restrict__ fr, float* __restrict__ csum,
                                                 float* __restrict__ csum2, double* __restrict__ snn_part){
    int b = blockIdx.x >> 3, chunk = blockIdx.x & 7;
    const float* img = fr + (size_t)b * NPIX + (size_t)chunk * (64*512);
    int t = threadIdx.x;
    float a0=0.f, q0=0.f, a1=0.f, q1=0.f;
    double sn = 0.0;
    for (int r = 0; r < 64; ++r){
        float v0 = img[(r<<9) + t];
        float v1 = img[(r<<9) + t + 256];
        a0 += v0; q0 += v0*v0; a1 += v1; q1 += v1*v1;
        float sv = v0 + v1;
        sn += ((r + t) & 1) ? -(double)sv : (double)sv;
    }
    size_t o = ((size_t)(b*8 + chunk) << 9) + t;
    csum[o] = a0;  csum[o + 256] = a1;
    csum2[o] = q0; csum2[o + 256] = q1;
    __shared__ double rs[256];
    rs[t] = sn; __syncthreads();
    for (int off = 128; off > 0; off >>= 1){
        if (t < off) rs[t] += rs[t+off];
        __syncthreads();
    }
    if (t == 0) snn_part[b*8 + chunk] = rs[0];
}

// K2b: finalize 121 window denominators
__global__ __launch_bounds__(256) void k_winfin(const float* __restrict__ fr, const float* __restrict__ csum,
                                                const float* __restrict__ csum2, const double* __restrict__ stats,
                                                double* __restrict__ den){
    int b = blockIdx.x;
    const float* img = fr + (size_t)b * NPIX;
    __shared__ double fc[512], fc2[512];
    __shared__ double rsum[20], rsum2[20];
    __shared__ float E[20][20], E2[20][20];
    __shared__ double red[256], red2[256];
    int t = threadIdx.x;
    for (int c = t; c < 512; c += 256){
        double s = 0.0, s2 = 0.0;
        for (int k = 0; k < 8; ++k){
            size_t o = ((size_t)(b*8 + k) << 9) + c;
            s += (double)csum[o]; s2 += (double)csum2[o];
        }
        fc[c] = s; fc2[c] = s2;
    }
    if (t < 400){
        int i = t / 20, j = t % 20;
        int row = (i < 10) ? i : (i + 492);
        int col = (j < 10) ? j : (j + 492);
        float v = img[(row<<9) + col];
        E[i][j] = v; E2[i][j] = v*v;
    }
    __syncthreads();
    red[t] = fc[t] + fc[t+256];
    red2[t] = fc2[t] + fc2[t+256];
    __syncthreads();
    for (int off = 128; off > 0; off >>= 1){
        if (t < off){ red[t] += red[t+off]; red2[t] += red2[t+off]; }
        __syncthreads();
    }
    double F1 = red[0], F2 = red2[0];
    int lane = t & 63, wv = t >> 6;
    for (int e = wv; e < 20; e += 4){
        int row = (e < 10) ? e : (e + 492);
        double s = 0.0, s2 = 0.0;
        for (int c = lane; c < 512; c += 64){
            float v = img[(row<<9) + c];
            s += v; s2 += (double)v*v;
        }
        #pragma unroll
        for (int off = 32; off > 0; off >>= 1){ s += __shfl_down(s, off); s2 += __shfl_down(s2, off); }
        if (lane == 0){ rsum[e] = s; rsum2[e] = s2; }
    }
    __syncthreads();
    if (t < 121){
        int u = t / 11, v = t % 11;
        double S1 = F1, S2 = F2;
        for (int i = 0; i < u; ++i){ S1 -= rsum[i]; S2 -= rsum2[i]; }
        for (int k = 10+u; k < 20; ++k){ S1 -= rsum[k]; S2 -= rsum2[k]; }
        for (int j = 0; j < v; ++j){
            double cw = fc[j], cq = fc2[j];
            for (int i = 0; i < u; ++i){ cw -= E[i][j]; cq -= E2[i][j]; }
            for (int k = 10+u; k < 20; ++k){ cw -= E[k][j]; cq -= E2[k][j]; }
            S1 -= cw; S2 -= cq;
        }
        for (int jj = 10+v; jj < 20; ++jj){
            int col = jj + 492;
            double cw = fc[col], cq = fc2[col];
            for (int i = 0; i < u; ++i){ cw -= E[i][jj]; cq -= E2[i][jj]; }
            for (int k = 10+u; k < 20; ++k){ cw -= E[k][jj]; cq -= E2[k][jj]; }
            S1 -= cw; S2 -= cq;
        }
        const double K = 502.0*502.0;
        double ivar = S2/K - (S1*S1)/(K*K*K) + 1e-8;
        if (ivar < 0.0) ivar = 0.0;
        den[b*121 + u*11 + v] = sqrt(stats[1] * ivar);
    }
}

// K3: MFMA NCC (R10 structure, verified)
__global__ __launch_bounds__(256, 2) void k_ncc(const float* __restrict__ fr,
                                                const unsigned short* __restrict__ tsp,
                                                float* __restrict__ partial){
    int b = blockIdx.x >> 6, chunk = blockIdx.x & 63;
    int i0 = chunk << 3;
    int tid = threadIdx.x;
    __shared__ unsigned short Th[24][520], Tl[24][520];
    __shared__ unsigned short Xh[8][544], Xl[8][544];
    __shared__ float Dred[4][16][16];
    for (int q = tid; q < 1536; q += 256){
        int r = q >> 6, c8 = (q & 63) << 3;
        int grow = (i0 - 5 + r + 512) & 511;
        *(float4*)&Th[r][c8] = *(const float4*)&tsp[((size_t)grow << 9) + c8];
        *(float4*)&Tl[r][c8] = *(const float4*)&tsp[262144 + ((size_t)grow << 9) + c8];
    }
    const float* img = fr + ((size_t)b << 18);
    for (int q = tid; q < 1088; q += 256){
        int r = q / 136, qq = q - r*136;
        int col = ((qq << 2) - 16) & 511;
        float4 v = *(const float4*)&img[((size_t)(i0 + r) << 9) + col];
        unsigned short h0 = f2bf(v.x), h1 = f2bf(v.y), h2 = f2bf(v.z), h3 = f2bf(v.w);
        v4u hv = {h0, h1, h2, h3};
        v4u lv = {f2bf(v.x - bf2f(h0)), f2bf(v.y - bf2f(h1)), f2bf(v.z - bf2f(h2)), f2bf(v.w - bf2f(h3))};
        *(v4u*)&Xh[r][qq << 2] = hv;
        *(v4u*)&Xl[r][qq << 2] = lv;
    }
    __syncthreads();
    int l = tid & 63, wv = tid >> 6;
    int lr = l & 15, lk = l >> 4;
    v4f acc = (v4f){0.f, 0.f, 0.f, 0.f};
    union UB { unsigned u[4]; v8s s; };
    int sbase = (lk << 3) - lr + 21;
    unsigned sh = (unsigned)((sbase & 1) << 4);
    #pragma unroll
    for (int ii = 0; ii < 2; ++ii){
        int ro = 2*wv + ii;
        const unsigned* xh32 = (const unsigned*)&Xh[ro][0];
        const unsigned* xl32 = (const unsigned*)&Xl[ro][0];
        #pragma unroll 1
        for (int ks = 0; ks < 16; ++ks){
            int ka = (ks << 5) + (lk << 3);
            v8s ah = *(v8s*)&Th[ro + lr][ka];
            v8s al = *(v8s*)&Tl[ro + lr][ka];
            int W = ((ks << 5) + sbase) >> 1;
            unsigned wh[5], wl[5];
            #pragma unroll
            for (int j = 0; j < 5; ++j){ wh[j] = xh32[W + j]; wl[j] = xl32[W + j]; }
            UB bh, bl;
            #pragma unroll
            for (int j = 0; j < 4; ++j){
                bh.u[j] = __builtin_amdgcn_alignbit(wh[j+1], wh[j], sh);
                bl.u[j] = __builtin_amdgcn_alignbit(wl[j+1], wl[j], sh);
            }
            acc = __builtin_amdgcn_mfma_f32_16x16x32_bf16(ah, bh.s, acc, 0, 0, 0);
            acc = __builtin_amdgcn_mfma_f32_16x16x32_bf16(al, bh.s, acc, 0, 0, 0);
            acc = __builtin_amdgcn_mfma_f32_16x16x32_bf16(ah, bl.s, acc, 0, 0, 0);
        }
    }
    #pragma unroll
    for (int r = 0; r < 4; ++r) Dred[wv][4*lk + r][lr] = acc[r];
    __syncthreads();
    if (tid < 121){
        int s0 = tid / 11, s1 = tid - s0*11;
        int dy = 10 - s0, dx = 10 - s1;
        partial[(size_t)(b*64 + chunk)*121 + tid] =
            Dred[0][dy][dx] + Dred[1][dy][dx] + Dred[2][dy][dx] + Dred[3][dy][dx];
    }
}

// K4: ncc finalize -> shifts, c2
__global__ __launch_bounds__(128) void k_shifts(const float* __restrict__ partial, const double* __restrict__ den,
                                                const double* __restrict__ snn_part, double* __restrict__ shx,
                                                double* __restrict__ shy, float* __restrict__ c2){
    int b = blockIdx.x;
    __shared__ double l[121], nc[121];
    for (int e = threadIdx.x; e < 121; e += 128){
        double s = 0.0;
        for (int c = 0; c < 64; ++c) s += (double)partial[(size_t)(b*64 + c)*121 + e];
        double nom = fabs(s);
        double v = nom / den[b*121 + e];
        if (v != v) v = 0.0;
        nc[e] = v;
        l[e] = log(v);
    }
    __syncthreads();
    if (threadIdx.x == 0){
        int am = 0; double best = nc[0];
        for (int e = 1; e < 121; ++e) if (nc[e] > best){ best = nc[e]; am = e; }
        int u = am / 11, v = am % 11;
        double sx = -(double)(u - 5), sy = -(double)(v - 5);
        int um1 = u - 1; if (um1 < 0) um1 += 11; if (um1 > 10) um1 = 10;
        int up1 = u + 1; if (up1 > 10) up1 = 10;
        int vm1 = v - 1; if (vm1 < 0) vm1 += 11; if (vm1 > 10) vm1 = 10;
        int vp1 = v + 1; if (vp1 > 10) vp1 = 10;
        double l0x4 = 4.0 * l[u*11 + v];
        double lm = l[um1*11 + v], lp = l[up1*11 + v];
        sx -= (lm - lp) / (2.0*lm - l0x4 + 2.0*lp);
        double lm2 = l[u*11 + vm1], lp2 = l[u*11 + vp1];
        sy -= (lm2 - lp2) / (2.0*lm2 - l0x4 + 2.0*lp2);
        shx[b] = sx; shy[b] = sy;
        double snn = 0.0;
        for (int c = 0; c < 8; ++c) snn += snn_part[b*8 + c];
        double kx = sin(PI_D * sx) / 512.0, ky = sin(PI_D * sy) / 512.0;
        c2[b] = (float)(kx * ky * snn);
    }
}

__device__ inline double grekern(int t, double s){
    double u = (double)t - s;
    if (u > 256.0) u -= 512.0;
    double a = PI_D * u / 512.0;
    double sp = sin(a);
    double D;
    if (fabs(sp) < 1e-12) D = cos(PI_D * u) / cos(a);
    else D = sin(PI_D * u) / (512.0 * sp);
    return D * cos(a);
}

// K4b: Dirichlet kernels -> bf16 hi/lo tables
__global__ __launch_bounds__(256) void k_tables(const double* __restrict__ shx, const double* __restrict__ shy,
                                                unsigned short* __restrict__ gtab){
    int b = blockIdx.x;
    double sx = shx[b], sy = shy[b];
    unsigned short* g = gtab + ((size_t)b << 11);
    for (int t = threadIdx.x; t < 512; t += 256){
        float gy = (float)grekern(t, sy);
        float gx = (float)grekern(t, sx);
        unsigned short yh = f2bf(gy); unsigned short yl = f2bf(gy - bf2f(yh));
        unsigned short xh = f2bf(gx); unsigned short xl = f2bf(gx - bf2f(xh));
        g[t] = yh; g[512 + t] = yl; g[1024 + t] = xh; g[1536 + t] = xl;
    }
}

// K7a: stage-1 MFMA circulant GEMM, A staged from f32 frames (splitx fused, R14-verified)
// + T14 async-stage split: next-ks global loads issued before the MFMA cluster.
__global__ __launch_bounds__(256) void k_gemmA(const float* __restrict__ fr,
                                               const unsigned short* __restrict__ gtab,
                                               float* __restrict__ Cout, int b0, int swz){
    int bid = blockIdx.x;
    int lb, tile;
    if (swz){ int x = bid & 7; int r = bid >> 3; lb = (r >> 4)*8 + x; tile = r & 15; }
    else    { lb = bid >> 4; tile = bid & 15; }
    int mt = tile >> 2, nt = tile & 3;
    int tid = threadIdx.x;
    __shared__ unsigned short Ath[128][40], Atl[128][40];   // 80B rows: 16B-aligned b128 reads
    __shared__ unsigned short grh[1024], grl[1024];
    int bg = b0 + lb;
    const unsigned short* gax = gtab + ((size_t)bg << 11);  // axis 0 (gy)
    for (int i = tid; i < 1024; i += 256){
        int src = (512 - (i & 511)) & 511;
        grh[i] = gax[src];
        grl[i] = gax[512 + src];
    }
    v4f acc[4][4];
    #pragma unroll
    for (int mi = 0; mi < 4; ++mi)
        #pragma unroll
        for (int ni = 0; ni < 4; ++ni) acc[mi][ni] = (v4f){0.f, 0.f, 0.f, 0.f};
    const float* img = fr + ((size_t)bg << 18) + (size_t)mt*128*512;
    int l = tid & 63, wv = tid >> 6;
    int wm = wv >> 1, wn = wv & 1;
    int lr = l & 15, lk = l >> 4;
    int colb = nt*128 + wn*64 + lr;
    unsigned sh = (unsigned)((colb & 1) << 4);
    const unsigned* grh32 = (const unsigned*)grh;
    const unsigned* grl32 = (const unsigned*)grl;
    union UB { unsigned u[4]; v8s s; };
    int rbase = tid >> 3, qoff = (tid & 7) << 2;            // staging addr components
    // prologue prefetch (ks = 0)
    float4 pf0 = *(const float4*)&img[(size_t)(rbase      )*512 + qoff];
    float4 pf1 = *(const float4*)&img[(size_t)(rbase + 32 )*512 + qoff];
    float4 pf2 = *(const float4*)&img[(size_t)(rbase + 64 )*512 + qoff];
    float4 pf3 = *(const float4*)&img[(size_t)(rbase + 96 )*512 + qoff];
    #pragma unroll 1
    for (int ks = 0; ks < 16; ++ks){
        __syncthreads();
        {   // convert + store prefetched A sub-tiles (8B LDS stores, R14-verified layout)
            float4 vv[4] = {pf0, pf1, pf2, pf3};
            #pragma unroll
            for (int p = 0; p < 4; ++p){
                float4 v = vv[p];
                unsigned short h0 = f2bf(v.x), h1 = f2bf(v.y), h2 = f2bf(v.z), h3 = f2bf(v.w);
                v4u hv = {h0, h1, h2, h3};
                v4u lv = {f2bf(v.x - bf2f(h0)), f2bf(v.y - bf2f(h1)), f2bf(v.z - bf2f(h2)), f2bf(v.w - bf2f(h3))};
                *(v4u*)&Ath[rbase + 32*p][qoff] = hv;
                *(v4u*)&Atl[rbase + 32*p][qoff] = lv;
            }
        }
        __syncthreads();
        v8s bhs[4], bls[4];
        #pragma unroll
        for (int ni = 0; ni < 4; ++ni){
            int f = ((ks << 5) + (lk << 3) - (colb + ni*16)) & 511;
            int W = f >> 1;
            unsigned wh[5], wl[5];
            #pragma unroll
            for (int j = 0; j < 5; ++j){ wh[j] = grh32[W + j]; wl[j] = grl32[W + j]; }
            UB bh, bl;
            #pragma unroll
            for (int j = 0; j < 4; ++j){
                bh.u[j] = __builtin_amdgcn_alignbit(wh[j+1], wh[j], sh);
                bl.u[j] = __builtin_amdgcn_alignbit(wl[j+1], wl[j], sh);
            }
            bhs[ni] = bh.s; bls[ni] = bl.s;
        }
        if (ks < 15){   // issue next-ks loads; latency hides under MFMA cluster
            int c0 = ((ks + 1) << 5) + qoff;
            pf0 = *(const float4*)&img[(size_t)(rbase      )*512 + c0];
            pf1 = *(const float4*)&img[(size_t)(rbase + 32 )*512 + c0];
            pf2 = *(const float4*)&img[(size_t)(rbase + 64 )*512 + c0];
            pf3 = *(const float4*)&img[(size_t)(rbase + 96 )*512 + c0];
        }
        #pragma unroll
        for (int mi = 0; mi < 4; ++mi){
            int row = wm*64 + mi*16 + lr;
            v8s ah = *(v8s*)&Ath[row][lk*8];
            v8s al = *(v8s*)&Atl[row][lk*8];
            #pragma unroll
            for (int ni = 0; ni < 4; ++ni){
                acc[mi][ni] = __builtin_amdgcn_mfma_f32_16x16x32_bf16(ah, bhs[ni], acc[mi][ni], 0, 0, 0);
                acc[mi][ni] = __builtin_amdgcn_mfma_f32_16x16x32_bf16(al, bhs[ni], acc[mi][ni], 0, 0, 0);
                acc[mi][ni] = __builtin_amdgcn_mfma_f32_16x16x32_bf16(ah, bls[ni], acc[mi][ni], 0, 0, 0);
            }
        }
    }
    float* outp = Cout + ((size_t)bg << 18);       // Y -> d_out (f32 scratch)
    int crow4 = lk * 4;
    #pragma unroll
    for (int mi = 0; mi < 4; ++mi)
        #pragma unroll
        for (int ni = 0; ni < 4; ++ni)
            #pragma unroll
            for (int rg = 0; rg < 4; ++rg){
                int row = mt*128 + wm*64 + mi*16 + crow4 + rg;
                int col = nt*128 + wn*64 + ni*16 + lr;
                outp[((size_t)row << 9) + col] = acc[mi][ni][rg];
            }
}

// K7: stage-2 MFMA circulant GEMM (R12-verified layout) + T14 prefetch on A staging.
template<int CORR>
__global__ __launch_bounds__(256) void k_gemm(const unsigned short* __restrict__ Ahi,
                                              const unsigned short* __restrict__ Alo,
                                              const unsigned short* __restrict__ gtab, int axis,
                                              float* __restrict__ Cout,
                                              const float* __restrict__ c2, int b0, int swz){
    int bid = blockIdx.x;
    int lb, tile;
    if (swz){ int x = bid & 7; int r = bid >> 3; lb = (r >> 4)*8 + x; tile = r & 15; }
    else    { lb = bid >> 4; tile = bid & 15; }
    int mt = tile >> 2, nt = tile & 3;
    int tid = threadIdx.x;
    __shared__ unsigned short Ath[128][40], Atl[128][40];   // 80B rows: 16B-aligned b128 reads
    __shared__ unsigned short grh[1024], grl[1024];         // reversed + duplicated table
    int bg = b0 + lb;
    const unsigned short* gax = gtab + ((size_t)bg << 11) + (axis << 10);
    for (int i = tid; i < 1024; i += 256){
        int src = (512 - (i & 511)) & 511;
        grh[i] = gax[src];
        grl[i] = gax[512 + src];
    }
    v4f acc[4][4];
    #pragma unroll
    for (int mi = 0; mi < 4; ++mi)
        #pragma unroll
        for (int ni = 0; ni < 4; ++ni) acc[mi][ni] = (v4f){0.f, 0.f, 0.f, 0.f};
    const unsigned short* Aph = Ahi + ((size_t)lb << 18) + (size_t)mt*128*512;
    const unsigned short* Apl = Alo + ((size_t)lb << 18) + (size_t)mt*128*512;
    int l = tid & 63, wv = tid >> 6;
    int wm = wv >> 1, wn = wv & 1;
    int lr = l & 15, lk = l >> 4;
    int colb = nt*128 + wn*64 + lr;                 // + ni*16
    unsigned sh = (unsigned)((colb & 1) << 4);      // parity fixed per thread
    int srow = tid >> 1, sc = (tid & 1) << 4;       // staging map
    const unsigned* grh32 = (const unsigned*)grh;
    const unsigned* grl32 = (const unsigned*)grl;
    union UB { unsigned u[4]; v8s s; };
    // prologue prefetch (ks = 0)
    size_t go0 = (size_t)srow*512 + sc;
    float4 ph0 = *(const float4*)&Aph[go0];
    float4 ph1 = *(const float4*)&Aph[go0 + 8];
    float4 pl0 = *(const float4*)&Apl[go0];
    float4 pl1 = *(const float4*)&Apl[go0 + 8];
    #pragma unroll 1
    for (int ks = 0; ks < 16; ++ks){
        __syncthreads();
        { *(float4*)&Ath[srow][sc]     = ph0;
          *(float4*)&Ath[srow][sc + 8] = ph1;
          *(float4*)&Atl[srow][sc]     = pl0;
          *(float4*)&Atl[srow][sc + 8] = pl1; }
        __syncthreads();
        v8s bhs[4], bls[4];
        #pragma unroll
        for (int ni = 0; ni < 4; ++ni){
            int f = ((ks << 5) + (lk << 3) - (colb + ni*16)) & 511;
            int W = f >> 1;
            unsigned wh[5], wl[5];
            #pragma unroll
            for (int j = 0; j < 5; ++j){ wh[j] = grh32[W + j]; wl[j] = grl32[W + j]; }
            UB bh, bl;
            #pragma unroll
            for (int j = 0; j < 4; ++j){
                bh.u[j] = __builtin_amdgcn_alignbit(wh[j+1], wh[j], sh);
                bl.u[j] = __builtin_amdgcn_alignbit(wl[j+1], wl[j], sh);
            }
            bhs[ni] = bh.s; bls[ni] = bl.s;
        }
        if (ks < 15){   // issue next-ks loads; latency hides under MFMA cluster
            size_t go = (size_t)srow*512 + ((ks + 1) << 5) + sc;
            ph0 = *(const float4*)&Aph[go];
            ph1 = *(const float4*)&Aph[go + 8];
            pl0 = *(const float4*)&Apl[go];
            pl1 = *(const float4*)&Apl[go + 8];
        }
        #pragma unroll
        for (int mi = 0; mi < 4; ++mi){
            int row = wm*64 + mi*16 + lr;
            v8s ah = *(v8s*)&Ath[row][lk*8];
            v8s al = *(v8s*)&Atl[row][lk*8];
            #pragma unroll
            for (int ni = 0; ni < 4; ++ni){
                acc[mi][ni] = __builtin_amdgcn_mfma_f32_16x16x32_bf16(ah, bhs[ni], acc[mi][ni], 0, 0, 0);
                acc[mi][ni] = __builtin_amdgcn_mfma_f32_16x16x32_bf16(al, bhs[ni], acc[mi][ni], 0, 0, 0);
                acc[mi][ni] = __builtin_amdgcn_mfma_f32_16x16x32_bf16(ah, bls[ni], acc[mi][ni], 0, 0, 0);
            }
        }
    }
    float cc = CORR ? c2[bg] : 0.f;
    float* outp = Cout + ((size_t)bg << 18);
    int crow4 = lk * 4;
    #pragma unroll
    for (int mi = 0; mi < 4; ++mi)
        #pragma unroll
        for (int ni = 0; ni < 4; ++ni)
            #pragma unroll
            for (int rg = 0; rg < 4; ++rg){
                int row = mt*128 + wm*64 + mi*16 + crow4 + rg;
                int col = nt*128 + wn*64 + ni*16 + lr;
                float v = acc[mi][ni][rg];
                if (CORR) v -= ((row + col) & 1) ? -cc : cc;
                outp[((size_t)row << 9) + col] = v;
            }
}

// K8: transpose Y -> YT hi/lo bf16 (R12-verified, verbatim)
__global__ __launch_bounds__(256) void k_transpose2(const float* __restrict__ Y,
                                                    unsigned short* __restrict__ Thi,
                                                    unsigned short* __restrict__ Tlo, int b0){
    int lb = blockIdx.x >> 8, tb = blockIdx.x & 255;
    int tx = (tb & 15) << 5, ty = ((tb >> 4) & 15) << 5;
    const float* src = Y + (((size_t)(b0 + lb)) << 18);
    unsigned short* dh = Thi + (((size_t)lb) << 18);
    unsigned short* dl = Tlo + (((size_t)lb) << 18);
    __shared__ float tile[32][33];
    int col = threadIdx.x & 31, rw = threadIdx.x >> 5;
    #pragma unroll
    for (int k = 0; k < 4; ++k){
        int ry = rw + k*8;
        tile[ry][col] = src[((size_t)(ty + ry) << 9) + tx + col];
    }
    __syncthreads();
    #pragma unroll
    for (int k = 0; k < 4; ++k){
        int ry = rw + k*8;
        float v = tile[col][ry];
        unsigned short h = f2bf(v);
        size_t o = ((size_t)(tx + ry) << 9) + ty + col;
        dh[o] = h;
        dl[o] = f2bf(v - bf2f(h));
    }
}

extern "C" void kernel_launch(void* const* d_in, const int* in_sizes, int n_in,
                              void* d_out, int out_size, void* d_ws, size_t ws_size,
                              hipStream_t stream){
    (void)in_sizes; (void)n_in; (void)out_size;
    const float* fr  = (const float*)d_in[0];
    const float* tpl = (const float*)d_in[1];
    float* out = (float*)d_out;
    char* ws = (char*)d_ws;

    double* stats  = (double*)(ws + 0);
    double* spart  = (double*)(ws + 64);
    double* den    = (double*)(ws + 2048);
    double* snnp   = (double*)(ws + 33280);
    double* shx    = (double*)(ws + 35328);
    double* shy    = (double*)(ws + 35584);
    float*  c2     = (float*) (ws + 35840);
    float*  part   = (float*) (ws + 36096);
    unsigned short* gtab = (unsigned short*)(ws + 1027328);
    unsigned short* tsp  = (unsigned short*)(ws + 1158400);
    float*  csum   = (float*) (ws + 2206976);
    float*  csum2  = (float*) (ws + 2731264);

    const size_t CB = 3255552;
    long long avail = ((long long)ws_size - (long long)CB) / (1ll << 20);
    int NC = (int)avail; if (NC > 32) NC = 32; if (NC < 1) NC = 1;
    if (NC >= 8) NC &= ~7;
    int swz = (NC % 8 == 0) ? 1 : 0;

    unsigned short* YThi = (unsigned short*)(ws + CB);
    unsigned short* YTlo = YThi + (size_t)NC*262144;

    k_stats_part<<<64, 256, 0, stream>>>(tpl, spart);
    k_stats_final<<<1, 64, 0, stream>>>(spart, stats);
    k_tsplit<<<256, 256, 0, stream>>>(tpl, stats, tsp);
    k_colsums<<<256, 256, 0, stream>>>(fr, csum, csum2, snnp);
    k_winfin<<<32, 256, 0, stream>>>(fr, csum, csum2, stats, den);
    k_ncc<<<2048, 256, 0, stream>>>(fr, tsp, part);
    k_shifts<<<32, 128, 0, stream>>>(part, den, snnp, shx, shy, c2);
    k_tables<<<32, 256, 0, stream>>>(shx, shy, gtab);

    for (int b0 = 0; b0 < 32; b0 += NC){
        int nb = (32 - b0 < NC) ? (32 - b0) : NC;
        int sw = (swz && (nb % 8 == 0)) ? 1 : 0;
        // stage 1 (fused splitx): Y = X * Gy -> d_out (f32 scratch)
        k_gemmA<<<nb*16, 256, 0, stream>>>(fr, gtab, out, b0, sw);
        // transpose + split: YT hi/lo (R12 path)
        k_transpose2<<<nb*256, 256, 0, stream>>>(out, YThi, YTlo, b0);
        // stage 2: Out = YT * Gx - c2*(-1)^(p+q) -> d_out (final)
        k_gemm<1><<<nb*16, 256, 0, stream>>>(YThi, YTlo, gtab, 1, out, c2, b0, sw);
    }
}